// Round 16
// baseline (6633.876 us; speedup 1.0000x reference)
//
#include <hip/hip_runtime.h>
#include <cstdint>
#include <cstddef>

// CMAlign forward. R16: conv epilogue writes transposed bf16 fqT/fkT + sumsq
// atomics (norm_transpose deleted); sim_mfma applies inv-norms inline.
// Conv main loop identical to R11 (best, 628us).
// Shapes: B=64, C=2048, Cq=512, H=24, W=12, HW=288.

namespace {
constexpr int kB    = 64;
constexpr int kHalf = 32;
constexpr int kC    = 2048;
constexpr int kCQ   = 512;
constexpr int kH    = 24;
constexpr int kW    = 12;
constexpr int kHW   = 288;
constexpr float kTemp = 50.0f;
constexpr int kXPlane = 366;  // 16B cells; 5856 B = 96 mod 128 -> kg quadrant offsets
}

typedef __attribute__((ext_vector_type(8))) __bf16 bf16x8;
typedef __attribute__((ext_vector_type(4))) float f32x4;
typedef __attribute__((ext_vector_type(8))) unsigned short ushort8;

__device__ __forceinline__ const float* feat_base(const float* fv, const float* ft, int b) {
  return (b < kHalf) ? (fv + (size_t)b * kC * kHW)
                     : (ft + (size_t)(b - kHalf) * kC * kHW);
}

__device__ __forceinline__ unsigned short f2bf(float f) {
  union { float f; unsigned u; } c; c.f = f;
  unsigned u = c.u;
  unsigned r = (u + 0x7FFFu + ((u >> 16) & 1u)) >> 16;  // RNE
  return (unsigned short)r;
}

__device__ __forceinline__ float bf2f(unsigned short h) {
  union { unsigned u; float f; } c; c.u = ((unsigned)h) << 16;
  return c.f;
}

__device__ __forceinline__ void gload_lds16(const void* g, void* l) {
  __builtin_amdgcn_global_load_lds(
      (const __attribute__((address_space(1))) unsigned int*)g,
      (__attribute__((address_space(3))) unsigned int*)l, 16, 0, 0);
}

__global__ void zero_kernel(float* __restrict__ p, int n) {
  int i = blockIdx.x * 256 + threadIdx.x;
  if (i < n) p[i] = 0.f;
}

// -------- weight prep: w[oc][ic][3][3] fp32 -> MFMA-image wt2 --------
__global__ __launch_bounds__(256) void prep_w_kernel(const float* __restrict__ qw,
                                                     const float* __restrict__ kw,
                                                     unsigned short* __restrict__ wtq,
                                                     unsigned short* __restrict__ wtk) {
  int oc = blockIdx.x;
  int z  = blockIdx.y;
  const float* w = (z ? kw : qw) + (size_t)oc * (kC * 9);
  unsigned short* wt = z ? wtk : wtq;
  __shared__ unsigned short lw[kC * 9];  // [ic][tap]
  int t = threadIdx.x;
#pragma unroll
  for (int it = 0; it < 18; ++it) {
    int i4 = (it * 256 + t) * 4;
    float4 v = *(const float4*)(w + i4);
    lw[i4 + 0] = f2bf(v.x);
    lw[i4 + 1] = f2bf(v.y);
    lw[i4 + 2] = f2bf(v.z);
    lw[i4 + 3] = f2bf(v.w);
  }
  __syncthreads();
  for (int item = t; item < 9 * 256; item += 256) {
    int tap = item >> 8;
    int icb = item & 255;
    ushort8 pk;
#pragma unroll
    for (int j = 0; j < 8; ++j) pk[j] = lw[(icb * 8 + j) * 9 + tap];
    size_t dst16 = (((size_t)(icb >> 2) * 9 + tap) * 32 + (oc >> 4)) * 64
                   + (oc & 15) + (icb & 3) * 16;
    *(ushort8*)(wt + dst16 * 8) = pk;
  }
}

// -------- FUSED MFMA conv: main loop = R11; epilogue -> bf16 transposed + sumsq --------
__global__ __launch_bounds__(512, 1) void conv_fused_kernel(const unsigned short* __restrict__ wtq,
                                                            const unsigned short* __restrict__ wtk,
                                                            const float* __restrict__ qb,
                                                            const float* __restrict__ kb,
                                                            const float* __restrict__ fv,
                                                            const float* __restrict__ ft,
                                                            unsigned short* __restrict__ fqT,
                                                            unsigned short* __restrict__ fkT,
                                                            float* __restrict__ qss,
                                                            float* __restrict__ kss) {
  __shared__ unsigned short Wbuf[2 * 6 * 4096];   // 98304 B (epilogue reuses as Ep[288][136])
  __shared__ unsigned short Xs[4 * kXPlane * 8];  // 23424 B
  int t    = threadIdx.x;
  int lane = t & 63;
  int wid  = t >> 6;
  int l15  = lane & 15, kg = lane >> 4;
  int wm   = wid & 1, wn = wid >> 1;  // 2M x 4N
  int n    = blockIdx.x;
  int xcd  = n & 7;
  int oc0  = (xcd >> 1) * 128;
  int b    = ((xcd & 1) << 5) + (n >> 3);
  int f0   = oc0 >> 4;
  const float* fb = feat_base(fv, ft, b);
  const char* wtqB = (const char*)wtq;
  const char* wtkB = (const char*)wtk;

  int  xoff[3];
  bool xvalid[3], xhas[3];
#pragma unroll
  for (int i = 0; i < 3; ++i) {
    int item = i * 512 + t;
    xhas[i] = item < 4 * kXPlane;
    int xkg = item / kXPlane;
    int hp  = item - xkg * kXPlane;
    int hy = hp / 14, hx = hp - hy * 14;
    int y = hy - 1, x = hx - 1;
    bool v = xhas[i] && hp < 364 && (y >= 0 && y < kH && x >= 0 && x < kW);
    xvalid[i] = v;
    xoff[i] = v ? (xkg * 8) * kHW + y * kW + x : 0;
  }

  int aAddr[4];
#pragma unroll
  for (int fm = 0; fm < 4; ++fm)
    aAddr[fm] = (((wm * 4 + fm) * 64) + lane) * 16;
  int nfn = (wn < 2) ? 5 : 4;
  int fnb = (wn < 2) ? wn * 5 : 10 + (wn - 2) * 4;
  int bAddr[5];
#pragma unroll
  for (int fi = 0; fi < 5; ++fi) {
    int p = (fnb + fi) * 16 + l15;
    if (p > 287) p = 287;
    int y = p / kW, x = p - y * kW;
    bAddr[fi] = kg * (kXPlane * 16) + ((y + 1) * 14 + (x + 1)) * 16;
  }

  f32x4 acc[2][4][5];
#pragma unroll
  for (int cv = 0; cv < 2; ++cv)
#pragma unroll
    for (int fm = 0; fm < 4; ++fm)
#pragma unroll
      for (int fi = 0; fi < 5; ++fi) acc[cv][fm][fi] = (f32x4){0.f, 0.f, 0.f, 0.f};

  char* WsB = (char*)Wbuf;
  char* XsB = (char*)Xs;
  int wavebase = t & ~63;

#pragma unroll
  for (int i = 0; i < 3; ++i) {
    if (xhas[i] && !xvalid[i]) {
      ushort8 pk;
#pragma unroll
      for (int j = 0; j < 8; ++j) pk[j] = 0;
      *(ushort8*)(XsB + (size_t)(i * 512 + t) * 16) = pk;
    }
  }
#pragma unroll
  for (int r = 0; r < 3; ++r) {
    size_t g16 = ((size_t)r * 32 + f0 + wid) * 64 + lane;
    gload_lds16(wtqB + g16 * 16, WsB + (size_t)(r * 2 + 0) * 8192 + wavebase * 16);
    gload_lds16(wtkB + g16 * 16, WsB + (size_t)(r * 2 + 1) * 8192 + wavebase * 16);
  }

  int buf = 0;
#pragma unroll 1
  for (int chunk = 0; chunk < 64; ++chunk) {
    int ic0 = chunk * 32;
    {
      float xv[3][8];
#pragma unroll
      for (int i = 0; i < 3; ++i)
        if (xvalid[i]) {
          const float* s = fb + (size_t)ic0 * kHW + xoff[i];
#pragma unroll
          for (int j = 0; j < 8; ++j) xv[i][j] = s[(size_t)j * kHW];
        }
#pragma unroll
      for (int i = 0; i < 3; ++i) {
        if (!xvalid[i]) continue;
        ushort8 pk;
#pragma unroll
        for (int j = 0; j < 8; ++j) pk[j] = f2bf(xv[i][j]);
        *(ushort8*)(XsB + (size_t)(i * 512 + t) * 16) = pk;
      }
    }
    __syncthreads();

#pragma unroll 1
    for (int g = 0; g < 3; ++g) {
      bool hn = (g < 2) || (chunk < 63);
      if (hn) {
        int nchunk = (g < 2) ? chunk : chunk + 1;
        int ng     = (g < 2) ? g + 1 : 0;
#pragma unroll
        for (int r = 0; r < 3; ++r) {
          size_t g16 = ((size_t)(nchunk * 9 + ng * 3 + r) * 32 + f0 + wid) * 64 + lane;
          gload_lds16(wtqB + g16 * 16,
                      WsB + (size_t)((buf ^ 1) * 6 + r * 2 + 0) * 8192 + wavebase * 16);
          gload_lds16(wtkB + g16 * 16,
                      WsB + (size_t)((buf ^ 1) * 6 + r * 2 + 1) * 8192 + wavebase * 16);
        }
      }
#pragma unroll
      for (int r = 0; r < 3; ++r) {
        int tap = g * 3 + r;
        int d16 = ((tap / 3 - 1) * 14 + (tap % 3 - 1)) * 16;
        bf16x8 af[2][4];
#pragma unroll
        for (int cv = 0; cv < 2; ++cv)
#pragma unroll
          for (int fm = 0; fm < 4; ++fm)
            af[cv][fm] = *(const bf16x8*)(WsB + (size_t)(buf * 6 + r * 2 + cv) * 8192 + aAddr[fm]);
#pragma unroll
        for (int fi = 0; fi < 5; ++fi) {
          if (fi >= nfn) continue;
#pragma unroll
          for (int cv = 0; cv < 2; ++cv) {
            bf16x8 bb = *(const bf16x8*)(XsB + bAddr[fi] + d16);
#pragma unroll
            for (int fm = 0; fm < 4; ++fm)
              acc[cv][fm][fi] =
                  __builtin_amdgcn_mfma_f32_16x16x32_bf16(af[cv][fm], bb, acc[cv][fm][fi], 0, 0, 0);
          }
        }
      }
      __syncthreads();
      buf ^= 1;
    }
  }

  // ---- epilogue: per cv, stage bf16 tile in Ep[288][136], sumsq atomics,
  //      then coalesced transposed store fqT/fkT[b][p][c] ----
  unsigned short* Ep = Wbuf;
#pragma unroll 1
  for (int cv = 0; cv < 2; ++cv) {
    const float* bias = cv ? kb : qb;
    float* ssq = cv ? kss : qss;
#pragma unroll
    for (int fi = 0; fi < 5; ++fi) {
      if (fi >= nfn) continue;
      int p = (fnb + fi) * 16 + l15;
      float ps = 0.f;
#pragma unroll
      for (int fm = 0; fm < 4; ++fm)
#pragma unroll
        for (int reg = 0; reg < 4; ++reg) {
          int ocl = wm * 64 + fm * 16 + kg * 4 + reg;
          float v = acc[cv][fm][fi][reg] + bias[oc0 + ocl];
          ps = fmaf(v, v, ps);
          Ep[p * 136 + ocl] = f2bf(v);
        }
      ps += __shfl_xor(ps, 16);
      ps += __shfl_xor(ps, 32);
      if (kg == 0) atomicAdd(ssq + b * kHW + p, ps);
    }
    __syncthreads();
    unsigned short* dstT = (cv ? fkT : fqT) + (size_t)b * kHW * kCQ + oc0;
#pragma unroll
    for (int it = 0; it < 9; ++it) {
      int item = it * 512 + t;
      int p = item >> 4, j = item & 15;
      *(ushort8*)(dstT + (size_t)p * kCQ + j * 8) =
          *(const ushort8*)(Ep + p * 136 + j * 8);
    }
    __syncthreads();
  }
}

// -------- warp GEMM via MFMA (unchanged) --------
__global__ __launch_bounds__(512) void warp_mfma_kernel(const float* __restrict__ fv,
                                                        const float* __restrict__ ft,
                                                        const unsigned short* __restrict__ prb,
                                                        const float* __restrict__ maskp,
                                                        const int* __restrict__ idx,
                                                        float* __restrict__ outp,
                                                        float* __restrict__ dsq,
                                                        int write_out) {
  __shared__ unsigned short AsHi[128 * 32];
  __shared__ unsigned short AsLo[128 * 32];
  __shared__ unsigned short Bs[288 * 32];
  int t    = threadIdx.x;
  int lane = t & 63;
  int wid  = t >> 6;
  int l15  = lane & 15, kg = lane >> 4;
  int wm   = wid >> 1, wn = wid & 1;
  int c0   = blockIdx.x * 128;
  int b    = blockIdx.y;
  int tb   = idx[b];
  const float* tgt = feat_base(fv, ft, tb);
  const float* fb  = feat_base(fv, ft, b);

  int ar = t >> 2, as = t & 3;
  int aslot = as ^ ((ar ^ (ar >> 2)) & 3);
  unsigned short* aDstHi = AsHi + ar * 32 + aslot * 8;
  unsigned short* aDstLo = AsLo + ar * 32 + aslot * 8;

  int aIdx[2];
#pragma unroll
  for (int fm = 0; fm < 2; ++fm) {
    int r = wm * 32 + fm * 16 + l15;
    aIdx[fm] = r * 32 + (kg ^ ((r ^ (r >> 2)) & 3)) * 8;
  }
  int bIdx[9];
#pragma unroll
  for (int fn = 0; fn < 9; ++fn) {
    int q = wn * 144 + fn * 16 + l15;
    bIdx[fn] = q * 32 + (kg ^ ((q ^ (q >> 2)) & 3)) * 8;
  }

  f32x4 acc[2][9];
#pragma unroll
  for (int fm = 0; fm < 2; ++fm)
#pragma unroll
    for (int fn = 0; fn < 9; ++fn) acc[fm][fn] = (f32x4){0.f, 0.f, 0.f, 0.f};

#pragma unroll 1
  for (int chunk = 0; chunk < 9; ++chunk) {
    int k0 = chunk * 32;
    __syncthreads();
    {
      const float* s = tgt + (size_t)(c0 + ar) * kHW + k0 + as * 8;
      float4 v0 = *(const float4*)(s);
      float4 v1 = *(const float4*)(s + 4);
      float xs[8] = {v0.x, v0.y, v0.z, v0.w, v1.x, v1.y, v1.z, v1.w};
      ushort8 hi, lo;
#pragma unroll
      for (int j = 0; j < 8; ++j) {
        unsigned short h = f2bf(xs[j]);
        hi[j] = h;
        lo[j] = f2bf(xs[j] - bf2f(h));
      }
      *(ushort8*)aDstHi = hi;
      *(ushort8*)aDstLo = lo;
    }
#pragma unroll
    for (int i = 0; i < 3; ++i) {
      int item = i * 512 + t;
      if (item < 1152) {
        int q = item >> 2, s = item & 3;
        ushort8 v = *(const ushort8*)(prb + ((size_t)b * kHW + q) * kHW + k0 + s * 8);
        *(ushort8*)(Bs + q * 32 + (s ^ ((q ^ (q >> 2)) & 3)) * 8) = v;
      }
    }
    __syncthreads();
    bf16x8 ah0 = *(const bf16x8*)(AsHi + aIdx[0]);
    bf16x8 al0 = *(const bf16x8*)(AsLo + aIdx[0]);
    bf16x8 ah1 = *(const bf16x8*)(AsHi + aIdx[1]);
    bf16x8 al1 = *(const bf16x8*)(AsLo + aIdx[1]);
#pragma unroll
    for (int fn = 0; fn < 9; ++fn) {
      bf16x8 bb = *(const bf16x8*)(Bs + bIdx[fn]);
      acc[0][fn] = __builtin_amdgcn_mfma_f32_16x16x32_bf16(ah0, bb, acc[0][fn], 0, 0, 0);
      acc[0][fn] = __builtin_amdgcn_mfma_f32_16x16x32_bf16(al0, bb, acc[0][fn], 0, 0, 0);
      acc[1][fn] = __builtin_amdgcn_mfma_f32_16x16x32_bf16(ah1, bb, acc[1][fn], 0, 0, 0);
      acc[1][fn] = __builtin_amdgcn_mfma_f32_16x16x32_bf16(al1, bb, acc[1][fn], 0, 0, 0);
    }
  }

#pragma unroll
  for (int fn = 0; fn < 9; ++fn) {
    int q = wn * 144 + fn * 16 + l15;
    float mj = maskp[b * kHW + q];
    float psum = 0.f;
#pragma unroll
    for (int fm = 0; fm < 2; ++fm) {
#pragma unroll
      for (int reg = 0; reg < 4; ++reg) {
        int c = c0 + wm * 32 + fm * 16 + kg * 4 + reg;
        float fvv = fb[(size_t)c * kHW + q];
        float Wv  = acc[fm][fn][reg];
        float d   = mj * (fvv - Wv) + 1e-6f;
        psum      = fmaf(d, d, psum);
        if (write_out)
          outp[((size_t)b * kC + c) * kHW + q] = mj * Wv + (1.f - mj) * fvv;
      }
    }
    psum += __shfl_xor(psum, 16);
    psum += __shfl_xor(psum, 32);
    if (lane < 16) atomicAdd(&dsq[b * kHW + q], psum);
  }
}

// -------- mask pass 1: partial channel sum-of-squares over 512-c slices --------
__global__ __launch_bounds__(320) void mask_part_kernel(const float* __restrict__ fv,
                                                        const float* __restrict__ ft,
                                                        float* __restrict__ part) {
  int b = blockIdx.x;
  int s = blockIdx.y;
  int t = threadIdx.x;
  if (t >= kHW) return;
  const float* fb = feat_base(fv, ft, b) + (size_t)(s * 512) * kHW;
  float sum = 0.f;
  for (int c = 0; c < 512; ++c) { float v = fb[(size_t)c * kHW + t]; sum += v * v; }
  part[((size_t)b * 4 + s) * kHW + t] = sum;
}

// -------- mask pass 2: finalize sqrt + per-sample min-max normalize --------
__global__ __launch_bounds__(320) void mask_fin_kernel(const float* __restrict__ part,
                                                       float* __restrict__ mask) {
  int b = blockIdx.x;
  int t = threadIdx.x;
  float n = 0.f;
  if (t < kHW) {
    const float* pb = part + (size_t)b * 4 * kHW;
    n = sqrtf(pb[t] + pb[kHW + t] + pb[2 * kHW + t] + pb[3 * kHW + t]);
  }
  __shared__ float sh[320];
  sh[t] = (t < kHW) ? n : 3.4e38f;
  __syncthreads();
  float mn;
  {
    float m = 3.4e38f;
    if (t < 64) {
      for (int i = t; i < 320; i += 64) m = fminf(m, sh[i]);
      for (int off = 32; off; off >>= 1) m = fminf(m, __shfl_xor(m, off));
    }
    __syncthreads();
    if (t == 0) sh[0] = m;
    __syncthreads();
    mn = sh[0];
    __syncthreads();
  }
  sh[t] = (t < kHW) ? n : -3.4e38f;
  __syncthreads();
  float mx;
  {
    float m = -3.4e38f;
    if (t < 64) {
      for (int i = t; i < 320; i += 64) m = fmaxf(m, sh[i]);
      for (int off = 32; off; off >>= 1) m = fmaxf(m, __shfl_xor(m, off));
    }
    __syncthreads();
    if (t == 0) sh[0] = m;
    __syncthreads();
    mx = sh[0];
  }
  if (t < kHW) mask[b * kHW + t] = (n - mn) / ((mx - mn) + 1e-12f);
}

// -------- sim via MFMA + fused softmax; inv-norms computed inline from sumsq --------
__global__ __launch_bounds__(512, 1) void sim_mfma_kernel(const unsigned short* __restrict__ fqT,
                                                          const unsigned short* __restrict__ fkT,
                                                          const float* __restrict__ qss,
                                                          const float* __restrict__ kss,
                                                          const int* __restrict__ idx,
                                                          unsigned short* __restrict__ prb) {
  __shared__ float Sbuf[96 * 289];  // 110976 B; As @0 (6KB), Bs @6144 (18KB) alias
  unsigned short* As = (unsigned short*)Sbuf;
  unsigned short* Bs = (unsigned short*)((char*)Sbuf + 6144);
  float (*S)[289] = (float(*)[289])Sbuf;
  int t    = threadIdx.x;
  int lane = t & 63;
  int wid  = t >> 6;
  int l15  = lane & 15, kg = lane >> 4;
  int wm   = wid & 1, wn = wid >> 1;  // 2M x 4N
  int q0   = blockIdx.x * 96;
  int b    = blockIdx.y;
  int tb   = idx[b];
  const unsigned short* fqb = fqT + ((size_t)b * kHW + q0) * kCQ;
  const unsigned short* fkb = fkT + (size_t)tb * kHW * kCQ;

  int aIdx[3];
#pragma unroll
  for (int fm = 0; fm < 3; ++fm) {
    int r = wm * 48 + fm * 16 + l15;
    aIdx[fm] = r * 32 + (kg ^ ((r ^ (r >> 2)) & 3)) * 8;
  }
  int nfn = (wn < 2) ? 5 : 4;
  int fnb = (wn < 2) ? wn * 5 : 10 + (wn - 2) * 4;
  int bIdx[5];
#pragma unroll
  for (int fi = 0; fi < 5; ++fi) {
    int kr = (fnb + fi) * 16 + l15;
    if (kr > 287) kr = 287;
    bIdx[fi] = kr * 32 + (kg ^ ((kr ^ (kr >> 2)) & 3)) * 8;
  }

  f32x4 acc[3][5];
#pragma unroll
  for (int fm = 0; fm < 3; ++fm)
#pragma unroll
    for (int fi = 0; fi < 5; ++fi) acc[fm][fi] = (f32x4){0.f, 0.f, 0.f, 0.f};

#pragma unroll 1
  for (int chunk = 0; chunk < 16; ++chunk) {
    int c0 = chunk * 32;
    __syncthreads();
    if (t < 384) {
      int ar = t >> 2, as = t & 3;
      ushort8 v = *(const ushort8*)(fqb + (size_t)ar * kCQ + c0 + as * 8);
      int slot = as ^ ((ar ^ (ar >> 2)) & 3);
      *(ushort8*)(As + ar * 32 + slot * 8) = v;
    }
#pragma unroll
    for (int i = 0; i < 3; ++i) {
      int item = i * 512 + t;
      if (item < 1152) {
        int kr = item >> 2, ks = item & 3;
        ushort8 v = *(const ushort8*)(fkb + (size_t)kr * kCQ + c0 + ks * 8);
        int slot = ks ^ ((kr ^ (kr >> 2)) & 3);
        *(ushort8*)(Bs + kr * 32 + slot * 8) = v;
      }
    }
    __syncthreads();
    bf16x8 a[3];
#pragma unroll
    for (int fm = 0; fm < 3; ++fm) a[fm] = *(const bf16x8*)(As + aIdx[fm]);
#pragma unroll
    for (int fi = 0; fi < 5; ++fi) {
      if (fi >= nfn) continue;
      bf16x8 bb = *(const bf16x8*)(Bs + bIdx[fi]);
#pragma unroll
      for (int fm = 0; fm < 3; ++fm)
        acc[fm][fi] = __builtin_amdgcn_mfma_f32_16x16x32_bf16(a[fm], bb, acc[fm][fi], 0, 0, 0);
    }
  }
  __syncthreads();  // all frag reads done before S overwrites As/Bs

  // inv-norms for this thread's rows/cols
  float kinvv[5];
#pragma unroll
  for (int fi = 0; fi < 5; ++fi) {
    int col = (fnb + fi) * 16 + l15;
    if (col > 287) col = 287;
    kinvv[fi] = 1.f / fmaxf(sqrtf(kss[tb * kHW + col]), 1e-12f);
  }
  // write S scaled: row q = wm*48+fm*16+kg*4+reg, col k = (fnb+fi)*16+l15
#pragma unroll
  for (int fm = 0; fm < 3; ++fm)
#pragma unroll
    for (int reg = 0; reg < 4; ++reg) {
      int row = wm * 48 + fm * 16 + kg * 4 + reg;
      float qi = kTemp / fmaxf(sqrtf(qss[b * kHW + q0 + row]), 1e-12f);
#pragma unroll
      for (int fi = 0; fi < 5; ++fi) {
        if (fi >= nfn) continue;
        S[row][(fnb + fi) * 16 + l15] = qi * kinvv[fi] * acc[fm][fi][reg];
      }
    }
  __syncthreads();

  // row softmax: wave w handles rows q = w, w+8, ...
  int l = lane;
  for (int q = wid; q < 96; q += 8) {
    float v[5];
    float m = -3.4e38f;
#pragma unroll
    for (int j = 0; j < 5; ++j) {
      int k = l + 64 * j;
      v[j] = (k < kHW) ? S[q][k] : -3.4e38f;
      m = fmaxf(m, v[j]);
    }
    for (int off = 32; off; off >>= 1) m = fmaxf(m, __shfl_xor(m, off));
    float e[5];
    float s = 0.f;
#pragma unroll
    for (int j = 0; j < 5; ++j) {
      int k = l + 64 * j;
      e[j] = (k < kHW) ? __expf(v[j] - m) : 0.f;
      s += e[j];
    }
    for (int off = 32; off; off >>= 1) s += __shfl_xor(s, off);
    float invs = 1.f / s;
    unsigned short* row = prb + ((size_t)b * kHW + q0 + q) * kHW;
#pragma unroll
    for (int j = 0; j < 5; ++j) {
      int k = l + 64 * j;
      if (k < kHW) row[k] = f2bf(e[j] * invs);
    }
  }
}

// -------- comask (reads bf16 pr) --------
__global__ __launch_bounds__(320) void comask_kernel(const unsigned short* __restrict__ prb,
                                                     const float* __restrict__ mask,
                                                     const int* __restrict__ idx,
                                                     float* __restrict__ comask) {
  int b = blockIdx.x;
  int t = threadIdx.x;
  int tb = idx[b];
  __shared__ float mt[kHW];
  __shared__ float cm[kHW];
  __shared__ float red[320];
  if (t < kHW) mt[t] = mask[tb * kHW + t];
  __syncthreads();
  int wv = t >> 6, l = t & 63;
  for (int q = wv; q < kHW; q += 5) {
    const unsigned short* prow = prb + ((size_t)b * kHW + q) * kHW;
    float s = 0.f;
    for (int k = l; k < kHW; k += 64) s += bf2f(prow[k]) * mt[k];
    for (int off = 32; off; off >>= 1) s += __shfl_xor(s, off);
    if (l == 0) cm[q] = mask[b * kHW + q] * s;
  }
  __syncthreads();
  float v = (t < kHW) ? cm[t] : 0.f;
  red[t] = (t < kHW) ? v : 3.4e38f;
  __syncthreads();
  float mn;
  {
    float m = 3.4e38f;
    if (t < 64) {
      for (int i = t; i < 320; i += 64) m = fminf(m, red[i]);
      for (int off = 32; off; off >>= 1) m = fminf(m, __shfl_xor(m, off));
    }
    __syncthreads();
    if (t == 0) red[0] = m;
    __syncthreads();
    mn = red[0];
    __syncthreads();
  }
  red[t] = (t < kHW) ? v : -3.4e38f;
  __syncthreads();
  float mx;
  {
    float m = -3.4e38f;
    if (t < 64) {
      for (int i = t; i < 320; i += 64) m = fmaxf(m, red[i]);
      for (int off = 32; off; off >>= 1) m = fmaxf(m, __shfl_xor(m, off));
    }
    __syncthreads();
    if (t == 0) red[0] = m;
    __syncthreads();
    mx = red[0];
  }
  if (t < kHW) comask[b * kHW + t] = (v - mn) / ((mx - mn) + 1e-12f);
}

// -------- triplet loss --------
__global__ __launch_bounds__(256) void loss_kernel(const float* __restrict__ dap,
                                                   const float* __restrict__ dan,
                                                   const float* __restrict__ comask,
                                                   float* __restrict__ out) {
  int t = threadIdx.x;
  float s = 0.f;
  for (int i = t; i < kB * kHW; i += 256) {
    float da = sqrtf(dap[i]);
    float db = sqrtf(dan[i]);
    float tr = fmaxf(da - db + 0.3f, 0.f);
    s += comask[i] * tr;
  }
  for (int off = 32; off; off >>= 1) s += __shfl_xor(s, off);
  __shared__ float sh[4];
  if ((t & 63) == 0) sh[t >> 6] = s;
  __syncthreads();
  if (t == 0)
    out[(size_t)kB * kC * kHW] = (sh[0] + sh[1] + sh[2] + sh[3]) * (1.f / (float)(kB * kHW));
}

extern "C" void kernel_launch(void* const* d_in, const int* in_sizes, int n_in,
                              void* d_out, int out_size, void* d_ws, size_t ws_size,
                              hipStream_t stream) {
  const float* fv = (const float*)d_in[0];
  const float* ft = (const float*)d_in[1];
  const float* qw = (const float*)d_in[4];
  const float* qb = (const float*)d_in[5];
  const float* kw = (const float*)d_in[6];
  const float* kb = (const float*)d_in[7];
  const int* pos_idx = (const int*)d_in[8];
  const int* neg_idx = (const int*)d_in[9];
  float* out = (float*)d_out;

  // ws layout: region1 (37.75M): fqT+fkT bf16 | region2 (37.75M): prb bf16 (10.6M)
  //            region3 (37.75M): part -> wtq|wtk | small: maskb,qss,kss,comask,dap,dan
  constexpr size_t kFQ = (size_t)kB * kCQ * kHW;            // 9,437,184
  float* ws   = (float*)d_ws;
  unsigned short* fqT = (unsigned short*)ws;                // region1
  unsigned short* fkT = fqT + (size_t)kB * kHW * kCQ;
  unsigned short* prb = (unsigned short*)(ws + kFQ);        // region2
  unsigned short* wtq = (unsigned short*)(ws + 2 * kFQ);    // region3
  unsigned short* wtk = wtq + (size_t)9 * kCQ * kC;
  float* part = (float*)wtq;                                // alias, dead before prep_w
  float* maskb   = (float*)(wtk + (size_t)9 * kCQ * kC);
  float* qss     = maskb + kB * kHW;
  float* kss     = qss + kB * kHW;
  float* comaskb = kss + kB * kHW;
  float* dap     = comaskb + kB * kHW;
  float* dan     = dap + kB * kHW;
  if (ws_size < (size_t)113688576) return;

  // zero qss,kss,comask,dap,dan (contiguous 5 regions)
  zero_kernel<<<dim3((5 * kB * kHW + 255) / 256), 256, 0, stream>>>(qss, 5 * kB * kHW);
  mask_part_kernel<<<dim3(kB, 4), 320, 0, stream>>>(fv, ft, part);
  mask_fin_kernel<<<dim3(kB), 320, 0, stream>>>(part, maskb);
  prep_w_kernel<<<dim3(kCQ, 2), 256, 0, stream>>>(qw, kw, wtq, wtk);
  conv_fused_kernel<<<dim3(256), 512, 0, stream>>>(wtq, wtk, qb, kb, fv, ft,
                                                   fqT, fkT, qss, kss);

  // positive branch
  sim_mfma_kernel<<<dim3(3, kB), 512, 0, stream>>>(fqT, fkT, qss, kss, pos_idx, prb);
  comask_kernel<<<dim3(kB), 320, 0, stream>>>(prb, maskb, pos_idx, comaskb);
  warp_mfma_kernel<<<dim3(16, kB), 512, 0, stream>>>(fv, ft, prb, maskb, pos_idx, out, dap, 1);

  // negative branch
  sim_mfma_kernel<<<dim3(3, kB), 512, 0, stream>>>(fqT, fkT, qss, kss, neg_idx, prb);
  warp_mfma_kernel<<<dim3(16, kB), 512, 0, stream>>>(fv, ft, prb, maskb, neg_idx, out, dan, 0);

  loss_kernel<<<dim3(1), 256, 0, stream>>>(dap, dan, comaskb, out);
}

// Round 17
// 1181.595 us; speedup vs baseline: 5.6143x; 5.6143x over previous
//
#include <hip/hip_runtime.h>
#include <cstdint>
#include <cstddef>

// CMAlign forward. R17: R16 with the acc->scratch demotion fixed (epilogue cv loop
// fully unrolled -> all acc indices compile-time; rule #20). Conv main loop = R11.
// Shapes: B=64, C=2048, Cq=512, H=24, W=12, HW=288.

namespace {
constexpr int kB    = 64;
constexpr int kHalf = 32;
constexpr int kC    = 2048;
constexpr int kCQ   = 512;
constexpr int kH    = 24;
constexpr int kW    = 12;
constexpr int kHW   = 288;
constexpr float kTemp = 50.0f;
constexpr int kXPlane = 366;  // 16B cells; 5856 B = 96 mod 128 -> kg quadrant offsets
}

typedef __attribute__((ext_vector_type(8))) __bf16 bf16x8;
typedef __attribute__((ext_vector_type(4))) float f32x4;
typedef __attribute__((ext_vector_type(8))) unsigned short ushort8;

__device__ __forceinline__ const float* feat_base(const float* fv, const float* ft, int b) {
  return (b < kHalf) ? (fv + (size_t)b * kC * kHW)
                     : (ft + (size_t)(b - kHalf) * kC * kHW);
}

__device__ __forceinline__ unsigned short f2bf(float f) {
  union { float f; unsigned u; } c; c.f = f;
  unsigned u = c.u;
  unsigned r = (u + 0x7FFFu + ((u >> 16) & 1u)) >> 16;  // RNE
  return (unsigned short)r;
}

__device__ __forceinline__ float bf2f(unsigned short h) {
  union { unsigned u; float f; } c; c.u = ((unsigned)h) << 16;
  return c.f;
}

__device__ __forceinline__ void gload_lds16(const void* g, void* l) {
  __builtin_amdgcn_global_load_lds(
      (const __attribute__((address_space(1))) unsigned int*)g,
      (__attribute__((address_space(3))) unsigned int*)l, 16, 0, 0);
}

__global__ void zero_kernel(float* __restrict__ p, int n) {
  int i = blockIdx.x * 256 + threadIdx.x;
  if (i < n) p[i] = 0.f;
}

// -------- weight prep: w[oc][ic][3][3] fp32 -> MFMA-image wt2 --------
__global__ __launch_bounds__(256) void prep_w_kernel(const float* __restrict__ qw,
                                                     const float* __restrict__ kw,
                                                     unsigned short* __restrict__ wtq,
                                                     unsigned short* __restrict__ wtk) {
  int oc = blockIdx.x;
  int z  = blockIdx.y;
  const float* w = (z ? kw : qw) + (size_t)oc * (kC * 9);
  unsigned short* wt = z ? wtk : wtq;
  __shared__ unsigned short lw[kC * 9];  // [ic][tap]
  int t = threadIdx.x;
#pragma unroll
  for (int it = 0; it < 18; ++it) {
    int i4 = (it * 256 + t) * 4;
    float4 v = *(const float4*)(w + i4);
    lw[i4 + 0] = f2bf(v.x);
    lw[i4 + 1] = f2bf(v.y);
    lw[i4 + 2] = f2bf(v.z);
    lw[i4 + 3] = f2bf(v.w);
  }
  __syncthreads();
  for (int item = t; item < 9 * 256; item += 256) {
    int tap = item >> 8;
    int icb = item & 255;
    ushort8 pk;
#pragma unroll
    for (int j = 0; j < 8; ++j) pk[j] = lw[(icb * 8 + j) * 9 + tap];
    size_t dst16 = (((size_t)(icb >> 2) * 9 + tap) * 32 + (oc >> 4)) * 64
                   + (oc & 15) + (icb & 3) * 16;
    *(ushort8*)(wt + dst16 * 8) = pk;
  }
}

// -------- FUSED MFMA conv: main loop = R11; epilogue -> bf16 transposed + sumsq --------
__global__ __launch_bounds__(512, 1) void conv_fused_kernel(const unsigned short* __restrict__ wtq,
                                                            const unsigned short* __restrict__ wtk,
                                                            const float* __restrict__ qb,
                                                            const float* __restrict__ kb,
                                                            const float* __restrict__ fv,
                                                            const float* __restrict__ ft,
                                                            unsigned short* __restrict__ fqT,
                                                            unsigned short* __restrict__ fkT,
                                                            float* __restrict__ qss,
                                                            float* __restrict__ kss) {
  __shared__ unsigned short Wbuf[2 * 6 * 4096];   // 98304 B (epilogue reuses as Ep[288][136])
  __shared__ unsigned short Xs[4 * kXPlane * 8];  // 23424 B
  int t    = threadIdx.x;
  int lane = t & 63;
  int wid  = t >> 6;
  int l15  = lane & 15, kg = lane >> 4;
  int wm   = wid & 1, wn = wid >> 1;  // 2M x 4N
  int n    = blockIdx.x;
  int xcd  = n & 7;
  int oc0  = (xcd >> 1) * 128;
  int b    = ((xcd & 1) << 5) + (n >> 3);
  int f0   = oc0 >> 4;
  const float* fb = feat_base(fv, ft, b);
  const char* wtqB = (const char*)wtq;
  const char* wtkB = (const char*)wtk;

  int  xoff[3];
  bool xvalid[3], xhas[3];
#pragma unroll
  for (int i = 0; i < 3; ++i) {
    int item = i * 512 + t;
    xhas[i] = item < 4 * kXPlane;
    int xkg = item / kXPlane;
    int hp  = item - xkg * kXPlane;
    int hy = hp / 14, hx = hp - hy * 14;
    int y = hy - 1, x = hx - 1;
    bool v = xhas[i] && hp < 364 && (y >= 0 && y < kH && x >= 0 && x < kW);
    xvalid[i] = v;
    xoff[i] = v ? (xkg * 8) * kHW + y * kW + x : 0;
  }

  int aAddr[4];
#pragma unroll
  for (int fm = 0; fm < 4; ++fm)
    aAddr[fm] = (((wm * 4 + fm) * 64) + lane) * 16;
  int nfn = (wn < 2) ? 5 : 4;
  int fnb = (wn < 2) ? wn * 5 : 10 + (wn - 2) * 4;
  int bAddr[5];
#pragma unroll
  for (int fi = 0; fi < 5; ++fi) {
    int p = (fnb + fi) * 16 + l15;
    if (p > 287) p = 287;
    int y = p / kW, x = p - y * kW;
    bAddr[fi] = kg * (kXPlane * 16) + ((y + 1) * 14 + (x + 1)) * 16;
  }

  f32x4 acc[2][4][5];
#pragma unroll
  for (int cv = 0; cv < 2; ++cv)
#pragma unroll
    for (int fm = 0; fm < 4; ++fm)
#pragma unroll
      for (int fi = 0; fi < 5; ++fi) acc[cv][fm][fi] = (f32x4){0.f, 0.f, 0.f, 0.f};

  char* WsB = (char*)Wbuf;
  char* XsB = (char*)Xs;
  int wavebase = t & ~63;

#pragma unroll
  for (int i = 0; i < 3; ++i) {
    if (xhas[i] && !xvalid[i]) {
      ushort8 pk;
#pragma unroll
      for (int j = 0; j < 8; ++j) pk[j] = 0;
      *(ushort8*)(XsB + (size_t)(i * 512 + t) * 16) = pk;
    }
  }
#pragma unroll
  for (int r = 0; r < 3; ++r) {
    size_t g16 = ((size_t)r * 32 + f0 + wid) * 64 + lane;
    gload_lds16(wtqB + g16 * 16, WsB + (size_t)(r * 2 + 0) * 8192 + wavebase * 16);
    gload_lds16(wtkB + g16 * 16, WsB + (size_t)(r * 2 + 1) * 8192 + wavebase * 16);
  }

  int buf = 0;
#pragma unroll 1
  for (int chunk = 0; chunk < 64; ++chunk) {
    int ic0 = chunk * 32;
    {
      float xv[3][8];
#pragma unroll
      for (int i = 0; i < 3; ++i)
        if (xvalid[i]) {
          const float* s = fb + (size_t)ic0 * kHW + xoff[i];
#pragma unroll
          for (int j = 0; j < 8; ++j) xv[i][j] = s[(size_t)j * kHW];
        }
#pragma unroll
      for (int i = 0; i < 3; ++i) {
        if (!xvalid[i]) continue;
        ushort8 pk;
#pragma unroll
        for (int j = 0; j < 8; ++j) pk[j] = f2bf(xv[i][j]);
        *(ushort8*)(XsB + (size_t)(i * 512 + t) * 16) = pk;
      }
    }
    __syncthreads();

#pragma unroll 1
    for (int g = 0; g < 3; ++g) {
      bool hn = (g < 2) || (chunk < 63);
      if (hn) {
        int nchunk = (g < 2) ? chunk : chunk + 1;
        int ng     = (g < 2) ? g + 1 : 0;
#pragma unroll
        for (int r = 0; r < 3; ++r) {
          size_t g16 = ((size_t)(nchunk * 9 + ng * 3 + r) * 32 + f0 + wid) * 64 + lane;
          gload_lds16(wtqB + g16 * 16,
                      WsB + (size_t)((buf ^ 1) * 6 + r * 2 + 0) * 8192 + wavebase * 16);
          gload_lds16(wtkB + g16 * 16,
                      WsB + (size_t)((buf ^ 1) * 6 + r * 2 + 1) * 8192 + wavebase * 16);
        }
      }
#pragma unroll
      for (int r = 0; r < 3; ++r) {
        int tap = g * 3 + r;
        int d16 = ((tap / 3 - 1) * 14 + (tap % 3 - 1)) * 16;
        bf16x8 af[2][4];
#pragma unroll
        for (int cv = 0; cv < 2; ++cv)
#pragma unroll
          for (int fm = 0; fm < 4; ++fm)
            af[cv][fm] = *(const bf16x8*)(WsB + (size_t)(buf * 6 + r * 2 + cv) * 8192 + aAddr[fm]);
#pragma unroll
        for (int fi = 0; fi < 5; ++fi) {
          if (fi >= nfn) continue;
          bf16x8 bb = *(const bf16x8*)(XsB + bAddr[fi] + d16);
#pragma unroll
          for (int cv = 0; cv < 2; ++cv)
#pragma unroll
            for (int fm = 0; fm < 4; ++fm)
              acc[cv][fm][fi] =
                  __builtin_amdgcn_mfma_f32_16x16x32_bf16(af[cv][fm], bb, acc[cv][fm][fi], 0, 0, 0);
        }
      }
      __syncthreads();
      buf ^= 1;
    }
  }

  // ---- epilogue: per cv (FULLY UNROLLED - compile-time acc indices), stage bf16
  //      tile in Ep[288][136], sumsq atomics, coalesced transposed store ----
  unsigned short* Ep = Wbuf;
#pragma unroll
  for (int cv = 0; cv < 2; ++cv) {
    const float* bias = cv ? kb : qb;
    float* ssq = cv ? kss : qss;
#pragma unroll
    for (int fi = 0; fi < 5; ++fi) {
      if (fi >= nfn) continue;
      int p = (fnb + fi) * 16 + l15;
      float ps = 0.f;
#pragma unroll
      for (int fm = 0; fm < 4; ++fm)
#pragma unroll
        for (int reg = 0; reg < 4; ++reg) {
          int ocl = wm * 64 + fm * 16 + kg * 4 + reg;
          float v = acc[cv][fm][fi][reg] + bias[oc0 + ocl];
          ps = fmaf(v, v, ps);
          Ep[p * 136 + ocl] = f2bf(v);
        }
      ps += __shfl_xor(ps, 16);
      ps += __shfl_xor(ps, 32);
      if (kg == 0) atomicAdd(ssq + b * kHW + p, ps);
    }
    __syncthreads();
    unsigned short* dstT = (cv ? fkT : fqT) + (size_t)b * kHW * kCQ + oc0;
#pragma unroll
    for (int it = 0; it < 9; ++it) {
      int item = it * 512 + t;
      int p = item >> 4, j = item & 15;
      *(ushort8*)(dstT + (size_t)p * kCQ + j * 8) =
          *(const ushort8*)(Ep + p * 136 + j * 8);
    }
    __syncthreads();
  }
}

// -------- warp GEMM via MFMA (unchanged) --------
__global__ __launch_bounds__(512) void warp_mfma_kernel(const float* __restrict__ fv,
                                                        const float* __restrict__ ft,
                                                        const unsigned short* __restrict__ prb,
                                                        const float* __restrict__ maskp,
                                                        const int* __restrict__ idx,
                                                        float* __restrict__ outp,
                                                        float* __restrict__ dsq,
                                                        int write_out) {
  __shared__ unsigned short AsHi[128 * 32];
  __shared__ unsigned short AsLo[128 * 32];
  __shared__ unsigned short Bs[288 * 32];
  int t    = threadIdx.x;
  int lane = t & 63;
  int wid  = t >> 6;
  int l15  = lane & 15, kg = lane >> 4;
  int wm   = wid >> 1, wn = wid & 1;
  int c0   = blockIdx.x * 128;
  int b    = blockIdx.y;
  int tb   = idx[b];
  const float* tgt = feat_base(fv, ft, tb);
  const float* fb  = feat_base(fv, ft, b);

  int ar = t >> 2, as = t & 3;
  int aslot = as ^ ((ar ^ (ar >> 2)) & 3);
  unsigned short* aDstHi = AsHi + ar * 32 + aslot * 8;
  unsigned short* aDstLo = AsLo + ar * 32 + aslot * 8;

  int aIdx[2];
#pragma unroll
  for (int fm = 0; fm < 2; ++fm) {
    int r = wm * 32 + fm * 16 + l15;
    aIdx[fm] = r * 32 + (kg ^ ((r ^ (r >> 2)) & 3)) * 8;
  }
  int bIdx[9];
#pragma unroll
  for (int fn = 0; fn < 9; ++fn) {
    int q = wn * 144 + fn * 16 + l15;
    bIdx[fn] = q * 32 + (kg ^ ((q ^ (q >> 2)) & 3)) * 8;
  }

  f32x4 acc[2][9];
#pragma unroll
  for (int fm = 0; fm < 2; ++fm)
#pragma unroll
    for (int fn = 0; fn < 9; ++fn) acc[fm][fn] = (f32x4){0.f, 0.f, 0.f, 0.f};

#pragma unroll 1
  for (int chunk = 0; chunk < 9; ++chunk) {
    int k0 = chunk * 32;
    __syncthreads();
    {
      const float* s = tgt + (size_t)(c0 + ar) * kHW + k0 + as * 8;
      float4 v0 = *(const float4*)(s);
      float4 v1 = *(const float4*)(s + 4);
      float xs[8] = {v0.x, v0.y, v0.z, v0.w, v1.x, v1.y, v1.z, v1.w};
      ushort8 hi, lo;
#pragma unroll
      for (int j = 0; j < 8; ++j) {
        unsigned short h = f2bf(xs[j]);
        hi[j] = h;
        lo[j] = f2bf(xs[j] - bf2f(h));
      }
      *(ushort8*)aDstHi = hi;
      *(ushort8*)aDstLo = lo;
    }
#pragma unroll
    for (int i = 0; i < 3; ++i) {
      int item = i * 512 + t;
      if (item < 1152) {
        int q = item >> 2, s = item & 3;
        ushort8 v = *(const ushort8*)(prb + ((size_t)b * kHW + q) * kHW + k0 + s * 8);
        *(ushort8*)(Bs + q * 32 + (s ^ ((q ^ (q >> 2)) & 3)) * 8) = v;
      }
    }
    __syncthreads();
    bf16x8 ah0 = *(const bf16x8*)(AsHi + aIdx[0]);
    bf16x8 al0 = *(const bf16x8*)(AsLo + aIdx[0]);
    bf16x8 ah1 = *(const bf16x8*)(AsHi + aIdx[1]);
    bf16x8 al1 = *(const bf16x8*)(AsLo + aIdx[1]);
#pragma unroll
    for (int fn = 0; fn < 9; ++fn) {
      bf16x8 bb = *(const bf16x8*)(Bs + bIdx[fn]);
      acc[0][fn] = __builtin_amdgcn_mfma_f32_16x16x32_bf16(ah0, bb, acc[0][fn], 0, 0, 0);
      acc[0][fn] = __builtin_amdgcn_mfma_f32_16x16x32_bf16(al0, bb, acc[0][fn], 0, 0, 0);
      acc[1][fn] = __builtin_amdgcn_mfma_f32_16x16x32_bf16(ah1, bb, acc[1][fn], 0, 0, 0);
      acc[1][fn] = __builtin_amdgcn_mfma_f32_16x16x32_bf16(al1, bb, acc[1][fn], 0, 0, 0);
    }
  }

#pragma unroll
  for (int fn = 0; fn < 9; ++fn) {
    int q = wn * 144 + fn * 16 + l15;
    float mj = maskp[b * kHW + q];
    float psum = 0.f;
#pragma unroll
    for (int fm = 0; fm < 2; ++fm) {
#pragma unroll
      for (int reg = 0; reg < 4; ++reg) {
        int c = c0 + wm * 32 + fm * 16 + kg * 4 + reg;
        float fvv = fb[(size_t)c * kHW + q];
        float Wv  = acc[fm][fn][reg];
        float d   = mj * (fvv - Wv) + 1e-6f;
        psum      = fmaf(d, d, psum);
        if (write_out)
          outp[((size_t)b * kC + c) * kHW + q] = mj * Wv + (1.f - mj) * fvv;
      }
    }
    psum += __shfl_xor(psum, 16);
    psum += __shfl_xor(psum, 32);
    if (lane < 16) atomicAdd(&dsq[b * kHW + q], psum);
  }
}

// -------- mask pass 1: partial channel sum-of-squares over 512-c slices --------
__global__ __launch_bounds__(320) void mask_part_kernel(const float* __restrict__ fv,
                                                        const float* __restrict__ ft,
                                                        float* __restrict__ part) {
  int b = blockIdx.x;
  int s = blockIdx.y;
  int t = threadIdx.x;
  if (t >= kHW) return;
  const float* fb = feat_base(fv, ft, b) + (size_t)(s * 512) * kHW;
  float sum = 0.f;
  for (int c = 0; c < 512; ++c) { float v = fb[(size_t)c * kHW + t]; sum += v * v; }
  part[((size_t)b * 4 + s) * kHW + t] = sum;
}

// -------- mask pass 2: finalize sqrt + per-sample min-max normalize --------
__global__ __launch_bounds__(320) void mask_fin_kernel(const float* __restrict__ part,
                                                       float* __restrict__ mask) {
  int b = blockIdx.x;
  int t = threadIdx.x;
  float n = 0.f;
  if (t < kHW) {
    const float* pb = part + (size_t)b * 4 * kHW;
    n = sqrtf(pb[t] + pb[kHW + t] + pb[2 * kHW + t] + pb[3 * kHW + t]);
  }
  __shared__ float sh[320];
  sh[t] = (t < kHW) ? n : 3.4e38f;
  __syncthreads();
  float mn;
  {
    float m = 3.4e38f;
    if (t < 64) {
      for (int i = t; i < 320; i += 64) m = fminf(m, sh[i]);
      for (int off = 32; off; off >>= 1) m = fminf(m, __shfl_xor(m, off));
    }
    __syncthreads();
    if (t == 0) sh[0] = m;
    __syncthreads();
    mn = sh[0];
    __syncthreads();
  }
  sh[t] = (t < kHW) ? n : -3.4e38f;
  __syncthreads();
  float mx;
  {
    float m = -3.4e38f;
    if (t < 64) {
      for (int i = t; i < 320; i += 64) m = fmaxf(m, sh[i]);
      for (int off = 32; off; off >>= 1) m = fmaxf(m, __shfl_xor(m, off));
    }
    __syncthreads();
    if (t == 0) sh[0] = m;
    __syncthreads();
    mx = sh[0];
  }
  if (t < kHW) mask[b * kHW + t] = (n - mn) / ((mx - mn) + 1e-12f);
}

// -------- sim via MFMA + fused softmax; inv-norms computed inline from sumsq --------
__global__ __launch_bounds__(512, 1) void sim_mfma_kernel(const unsigned short* __restrict__ fqT,
                                                          const unsigned short* __restrict__ fkT,
                                                          const float* __restrict__ qss,
                                                          const float* __restrict__ kss,
                                                          const int* __restrict__ idx,
                                                          unsigned short* __restrict__ prb) {
  __shared__ float Sbuf[96 * 289];  // 110976 B; As @0 (6KB), Bs @6144 (18KB) alias
  unsigned short* As = (unsigned short*)Sbuf;
  unsigned short* Bs = (unsigned short*)((char*)Sbuf + 6144);
  float (*S)[289] = (float(*)[289])Sbuf;
  int t    = threadIdx.x;
  int lane = t & 63;
  int wid  = t >> 6;
  int l15  = lane & 15, kg = lane >> 4;
  int wm   = wid & 1, wn = wid >> 1;  // 2M x 4N
  int q0   = blockIdx.x * 96;
  int b    = blockIdx.y;
  int tb   = idx[b];
  const unsigned short* fqb = fqT + ((size_t)b * kHW + q0) * kCQ;
  const unsigned short* fkb = fkT + (size_t)tb * kHW * kCQ;

  int aIdx[3];
#pragma unroll
  for (int fm = 0; fm < 3; ++fm) {
    int r = wm * 48 + fm * 16 + l15;
    aIdx[fm] = r * 32 + (kg ^ ((r ^ (r >> 2)) & 3)) * 8;
  }
  int nfn = (wn < 2) ? 5 : 4;
  int fnb = (wn < 2) ? wn * 5 : 10 + (wn - 2) * 4;
  int bIdx[5];
#pragma unroll
  for (int fi = 0; fi < 5; ++fi) {
    int kr = (fnb + fi) * 16 + l15;
    if (kr > 287) kr = 287;
    bIdx[fi] = kr * 32 + (kg ^ ((kr ^ (kr >> 2)) & 3)) * 8;
  }

  f32x4 acc[3][5];
#pragma unroll
  for (int fm = 0; fm < 3; ++fm)
#pragma unroll
    for (int fi = 0; fi < 5; ++fi) acc[fm][fi] = (f32x4){0.f, 0.f, 0.f, 0.f};

#pragma unroll 1
  for (int chunk = 0; chunk < 16; ++chunk) {
    int c0 = chunk * 32;
    __syncthreads();
    if (t < 384) {
      int ar = t >> 2, as = t & 3;
      ushort8 v = *(const ushort8*)(fqb + (size_t)ar * kCQ + c0 + as * 8);
      int slot = as ^ ((ar ^ (ar >> 2)) & 3);
      *(ushort8*)(As + ar * 32 + slot * 8) = v;
    }
#pragma unroll
    for (int i = 0; i < 3; ++i) {
      int item = i * 512 + t;
      if (item < 1152) {
        int kr = item >> 2, ks = item & 3;
        ushort8 v = *(const ushort8*)(fkb + (size_t)kr * kCQ + c0 + ks * 8);
        int slot = ks ^ ((kr ^ (kr >> 2)) & 3);
        *(ushort8*)(Bs + kr * 32 + slot * 8) = v;
      }
    }
    __syncthreads();
    bf16x8 a[3];
#pragma unroll
    for (int fm = 0; fm < 3; ++fm) a[fm] = *(const bf16x8*)(As + aIdx[fm]);
#pragma unroll
    for (int fi = 0; fi < 5; ++fi) {
      if (fi >= nfn) continue;
      bf16x8 bb = *(const bf16x8*)(Bs + bIdx[fi]);
#pragma unroll
      for (int fm = 0; fm < 3; ++fm)
        acc[fm][fi] = __builtin_amdgcn_mfma_f32_16x16x32_bf16(a[fm], bb, acc[fm][fi], 0, 0, 0);
    }
  }
  __syncthreads();  // all frag reads done before S overwrites As/Bs

  float kinvv[5];
#pragma unroll
  for (int fi = 0; fi < 5; ++fi) {
    int col = (fnb + fi) * 16 + l15;
    if (col > 287) col = 287;
    kinvv[fi] = 1.f / fmaxf(sqrtf(kss[tb * kHW + col]), 1e-12f);
  }
#pragma unroll
  for (int fm = 0; fm < 3; ++fm)
#pragma unroll
    for (int reg = 0; reg < 4; ++reg) {
      int row = wm * 48 + fm * 16 + kg * 4 + reg;
      float qi = kTemp / fmaxf(sqrtf(qss[b * kHW + q0 + row]), 1e-12f);
#pragma unroll
      for (int fi = 0; fi < 5; ++fi) {
        if (fi >= nfn) continue;
        S[row][(fnb + fi) * 16 + l15] = qi * kinvv[fi] * acc[fm][fi][reg];
      }
    }
  __syncthreads();

  int l = lane;
  for (int q = wid; q < 96; q += 8) {
    float v[5];
    float m = -3.4e38f;
#pragma unroll
    for (int j = 0; j < 5; ++j) {
      int k = l + 64 * j;
      v[j] = (k < kHW) ? S[q][k] : -3.4e38f;
      m = fmaxf(m, v[j]);
    }
    for (int off = 32; off; off >>= 1) m = fmaxf(m, __shfl_xor(m, off));
    float e[5];
    float s = 0.f;
#pragma unroll
    for (int j = 0; j < 5; ++j) {
      int k = l + 64 * j;
      e[j] = (k < kHW) ? __expf(v[j] - m) : 0.f;
      s += e[j];
    }
    for (int off = 32; off; off >>= 1) s += __shfl_xor(s, off);
    float invs = 1.f / s;
    unsigned short* row = prb + ((size_t)b * kHW + q0 + q) * kHW;
#pragma unroll
    for (int j = 0; j < 5; ++j) {
      int k = l + 64 * j;
      if (k < kHW) row[k] = f2bf(e[j] * invs);
    }
  }
}

// -------- comask (reads bf16 pr) --------
__global__ __launch_bounds__(320) void comask_kernel(const unsigned short* __restrict__ prb,
                                                     const float* __restrict__ mask,
                                                     const int* __restrict__ idx,
                                                     float* __restrict__ comask) {
  int b = blockIdx.x;
  int t = threadIdx.x;
  int tb = idx[b];
  __shared__ float mt[kHW];
  __shared__ float cm[kHW];
  __shared__ float red[320];
  if (t < kHW) mt[t] = mask[tb * kHW + t];
  __syncthreads();
  int wv = t >> 6, l = t & 63;
  for (int q = wv; q < kHW; q += 5) {
    const unsigned short* prow = prb + ((size_t)b * kHW + q) * kHW;
    float s = 0.f;
    for (int k = l; k < kHW; k += 64) s += bf2f(prow[k]) * mt[k];
    for (int off = 32; off; off >>= 1) s += __shfl_xor(s, off);
    if (l == 0) cm[q] = mask[b * kHW + q] * s;
  }
  __syncthreads();
  float v = (t < kHW) ? cm[t] : 0.f;
  red[t] = (t < kHW) ? v : 3.4e38f;
  __syncthreads();
  float mn;
  {
    float m = 3.4e38f;
    if (t < 64) {
      for (int i = t; i < 320; i += 64) m = fminf(m, red[i]);
      for (int off = 32; off; off >>= 1) m = fminf(m, __shfl_xor(m, off));
    }
    __syncthreads();
    if (t == 0) red[0] = m;
    __syncthreads();
    mn = red[0];
    __syncthreads();
  }
  red[t] = (t < kHW) ? v : -3.4e38f;
  __syncthreads();
  float mx;
  {
    float m = -3.4e38f;
    if (t < 64) {
      for (int i = t; i < 320; i += 64) m = fmaxf(m, red[i]);
      for (int off = 32; off; off >>= 1) m = fmaxf(m, __shfl_xor(m, off));
    }
    __syncthreads();
    if (t == 0) red[0] = m;
    __syncthreads();
    mx = red[0];
  }
  if (t < kHW) comask[b * kHW + t] = (v - mn) / ((mx - mn) + 1e-12f);
}

// -------- triplet loss --------
__global__ __launch_bounds__(256) void loss_kernel(const float* __restrict__ dap,
                                                   const float* __restrict__ dan,
                                                   const float* __restrict__ comask,
                                                   float* __restrict__ out) {
  int t = threadIdx.x;
  float s = 0.f;
  for (int i = t; i < kB * kHW; i += 256) {
    float da = sqrtf(dap[i]);
    float db = sqrtf(dan[i]);
    float tr = fmaxf(da - db + 0.3f, 0.f);
    s += comask[i] * tr;
  }
  for (int off = 32; off; off >>= 1) s += __shfl_xor(s, off);
  __shared__ float sh[4];
  if ((t & 63) == 0) sh[t >> 6] = s;
  __syncthreads();
  if (t == 0)
    out[(size_t)kB * kC * kHW] = (sh[0] + sh[1] + sh[2] + sh[3]) * (1.f / (float)(kB * kHW));
}

extern "C" void kernel_launch(void* const* d_in, const int* in_sizes, int n_in,
                              void* d_out, int out_size, void* d_ws, size_t ws_size,
                              hipStream_t stream) {
  const float* fv = (const float*)d_in[0];
  const float* ft = (const float*)d_in[1];
  const float* qw = (const float*)d_in[4];
  const float* qb = (const float*)d_in[5];
  const float* kw = (const float*)d_in[6];
  const float* kb = (const float*)d_in[7];
  const int* pos_idx = (const int*)d_in[8];
  const int* neg_idx = (const int*)d_in[9];
  float* out = (float*)d_out;

  constexpr size_t kFQ = (size_t)kB * kCQ * kHW;            // 9,437,184
  float* ws   = (float*)d_ws;
  unsigned short* fqT = (unsigned short*)ws;                // region1
  unsigned short* fkT = fqT + (size_t)kB * kHW * kCQ;
  unsigned short* prb = (unsigned short*)(ws + kFQ);        // region2
  unsigned short* wtq = (unsigned short*)(ws + 2 * kFQ);    // region3
  unsigned short* wtk = wtq + (size_t)9 * kCQ * kC;
  float* part = (float*)wtq;                                // alias, dead before prep_w
  float* maskb   = (float*)(wtk + (size_t)9 * kCQ * kC);
  float* qss     = maskb + kB * kHW;
  float* kss     = qss + kB * kHW;
  float* comaskb = kss + kB * kHW;
  float* dap     = comaskb + kB * kHW;
  float* dan     = dap + kB * kHW;
  if (ws_size < (size_t)113688576) return;

  zero_kernel<<<dim3((5 * kB * kHW + 255) / 256), 256, 0, stream>>>(qss, 5 * kB * kHW);
  mask_part_kernel<<<dim3(kB, 4), 320, 0, stream>>>(fv, ft, part);
  mask_fin_kernel<<<dim3(kB), 320, 0, stream>>>(part, maskb);
  prep_w_kernel<<<dim3(kCQ, 2), 256, 0, stream>>>(qw, kw, wtq, wtk);
  conv_fused_kernel<<<dim3(256), 512, 0, stream>>>(wtq, wtk, qb, kb, fv, ft,
                                                   fqT, fkT, qss, kss);

  // positive branch
  sim_mfma_kernel<<<dim3(3, kB), 512, 0, stream>>>(fqT, fkT, qss, kss, pos_idx, prb);
  comask_kernel<<<dim3(kB), 320, 0, stream>>>(prb, maskb, pos_idx, comaskb);
  warp_mfma_kernel<<<dim3(16, kB), 512, 0, stream>>>(fv, ft, prb, maskb, pos_idx, out, dap, 1);

  // negative branch
  sim_mfma_kernel<<<dim3(3, kB), 512, 0, stream>>>(fqT, fkT, qss, kss, neg_idx, prb);
  warp_mfma_kernel<<<dim3(16, kB), 512, 0, stream>>>(fv, ft, prb, maskb, neg_idx, out, dan, 0);

  loss_kernel<<<dim3(1), 256, 0, stream>>>(dap, dan, comaskb, out);
}

// Round 18
// 1163.780 us; speedup vs baseline: 5.7003x; 1.0153x over previous
//
#include <hip/hip_runtime.h>
#include <cstdint>
#include <cstddef>

// CMAlign forward. R18: R17 + branch-merged launches — one sim_mfma (z=2 branches,
// separate prb buffers) and one warp_mfma (z=2). 9 launches total.
// Conv = R17 (main loop R11 + bf16T/sumsq epilogue).
// Shapes: B=64, C=2048, Cq=512, H=24, W=12, HW=288.

namespace {
constexpr int kB    = 64;
constexpr int kHalf = 32;
constexpr int kC    = 2048;
constexpr int kCQ   = 512;
constexpr int kH    = 24;
constexpr int kW    = 12;
constexpr int kHW   = 288;
constexpr float kTemp = 50.0f;
constexpr int kXPlane = 366;  // 16B cells; 5856 B = 96 mod 128 -> kg quadrant offsets
}

typedef __attribute__((ext_vector_type(8))) __bf16 bf16x8;
typedef __attribute__((ext_vector_type(4))) float f32x4;
typedef __attribute__((ext_vector_type(8))) unsigned short ushort8;

__device__ __forceinline__ const float* feat_base(const float* fv, const float* ft, int b) {
  return (b < kHalf) ? (fv + (size_t)b * kC * kHW)
                     : (ft + (size_t)(b - kHalf) * kC * kHW);
}

__device__ __forceinline__ unsigned short f2bf(float f) {
  union { float f; unsigned u; } c; c.f = f;
  unsigned u = c.u;
  unsigned r = (u + 0x7FFFu + ((u >> 16) & 1u)) >> 16;  // RNE
  return (unsigned short)r;
}

__device__ __forceinline__ float bf2f(unsigned short h) {
  union { unsigned u; float f; } c; c.u = ((unsigned)h) << 16;
  return c.f;
}

__device__ __forceinline__ void gload_lds16(const void* g, void* l) {
  __builtin_amdgcn_global_load_lds(
      (const __attribute__((address_space(1))) unsigned int*)g,
      (__attribute__((address_space(3))) unsigned int*)l, 16, 0, 0);
}

__global__ void zero_kernel(float* __restrict__ p, int n) {
  int i = blockIdx.x * 256 + threadIdx.x;
  if (i < n) p[i] = 0.f;
}

// -------- weight prep: w[oc][ic][3][3] fp32 -> MFMA-image wt2 --------
__global__ __launch_bounds__(256) void prep_w_kernel(const float* __restrict__ qw,
                                                     const float* __restrict__ kw,
                                                     unsigned short* __restrict__ wtq,
                                                     unsigned short* __restrict__ wtk) {
  int oc = blockIdx.x;
  int z  = blockIdx.y;
  const float* w = (z ? kw : qw) + (size_t)oc * (kC * 9);
  unsigned short* wt = z ? wtk : wtq;
  __shared__ unsigned short lw[kC * 9];  // [ic][tap]
  int t = threadIdx.x;
#pragma unroll
  for (int it = 0; it < 18; ++it) {
    int i4 = (it * 256 + t) * 4;
    float4 v = *(const float4*)(w + i4);
    lw[i4 + 0] = f2bf(v.x);
    lw[i4 + 1] = f2bf(v.y);
    lw[i4 + 2] = f2bf(v.z);
    lw[i4 + 3] = f2bf(v.w);
  }
  __syncthreads();
  for (int item = t; item < 9 * 256; item += 256) {
    int tap = item >> 8;
    int icb = item & 255;
    ushort8 pk;
#pragma unroll
    for (int j = 0; j < 8; ++j) pk[j] = lw[(icb * 8 + j) * 9 + tap];
    size_t dst16 = (((size_t)(icb >> 2) * 9 + tap) * 32 + (oc >> 4)) * 64
                   + (oc & 15) + (icb & 3) * 16;
    *(ushort8*)(wt + dst16 * 8) = pk;
  }
}

// -------- FUSED MFMA conv: main loop = R11; epilogue -> bf16 transposed + sumsq --------
__global__ __launch_bounds__(512, 1) void conv_fused_kernel(const unsigned short* __restrict__ wtq,
                                                            const unsigned short* __restrict__ wtk,
                                                            const float* __restrict__ qb,
                                                            const float* __restrict__ kb,
                                                            const float* __restrict__ fv,
                                                            const float* __restrict__ ft,
                                                            unsigned short* __restrict__ fqT,
                                                            unsigned short* __restrict__ fkT,
                                                            float* __restrict__ qss,
                                                            float* __restrict__ kss) {
  __shared__ unsigned short Wbuf[2 * 6 * 4096];   // 98304 B (epilogue reuses as Ep[288][136])
  __shared__ unsigned short Xs[4 * kXPlane * 8];  // 23424 B
  int t    = threadIdx.x;
  int lane = t & 63;
  int wid  = t >> 6;
  int l15  = lane & 15, kg = lane >> 4;
  int wm   = wid & 1, wn = wid >> 1;  // 2M x 4N
  int n    = blockIdx.x;
  int xcd  = n & 7;
  int oc0  = (xcd >> 1) * 128;
  int b    = ((xcd & 1) << 5) + (n >> 3);
  int f0   = oc0 >> 4;
  const float* fb = feat_base(fv, ft, b);
  const char* wtqB = (const char*)wtq;
  const char* wtkB = (const char*)wtk;

  int  xoff[3];
  bool xvalid[3], xhas[3];
#pragma unroll
  for (int i = 0; i < 3; ++i) {
    int item = i * 512 + t;
    xhas[i] = item < 4 * kXPlane;
    int xkg = item / kXPlane;
    int hp  = item - xkg * kXPlane;
    int hy = hp / 14, hx = hp - hy * 14;
    int y = hy - 1, x = hx - 1;
    bool v = xhas[i] && hp < 364 && (y >= 0 && y < kH && x >= 0 && x < kW);
    xvalid[i] = v;
    xoff[i] = v ? (xkg * 8) * kHW + y * kW + x : 0;
  }

  int aAddr[4];
#pragma unroll
  for (int fm = 0; fm < 4; ++fm)
    aAddr[fm] = (((wm * 4 + fm) * 64) + lane) * 16;
  int nfn = (wn < 2) ? 5 : 4;
  int fnb = (wn < 2) ? wn * 5 : 10 + (wn - 2) * 4;
  int bAddr[5];
#pragma unroll
  for (int fi = 0; fi < 5; ++fi) {
    int p = (fnb + fi) * 16 + l15;
    if (p > 287) p = 287;
    int y = p / kW, x = p - y * kW;
    bAddr[fi] = kg * (kXPlane * 16) + ((y + 1) * 14 + (x + 1)) * 16;
  }

  f32x4 acc[2][4][5];
#pragma unroll
  for (int cv = 0; cv < 2; ++cv)
#pragma unroll
    for (int fm = 0; fm < 4; ++fm)
#pragma unroll
      for (int fi = 0; fi < 5; ++fi) acc[cv][fm][fi] = (f32x4){0.f, 0.f, 0.f, 0.f};

  char* WsB = (char*)Wbuf;
  char* XsB = (char*)Xs;
  int wavebase = t & ~63;

#pragma unroll
  for (int i = 0; i < 3; ++i) {
    if (xhas[i] && !xvalid[i]) {
      ushort8 pk;
#pragma unroll
      for (int j = 0; j < 8; ++j) pk[j] = 0;
      *(ushort8*)(XsB + (size_t)(i * 512 + t) * 16) = pk;
    }
  }
#pragma unroll
  for (int r = 0; r < 3; ++r) {
    size_t g16 = ((size_t)r * 32 + f0 + wid) * 64 + lane;
    gload_lds16(wtqB + g16 * 16, WsB + (size_t)(r * 2 + 0) * 8192 + wavebase * 16);
    gload_lds16(wtkB + g16 * 16, WsB + (size_t)(r * 2 + 1) * 8192 + wavebase * 16);
  }

  int buf = 0;
#pragma unroll 1
  for (int chunk = 0; chunk < 64; ++chunk) {
    int ic0 = chunk * 32;
    {
      float xv[3][8];
#pragma unroll
      for (int i = 0; i < 3; ++i)
        if (xvalid[i]) {
          const float* s = fb + (size_t)ic0 * kHW + xoff[i];
#pragma unroll
          for (int j = 0; j < 8; ++j) xv[i][j] = s[(size_t)j * kHW];
        }
#pragma unroll
      for (int i = 0; i < 3; ++i) {
        if (!xvalid[i]) continue;
        ushort8 pk;
#pragma unroll
        for (int j = 0; j < 8; ++j) pk[j] = f2bf(xv[i][j]);
        *(ushort8*)(XsB + (size_t)(i * 512 + t) * 16) = pk;
      }
    }
    __syncthreads();

#pragma unroll 1
    for (int g = 0; g < 3; ++g) {
      bool hn = (g < 2) || (chunk < 63);
      if (hn) {
        int nchunk = (g < 2) ? chunk : chunk + 1;
        int ng     = (g < 2) ? g + 1 : 0;
#pragma unroll
        for (int r = 0; r < 3; ++r) {
          size_t g16 = ((size_t)(nchunk * 9 + ng * 3 + r) * 32 + f0 + wid) * 64 + lane;
          gload_lds16(wtqB + g16 * 16,
                      WsB + (size_t)((buf ^ 1) * 6 + r * 2 + 0) * 8192 + wavebase * 16);
          gload_lds16(wtkB + g16 * 16,
                      WsB + (size_t)((buf ^ 1) * 6 + r * 2 + 1) * 8192 + wavebase * 16);
        }
      }
#pragma unroll
      for (int r = 0; r < 3; ++r) {
        int tap = g * 3 + r;
        int d16 = ((tap / 3 - 1) * 14 + (tap % 3 - 1)) * 16;
        bf16x8 af[2][4];
#pragma unroll
        for (int cv = 0; cv < 2; ++cv)
#pragma unroll
          for (int fm = 0; fm < 4; ++fm)
            af[cv][fm] = *(const bf16x8*)(WsB + (size_t)(buf * 6 + r * 2 + cv) * 8192 + aAddr[fm]);
#pragma unroll
        for (int fi = 0; fi < 5; ++fi) {
          if (fi >= nfn) continue;
          bf16x8 bb = *(const bf16x8*)(XsB + bAddr[fi] + d16);
#pragma unroll
          for (int cv = 0; cv < 2; ++cv)
#pragma unroll
            for (int fm = 0; fm < 4; ++fm)
              acc[cv][fm][fi] =
                  __builtin_amdgcn_mfma_f32_16x16x32_bf16(af[cv][fm], bb, acc[cv][fm][fi], 0, 0, 0);
        }
      }
      __syncthreads();
      buf ^= 1;
    }
  }

  // ---- epilogue: per cv (fully unrolled), stage bf16 tile in Ep[288][136],
  //      sumsq atomics, coalesced transposed store ----
  unsigned short* Ep = Wbuf;
#pragma unroll
  for (int cv = 0; cv < 2; ++cv) {
    const float* bias = cv ? kb : qb;
    float* ssq = cv ? kss : qss;
#pragma unroll
    for (int fi = 0; fi < 5; ++fi) {
      if (fi >= nfn) continue;
      int p = (fnb + fi) * 16 + l15;
      float ps = 0.f;
#pragma unroll
      for (int fm = 0; fm < 4; ++fm)
#pragma unroll
        for (int reg = 0; reg < 4; ++reg) {
          int ocl = wm * 64 + fm * 16 + kg * 4 + reg;
          float v = acc[cv][fm][fi][reg] + bias[oc0 + ocl];
          ps = fmaf(v, v, ps);
          Ep[p * 136 + ocl] = f2bf(v);
        }
      ps += __shfl_xor(ps, 16);
      ps += __shfl_xor(ps, 32);
      if (kg == 0) atomicAdd(ssq + b * kHW + p, ps);
    }
    __syncthreads();
    unsigned short* dstT = (cv ? fkT : fqT) + (size_t)b * kHW * kCQ + oc0;
#pragma unroll
    for (int it = 0; it < 9; ++it) {
      int item = it * 512 + t;
      int p = item >> 4, j = item & 15;
      *(ushort8*)(dstT + (size_t)p * kCQ + j * 8) =
          *(const ushort8*)(Ep + p * 136 + j * 8);
    }
    __syncthreads();
  }
}

// -------- warp GEMM via MFMA, BOTH branches (z = 0 pos / 1 neg) --------
__global__ __launch_bounds__(512) void warp_mfma_kernel(const float* __restrict__ fv,
                                                        const float* __restrict__ ft,
                                                        const unsigned short* __restrict__ prb0,
                                                        const unsigned short* __restrict__ prb1,
                                                        const float* __restrict__ maskp,
                                                        const int* __restrict__ pos_idx,
                                                        const int* __restrict__ neg_idx,
                                                        float* __restrict__ outp,
                                                        float* __restrict__ dap,
                                                        float* __restrict__ dan) {
  __shared__ unsigned short AsHi[128 * 32];
  __shared__ unsigned short AsLo[128 * 32];
  __shared__ unsigned short Bs[288 * 32];
  int t    = threadIdx.x;
  int lane = t & 63;
  int wid  = t >> 6;
  int l15  = lane & 15, kg = lane >> 4;
  int wm   = wid >> 1, wn = wid & 1;
  int c0   = blockIdx.x * 128;
  int b    = blockIdx.y;
  int z    = blockIdx.z;
  int write_out = (z == 0);
  const unsigned short* prb = z ? prb1 : prb0;
  float* dsq = z ? dan : dap;
  int tb   = (z ? neg_idx : pos_idx)[b];
  const float* tgt = feat_base(fv, ft, tb);
  const float* fb  = feat_base(fv, ft, b);

  int ar = t >> 2, as = t & 3;
  int aslot = as ^ ((ar ^ (ar >> 2)) & 3);
  unsigned short* aDstHi = AsHi + ar * 32 + aslot * 8;
  unsigned short* aDstLo = AsLo + ar * 32 + aslot * 8;

  int aIdx[2];
#pragma unroll
  for (int fm = 0; fm < 2; ++fm) {
    int r = wm * 32 + fm * 16 + l15;
    aIdx[fm] = r * 32 + (kg ^ ((r ^ (r >> 2)) & 3)) * 8;
  }
  int bIdx[9];
#pragma unroll
  for (int fn = 0; fn < 9; ++fn) {
    int q = wn * 144 + fn * 16 + l15;
    bIdx[fn] = q * 32 + (kg ^ ((q ^ (q >> 2)) & 3)) * 8;
  }

  f32x4 acc[2][9];
#pragma unroll
  for (int fm = 0; fm < 2; ++fm)
#pragma unroll
    for (int fn = 0; fn < 9; ++fn) acc[fm][fn] = (f32x4){0.f, 0.f, 0.f, 0.f};

#pragma unroll 1
  for (int chunk = 0; chunk < 9; ++chunk) {
    int k0 = chunk * 32;
    __syncthreads();
    {
      const float* s = tgt + (size_t)(c0 + ar) * kHW + k0 + as * 8;
      float4 v0 = *(const float4*)(s);
      float4 v1 = *(const float4*)(s + 4);
      float xs[8] = {v0.x, v0.y, v0.z, v0.w, v1.x, v1.y, v1.z, v1.w};
      ushort8 hi, lo;
#pragma unroll
      for (int j = 0; j < 8; ++j) {
        unsigned short h = f2bf(xs[j]);
        hi[j] = h;
        lo[j] = f2bf(xs[j] - bf2f(h));
      }
      *(ushort8*)aDstHi = hi;
      *(ushort8*)aDstLo = lo;
    }
#pragma unroll
    for (int i = 0; i < 3; ++i) {
      int item = i * 512 + t;
      if (item < 1152) {
        int q = item >> 2, s = item & 3;
        ushort8 v = *(const ushort8*)(prb + ((size_t)b * kHW + q) * kHW + k0 + s * 8);
        *(ushort8*)(Bs + q * 32 + (s ^ ((q ^ (q >> 2)) & 3)) * 8) = v;
      }
    }
    __syncthreads();
    bf16x8 ah0 = *(const bf16x8*)(AsHi + aIdx[0]);
    bf16x8 al0 = *(const bf16x8*)(AsLo + aIdx[0]);
    bf16x8 ah1 = *(const bf16x8*)(AsHi + aIdx[1]);
    bf16x8 al1 = *(const bf16x8*)(AsLo + aIdx[1]);
#pragma unroll
    for (int fn = 0; fn < 9; ++fn) {
      bf16x8 bb = *(const bf16x8*)(Bs + bIdx[fn]);
      acc[0][fn] = __builtin_amdgcn_mfma_f32_16x16x32_bf16(ah0, bb, acc[0][fn], 0, 0, 0);
      acc[0][fn] = __builtin_amdgcn_mfma_f32_16x16x32_bf16(al0, bb, acc[0][fn], 0, 0, 0);
      acc[1][fn] = __builtin_amdgcn_mfma_f32_16x16x32_bf16(ah1, bb, acc[1][fn], 0, 0, 0);
      acc[1][fn] = __builtin_amdgcn_mfma_f32_16x16x32_bf16(al1, bb, acc[1][fn], 0, 0, 0);
    }
  }

#pragma unroll
  for (int fn = 0; fn < 9; ++fn) {
    int q = wn * 144 + fn * 16 + l15;
    float mj = maskp[b * kHW + q];
    float psum = 0.f;
#pragma unroll
    for (int fm = 0; fm < 2; ++fm) {
#pragma unroll
      for (int reg = 0; reg < 4; ++reg) {
        int c = c0 + wm * 32 + fm * 16 + kg * 4 + reg;
        float fvv = fb[(size_t)c * kHW + q];
        float Wv  = acc[fm][fn][reg];
        float d   = mj * (fvv - Wv) + 1e-6f;
        psum      = fmaf(d, d, psum);
        if (write_out)
          outp[((size_t)b * kC + c) * kHW + q] = mj * Wv + (1.f - mj) * fvv;
      }
    }
    psum += __shfl_xor(psum, 16);
    psum += __shfl_xor(psum, 32);
    if (lane < 16) atomicAdd(&dsq[b * kHW + q], psum);
  }
}

// -------- mask pass 1: partial channel sum-of-squares over 512-c slices --------
__global__ __launch_bounds__(320) void mask_part_kernel(const float* __restrict__ fv,
                                                        const float* __restrict__ ft,
                                                        float* __restrict__ part) {
  int b = blockIdx.x;
  int s = blockIdx.y;
  int t = threadIdx.x;
  if (t >= kHW) return;
  const float* fb = feat_base(fv, ft, b) + (size_t)(s * 512) * kHW;
  float sum = 0.f;
  for (int c = 0; c < 512; ++c) { float v = fb[(size_t)c * kHW + t]; sum += v * v; }
  part[((size_t)b * 4 + s) * kHW + t] = sum;
}

// -------- mask pass 2: finalize sqrt + per-sample min-max normalize --------
__global__ __launch_bounds__(320) void mask_fin_kernel(const float* __restrict__ part,
                                                       float* __restrict__ mask) {
  int b = blockIdx.x;
  int t = threadIdx.x;
  float n = 0.f;
  if (t < kHW) {
    const float* pb = part + (size_t)b * 4 * kHW;
    n = sqrtf(pb[t] + pb[kHW + t] + pb[2 * kHW + t] + pb[3 * kHW + t]);
  }
  __shared__ float sh[320];
  sh[t] = (t < kHW) ? n : 3.4e38f;
  __syncthreads();
  float mn;
  {
    float m = 3.4e38f;
    if (t < 64) {
      for (int i = t; i < 320; i += 64) m = fminf(m, sh[i]);
      for (int off = 32; off; off >>= 1) m = fminf(m, __shfl_xor(m, off));
    }
    __syncthreads();
    if (t == 0) sh[0] = m;
    __syncthreads();
    mn = sh[0];
    __syncthreads();
  }
  sh[t] = (t < kHW) ? n : -3.4e38f;
  __syncthreads();
  float mx;
  {
    float m = -3.4e38f;
    if (t < 64) {
      for (int i = t; i < 320; i += 64) m = fmaxf(m, sh[i]);
      for (int off = 32; off; off >>= 1) m = fmaxf(m, __shfl_xor(m, off));
    }
    __syncthreads();
    if (t == 0) sh[0] = m;
    __syncthreads();
    mx = sh[0];
  }
  if (t < kHW) mask[b * kHW + t] = (n - mn) / ((mx - mn) + 1e-12f);
}

// -------- sim via MFMA + fused softmax, BOTH branches (z dim) --------
__global__ __launch_bounds__(512, 1) void sim_mfma_kernel(const unsigned short* __restrict__ fqT,
                                                          const unsigned short* __restrict__ fkT,
                                                          const float* __restrict__ qss,
                                                          const float* __restrict__ kss,
                                                          const int* __restrict__ pos_idx,
                                                          const int* __restrict__ neg_idx,
                                                          unsigned short* __restrict__ prb0,
                                                          unsigned short* __restrict__ prb1) {
  __shared__ float Sbuf[96 * 289];  // 110976 B; As @0 (6KB), Bs @6144 (18KB) alias
  unsigned short* As = (unsigned short*)Sbuf;
  unsigned short* Bs = (unsigned short*)((char*)Sbuf + 6144);
  float (*S)[289] = (float(*)[289])Sbuf;
  int t    = threadIdx.x;
  int lane = t & 63;
  int wid  = t >> 6;
  int l15  = lane & 15, kg = lane >> 4;
  int wm   = wid & 1, wn = wid >> 1;  // 2M x 4N
  int q0   = blockIdx.x * 96;
  int b    = blockIdx.y;
  int z    = blockIdx.z;
  int tb   = (z ? neg_idx : pos_idx)[b];
  unsigned short* prb = z ? prb1 : prb0;
  const unsigned short* fqb = fqT + ((size_t)b * kHW + q0) * kCQ;
  const unsigned short* fkb = fkT + (size_t)tb * kHW * kCQ;

  int aIdx[3];
#pragma unroll
  for (int fm = 0; fm < 3; ++fm) {
    int r = wm * 48 + fm * 16 + l15;
    aIdx[fm] = r * 32 + (kg ^ ((r ^ (r >> 2)) & 3)) * 8;
  }
  int nfn = (wn < 2) ? 5 : 4;
  int fnb = (wn < 2) ? wn * 5 : 10 + (wn - 2) * 4;
  int bIdx[5];
#pragma unroll
  for (int fi = 0; fi < 5; ++fi) {
    int kr = (fnb + fi) * 16 + l15;
    if (kr > 287) kr = 287;
    bIdx[fi] = kr * 32 + (kg ^ ((kr ^ (kr >> 2)) & 3)) * 8;
  }

  f32x4 acc[3][5];
#pragma unroll
  for (int fm = 0; fm < 3; ++fm)
#pragma unroll
    for (int fi = 0; fi < 5; ++fi) acc[fm][fi] = (f32x4){0.f, 0.f, 0.f, 0.f};

#pragma unroll 1
  for (int chunk = 0; chunk < 16; ++chunk) {
    int c0 = chunk * 32;
    __syncthreads();
    if (t < 384) {
      int ar = t >> 2, as = t & 3;
      ushort8 v = *(const ushort8*)(fqb + (size_t)ar * kCQ + c0 + as * 8);
      int slot = as ^ ((ar ^ (ar >> 2)) & 3);
      *(ushort8*)(As + ar * 32 + slot * 8) = v;
    }
#pragma unroll
    for (int i = 0; i < 3; ++i) {
      int item = i * 512 + t;
      if (item < 1152) {
        int kr = item >> 2, ks = item & 3;
        ushort8 v = *(const ushort8*)(fkb + (size_t)kr * kCQ + c0 + ks * 8);
        int slot = ks ^ ((kr ^ (kr >> 2)) & 3);
        *(ushort8*)(Bs + kr * 32 + slot * 8) = v;
      }
    }
    __syncthreads();
    bf16x8 a[3];
#pragma unroll
    for (int fm = 0; fm < 3; ++fm) a[fm] = *(const bf16x8*)(As + aIdx[fm]);
#pragma unroll
    for (int fi = 0; fi < 5; ++fi) {
      if (fi >= nfn) continue;
      bf16x8 bb = *(const bf16x8*)(Bs + bIdx[fi]);
#pragma unroll
      for (int fm = 0; fm < 3; ++fm)
        acc[fm][fi] = __builtin_amdgcn_mfma_f32_16x16x32_bf16(a[fm], bb, acc[fm][fi], 0, 0, 0);
    }
  }
  __syncthreads();  // all frag reads done before S overwrites As/Bs

  float kinvv[5];
#pragma unroll
  for (int fi = 0; fi < 5; ++fi) {
    int col = (fnb + fi) * 16 + l15;
    if (col > 287) col = 287;
    kinvv[fi] = 1.f / fmaxf(sqrtf(kss[tb * kHW + col]), 1e-12f);
  }
#pragma unroll
  for (int fm = 0; fm < 3; ++fm)
#pragma unroll
    for (int reg = 0; reg < 4; ++reg) {
      int row = wm * 48 + fm * 16 + kg * 4 + reg;
      float qi = kTemp / fmaxf(sqrtf(qss[b * kHW + q0 + row]), 1e-12f);
#pragma unroll
      for (int fi = 0; fi < 5; ++fi) {
        if (fi >= nfn) continue;
        S[row][(fnb + fi) * 16 + l15] = qi * kinvv[fi] * acc[fm][fi][reg];
      }
    }
  __syncthreads();

  int l = lane;
  for (int q = wid; q < 96; q += 8) {
    float v[5];
    float m = -3.4e38f;
#pragma unroll
    for (int j = 0; j < 5; ++j) {
      int k = l + 64 * j;
      v[j] = (k < kHW) ? S[q][k] : -3.4e38f;
      m = fmaxf(m, v[j]);
    }
    for (int off = 32; off; off >>= 1) m = fmaxf(m, __shfl_xor(m, off));
    float e[5];
    float s = 0.f;
#pragma unroll
    for (int j = 0; j < 5; ++j) {
      int k = l + 64 * j;
      e[j] = (k < kHW) ? __expf(v[j] - m) : 0.f;
      s += e[j];
    }
    for (int off = 32; off; off >>= 1) s += __shfl_xor(s, off);
    float invs = 1.f / s;
    unsigned short* row = prb + ((size_t)b * kHW + q0 + q) * kHW;
#pragma unroll
    for (int j = 0; j < 5; ++j) {
      int k = l + 64 * j;
      if (k < kHW) row[k] = f2bf(e[j] * invs);
    }
  }
}

// -------- comask (reads bf16 pr_pos) --------
__global__ __launch_bounds__(320) void comask_kernel(const unsigned short* __restrict__ prb,
                                                     const float* __restrict__ mask,
                                                     const int* __restrict__ idx,
                                                     float* __restrict__ comask) {
  int b = blockIdx.x;
  int t = threadIdx.x;
  int tb = idx[b];
  __shared__ float mt[kHW];
  __shared__ float cm[kHW];
  __shared__ float red[320];
  if (t < kHW) mt[t] = mask[tb * kHW + t];
  __syncthreads();
  int wv = t >> 6, l = t & 63;
  for (int q = wv; q < kHW; q += 5) {
    const unsigned short* prow = prb + ((size_t)b * kHW + q) * kHW;
    float s = 0.f;
    for (int k = l; k < kHW; k += 64) s += bf2f(prow[k]) * mt[k];
    for (int off = 32; off; off >>= 1) s += __shfl_xor(s, off);
    if (l == 0) cm[q] = mask[b * kHW + q] * s;
  }
  __syncthreads();
  float v = (t < kHW) ? cm[t] : 0.f;
  red[t] = (t < kHW) ? v : 3.4e38f;
  __syncthreads();
  float mn;
  {
    float m = 3.4e38f;
    if (t < 64) {
      for (int i = t; i < 320; i += 64) m = fminf(m, red[i]);
      for (int off = 32; off; off >>= 1) m = fminf(m, __shfl_xor(m, off));
    }
    __syncthreads();
    if (t == 0) red[0] = m;
    __syncthreads();
    mn = red[0];
    __syncthreads();
  }
  red[t] = (t < kHW) ? v : -3.4e38f;
  __syncthreads();
  float mx;
  {
    float m = -3.4e38f;
    if (t < 64) {
      for (int i = t; i < 320; i += 64) m = fmaxf(m, red[i]);
      for (int off = 32; off; off >>= 1) m = fmaxf(m, __shfl_xor(m, off));
    }
    __syncthreads();
    if (t == 0) red[0] = m;
    __syncthreads();
    mx = red[0];
  }
  if (t < kHW) comask[b * kHW + t] = (v - mn) / ((mx - mn) + 1e-12f);
}

// -------- triplet loss --------
__global__ __launch_bounds__(256) void loss_kernel(const float* __restrict__ dap,
                                                   const float* __restrict__ dan,
                                                   const float* __restrict__ comask,
                                                   float* __restrict__ out) {
  int t = threadIdx.x;
  float s = 0.f;
  for (int i = t; i < kB * kHW; i += 256) {
    float da = sqrtf(dap[i]);
    float db = sqrtf(dan[i]);
    float tr = fmaxf(da - db + 0.3f, 0.f);
    s += comask[i] * tr;
  }
  for (int off = 32; off; off >>= 1) s += __shfl_xor(s, off);
  __shared__ float sh[4];
  if ((t & 63) == 0) sh[t >> 6] = s;
  __syncthreads();
  if (t == 0)
    out[(size_t)kB * kC * kHW] = (sh[0] + sh[1] + sh[2] + sh[3]) * (1.f / (float)(kB * kHW));
}

extern "C" void kernel_launch(void* const* d_in, const int* in_sizes, int n_in,
                              void* d_out, int out_size, void* d_ws, size_t ws_size,
                              hipStream_t stream) {
  const float* fv = (const float*)d_in[0];
  const float* ft = (const float*)d_in[1];
  const float* qw = (const float*)d_in[4];
  const float* qb = (const float*)d_in[5];
  const float* kw = (const float*)d_in[6];
  const float* kb = (const float*)d_in[7];
  const int* pos_idx = (const int*)d_in[8];
  const int* neg_idx = (const int*)d_in[9];
  float* out = (float*)d_out;

  constexpr size_t kFQ = (size_t)kB * kCQ * kHW;            // 9,437,184
  constexpr size_t kPR = (size_t)kB * kHW * kHW;            // 5,308,416 (u16)
  float* ws   = (float*)d_ws;
  unsigned short* fqT = (unsigned short*)ws;                // region1 (37.75M)
  unsigned short* fkT = fqT + (size_t)kB * kHW * kCQ;
  unsigned short* prb0 = (unsigned short*)(ws + kFQ);       // region2: pos P (10.6M)
  unsigned short* prb1 = prb0 + kPR;                        //          neg P (10.6M)
  unsigned short* wtq = (unsigned short*)(ws + 2 * kFQ);    // region3
  unsigned short* wtk = wtq + (size_t)9 * kCQ * kC;
  float* part = (float*)wtq;                                // alias, dead before prep_w
  float* maskb   = (float*)(wtk + (size_t)9 * kCQ * kC);
  float* qss     = maskb + kB * kHW;
  float* kss     = qss + kB * kHW;
  float* comaskb = kss + kB * kHW;
  float* dap     = comaskb + kB * kHW;
  float* dan     = dap + kB * kHW;
  if (ws_size < (size_t)113688576) return;

  zero_kernel<<<dim3((5 * kB * kHW + 255) / 256), 256, 0, stream>>>(qss, 5 * kB * kHW);
  mask_part_kernel<<<dim3(kB, 4), 320, 0, stream>>>(fv, ft, part);
  mask_fin_kernel<<<dim3(kB), 320, 0, stream>>>(part, maskb);
  prep_w_kernel<<<dim3(kCQ, 2), 256, 0, stream>>>(qw, kw, wtq, wtk);
  conv_fused_kernel<<<dim3(256), 512, 0, stream>>>(wtq, wtk, qb, kb, fv, ft,
                                                   fqT, fkT, qss, kss);

  // both branches in single launches
  sim_mfma_kernel<<<dim3(3, kB, 2), 512, 0, stream>>>(fqT, fkT, qss, kss,
                                                      pos_idx, neg_idx, prb0, prb1);
  comask_kernel<<<dim3(kB), 320, 0, stream>>>(prb0, maskb, pos_idx, comaskb);
  warp_mfma_kernel<<<dim3(16, kB, 2), 512, 0, stream>>>(fv, ft, prb0, prb1, maskb,
                                                        pos_idx, neg_idx, out, dap, dan);

  loss_kernel<<<dim3(1), 256, 0, stream>>>(dap, dan, comaskb, out);
}

// Round 19
// 1144.126 us; speedup vs baseline: 5.7982x; 1.0172x over previous
//
#include <hip/hip_runtime.h>
#include <cstdint>
#include <cstddef>

// CMAlign forward. R19: launch-count attack — mask fused into conv (per-thread
// sum-of-squares during X staging + tile-0 block reduce), comask fused into sim
// (row dot with mask_t in-register), min-max+loss in one final kernel.
// 6 launches: zero, prep_w, conv, sim, warp, loss.
// Shapes: B=64, C=2048, Cq=512, H=24, W=12, HW=288.

namespace {
constexpr int kB    = 64;
constexpr int kHalf = 32;
constexpr int kC    = 2048;
constexpr int kCQ   = 512;
constexpr int kH    = 24;
constexpr int kW    = 12;
constexpr int kHW   = 288;
constexpr float kTemp = 50.0f;
constexpr int kXPlane = 366;  // 16B cells; 5856 B = 96 mod 128 -> kg quadrant offsets
}

typedef __attribute__((ext_vector_type(8))) __bf16 bf16x8;
typedef __attribute__((ext_vector_type(4))) float f32x4;
typedef __attribute__((ext_vector_type(8))) unsigned short ushort8;

__device__ __forceinline__ const float* feat_base(const float* fv, const float* ft, int b) {
  return (b < kHalf) ? (fv + (size_t)b * kC * kHW)
                     : (ft + (size_t)(b - kHalf) * kC * kHW);
}

__device__ __forceinline__ unsigned short f2bf(float f) {
  union { float f; unsigned u; } c; c.f = f;
  unsigned u = c.u;
  unsigned r = (u + 0x7FFFu + ((u >> 16) & 1u)) >> 16;  // RNE
  return (unsigned short)r;
}

__device__ __forceinline__ float bf2f(unsigned short h) {
  union { unsigned u; float f; } c; c.u = ((unsigned)h) << 16;
  return c.f;
}

__device__ __forceinline__ void gload_lds16(const void* g, void* l) {
  __builtin_amdgcn_global_load_lds(
      (const __attribute__((address_space(1))) unsigned int*)g,
      (__attribute__((address_space(3))) unsigned int*)l, 16, 0, 0);
}

__global__ void zero_kernel(float* __restrict__ p, int n) {
  int i = blockIdx.x * 256 + threadIdx.x;
  if (i < n) p[i] = 0.f;
}

// -------- weight prep: w[oc][ic][3][3] fp32 -> MFMA-image wt2 --------
__global__ __launch_bounds__(256) void prep_w_kernel(const float* __restrict__ qw,
                                                     const float* __restrict__ kw,
                                                     unsigned short* __restrict__ wtq,
                                                     unsigned short* __restrict__ wtk) {
  int oc = blockIdx.x;
  int z  = blockIdx.y;
  const float* w = (z ? kw : qw) + (size_t)oc * (kC * 9);
  unsigned short* wt = z ? wtk : wtq;
  __shared__ unsigned short lw[kC * 9];  // [ic][tap]
  int t = threadIdx.x;
#pragma unroll
  for (int it = 0; it < 18; ++it) {
    int i4 = (it * 256 + t) * 4;
    float4 v = *(const float4*)(w + i4);
    lw[i4 + 0] = f2bf(v.x);
    lw[i4 + 1] = f2bf(v.y);
    lw[i4 + 2] = f2bf(v.z);
    lw[i4 + 3] = f2bf(v.w);
  }
  __syncthreads();
  for (int item = t; item < 9 * 256; item += 256) {
    int tap = item >> 8;
    int icb = item & 255;
    ushort8 pk;
#pragma unroll
    for (int j = 0; j < 8; ++j) pk[j] = lw[(icb * 8 + j) * 9 + tap];
    size_t dst16 = (((size_t)(icb >> 2) * 9 + tap) * 32 + (oc >> 4)) * 64
                   + (oc & 15) + (icb & 3) * 16;
    *(ushort8*)(wt + dst16 * 8) = pk;
  }
}

// -------- FUSED MFMA conv + mask: main loop = R11; epilogue -> bf16T + sumsq + mask --------
__global__ __launch_bounds__(512, 1) void conv_fused_kernel(const unsigned short* __restrict__ wtq,
                                                            const unsigned short* __restrict__ wtk,
                                                            const float* __restrict__ qb,
                                                            const float* __restrict__ kb,
                                                            const float* __restrict__ fv,
                                                            const float* __restrict__ ft,
                                                            unsigned short* __restrict__ fqT,
                                                            unsigned short* __restrict__ fkT,
                                                            float* __restrict__ qss,
                                                            float* __restrict__ kss,
                                                            float* __restrict__ maskb) {
  __shared__ unsigned short Wbuf[2 * 6 * 4096];   // 98304 B (reused: mask red / Ep)
  __shared__ unsigned short Xs[4 * kXPlane * 8];  // 23424 B (reused: mask Mred)
  int t    = threadIdx.x;
  int lane = t & 63;
  int wid  = t >> 6;
  int l15  = lane & 15, kg = lane >> 4;
  int wm   = wid & 1, wn = wid >> 1;  // 2M x 4N
  int n    = blockIdx.x;
  int xcd  = n & 7;
  int oc0  = (xcd >> 1) * 128;
  int b    = ((xcd & 1) << 5) + (n >> 3);
  int f0   = oc0 >> 4;
  const float* fb = feat_base(fv, ft, b);
  const char* wtqB = (const char*)wtq;
  const char* wtkB = (const char*)wtk;

  int  xoff[3];
  bool xvalid[3], xhas[3];
#pragma unroll
  for (int i = 0; i < 3; ++i) {
    int item = i * 512 + t;
    xhas[i] = item < 4 * kXPlane;
    int xkg = item / kXPlane;
    int hp  = item - xkg * kXPlane;
    int hy = hp / 14, hx = hp - hy * 14;
    int y = hy - 1, x = hx - 1;
    bool v = xhas[i] && hp < 364 && (y >= 0 && y < kH && x >= 0 && x < kW);
    xvalid[i] = v;
    xoff[i] = v ? (xkg * 8) * kHW + y * kW + x : 0;
  }

  int aAddr[4];
#pragma unroll
  for (int fm = 0; fm < 4; ++fm)
    aAddr[fm] = (((wm * 4 + fm) * 64) + lane) * 16;
  int nfn = (wn < 2) ? 5 : 4;
  int fnb = (wn < 2) ? wn * 5 : 10 + (wn - 2) * 4;
  int bAddr[5];
#pragma unroll
  for (int fi = 0; fi < 5; ++fi) {
    int p = (fnb + fi) * 16 + l15;
    if (p > 287) p = 287;
    int y = p / kW, x = p - y * kW;
    bAddr[fi] = kg * (kXPlane * 16) + ((y + 1) * 14 + (x + 1)) * 16;
  }

  f32x4 acc[2][4][5];
#pragma unroll
  for (int cv = 0; cv < 2; ++cv)
#pragma unroll
    for (int fm = 0; fm < 4; ++fm)
#pragma unroll
      for (int fi = 0; fi < 5; ++fi) acc[cv][fm][fi] = (f32x4){0.f, 0.f, 0.f, 0.f};

  float msum0 = 0.f, msum1 = 0.f, msum2 = 0.f;  // per-item sum of x^2 (mask)

  char* WsB = (char*)Wbuf;
  char* XsB = (char*)Xs;
  int wavebase = t & ~63;

#pragma unroll
  for (int i = 0; i < 3; ++i) {
    if (xhas[i] && !xvalid[i]) {
      ushort8 pk;
#pragma unroll
      for (int j = 0; j < 8; ++j) pk[j] = 0;
      *(ushort8*)(XsB + (size_t)(i * 512 + t) * 16) = pk;
    }
  }
#pragma unroll
  for (int r = 0; r < 3; ++r) {
    size_t g16 = ((size_t)r * 32 + f0 + wid) * 64 + lane;
    gload_lds16(wtqB + g16 * 16, WsB + (size_t)(r * 2 + 0) * 8192 + wavebase * 16);
    gload_lds16(wtkB + g16 * 16, WsB + (size_t)(r * 2 + 1) * 8192 + wavebase * 16);
  }

  int buf = 0;
#pragma unroll 1
  for (int chunk = 0; chunk < 64; ++chunk) {
    int ic0 = chunk * 32;
    {
      float xv[3][8];
#pragma unroll
      for (int i = 0; i < 3; ++i)
        if (xvalid[i]) {
          const float* s = fb + (size_t)ic0 * kHW + xoff[i];
#pragma unroll
          for (int j = 0; j < 8; ++j) xv[i][j] = s[(size_t)j * kHW];
        }
      // mask accumulation (fp32, matches reference norms)
      if (xvalid[0]) {
#pragma unroll
        for (int j = 0; j < 8; ++j) msum0 = fmaf(xv[0][j], xv[0][j], msum0);
      }
      if (xvalid[1]) {
#pragma unroll
        for (int j = 0; j < 8; ++j) msum1 = fmaf(xv[1][j], xv[1][j], msum1);
      }
      if (xvalid[2]) {
#pragma unroll
        for (int j = 0; j < 8; ++j) msum2 = fmaf(xv[2][j], xv[2][j], msum2);
      }
#pragma unroll
      for (int i = 0; i < 3; ++i) {
        if (!xvalid[i]) continue;
        ushort8 pk;
#pragma unroll
        for (int j = 0; j < 8; ++j) pk[j] = f2bf(xv[i][j]);
        *(ushort8*)(XsB + (size_t)(i * 512 + t) * 16) = pk;
      }
    }
    __syncthreads();

#pragma unroll 1
    for (int g = 0; g < 3; ++g) {
      bool hn = (g < 2) || (chunk < 63);
      if (hn) {
        int nchunk = (g < 2) ? chunk : chunk + 1;
        int ng     = (g < 2) ? g + 1 : 0;
#pragma unroll
        for (int r = 0; r < 3; ++r) {
          size_t g16 = ((size_t)(nchunk * 9 + ng * 3 + r) * 32 + f0 + wid) * 64 + lane;
          gload_lds16(wtqB + g16 * 16,
                      WsB + (size_t)((buf ^ 1) * 6 + r * 2 + 0) * 8192 + wavebase * 16);
          gload_lds16(wtkB + g16 * 16,
                      WsB + (size_t)((buf ^ 1) * 6 + r * 2 + 1) * 8192 + wavebase * 16);
        }
      }
#pragma unroll
      for (int r = 0; r < 3; ++r) {
        int tap = g * 3 + r;
        int d16 = ((tap / 3 - 1) * 14 + (tap % 3 - 1)) * 16;
        bf16x8 af[2][4];
#pragma unroll
        for (int cv = 0; cv < 2; ++cv)
#pragma unroll
          for (int fm = 0; fm < 4; ++fm)
            af[cv][fm] = *(const bf16x8*)(WsB + (size_t)(buf * 6 + r * 2 + cv) * 8192 + aAddr[fm]);
#pragma unroll
        for (int fi = 0; fi < 5; ++fi) {
          if (fi >= nfn) continue;
          bf16x8 bb = *(const bf16x8*)(XsB + bAddr[fi] + d16);
#pragma unroll
          for (int cv = 0; cv < 2; ++cv)
#pragma unroll
            for (int fm = 0; fm < 4; ++fm)
              acc[cv][fm][fi] =
                  __builtin_amdgcn_mfma_f32_16x16x32_bf16(af[cv][fm], bb, acc[cv][fm][fi], 0, 0, 0);
        }
      }
      __syncthreads();
      buf ^= 1;
    }
  }

  // ---- mask reduce: only tile-0 blocks (one per b). Xs -> Mred, Wbuf -> red ----
  if (oc0 == 0) {
    float* Mred = (float*)Xs;   // 4*288 floats
    float msum[3] = {msum0, msum1, msum2};
#pragma unroll
    for (int i = 0; i < 3; ++i) {
      if (!xvalid[i]) continue;
      int item = i * 512 + t;
      int xkg = item / kXPlane;
      int hp  = item - xkg * kXPlane;
      int y = hp / 14 - 1, x = hp % 14 - 1;
      Mred[xkg * kHW + y * kW + x] = msum[i];
    }
    __syncthreads();
    float nv = 0.f;
    if (t < kHW)
      nv = sqrtf(Mred[t] + Mred[kHW + t] + Mred[2 * kHW + t] + Mred[3 * kHW + t]);
    float* red = (float*)Wbuf;  // 512 floats
    red[t] = (t < kHW) ? nv : 3.4e38f;
    __syncthreads();
    float mn;
    {
      float m = 3.4e38f;
      if (t < 64) {
        for (int i = t; i < 512; i += 64) m = fminf(m, red[i]);
        for (int off = 32; off; off >>= 1) m = fminf(m, __shfl_xor(m, off));
      }
      __syncthreads();
      if (t == 0) red[0] = m;
      __syncthreads();
      mn = red[0];
      __syncthreads();
    }
    red[t] = (t < kHW) ? nv : -3.4e38f;
    __syncthreads();
    float mx;
    {
      float m = -3.4e38f;
      if (t < 64) {
        for (int i = t; i < 512; i += 64) m = fmaxf(m, red[i]);
        for (int off = 32; off; off >>= 1) m = fmaxf(m, __shfl_xor(m, off));
      }
      __syncthreads();
      if (t == 0) red[0] = m;
      __syncthreads();
      mx = red[0];
    }
    if (t < kHW) maskb[b * kHW + t] = (nv - mn) / ((mx - mn) + 1e-12f);
    __syncthreads();  // red (Wbuf) reads done before Ep writes
  }

  // ---- epilogue: per cv (fully unrolled), Ep[288][136] stage, sumsq, transposed store ----
  unsigned short* Ep = Wbuf;
#pragma unroll
  for (int cv = 0; cv < 2; ++cv) {
    const float* bias = cv ? kb : qb;
    float* ssq = cv ? kss : qss;
#pragma unroll
    for (int fi = 0; fi < 5; ++fi) {
      if (fi >= nfn) continue;
      int p = (fnb + fi) * 16 + l15;
      float ps = 0.f;
#pragma unroll
      for (int fm = 0; fm < 4; ++fm)
#pragma unroll
        for (int reg = 0; reg < 4; ++reg) {
          int ocl = wm * 64 + fm * 16 + kg * 4 + reg;
          float v = acc[cv][fm][fi][reg] + bias[oc0 + ocl];
          ps = fmaf(v, v, ps);
          Ep[p * 136 + ocl] = f2bf(v);
        }
      ps += __shfl_xor(ps, 16);
      ps += __shfl_xor(ps, 32);
      if (kg == 0) atomicAdd(ssq + b * kHW + p, ps);
    }
    __syncthreads();
    unsigned short* dstT = (cv ? fkT : fqT) + (size_t)b * kHW * kCQ + oc0;
#pragma unroll
    for (int it = 0; it < 9; ++it) {
      int item = it * 512 + t;
      int p = item >> 4, j = item & 15;
      *(ushort8*)(dstT + (size_t)p * kCQ + j * 8) =
          *(const ushort8*)(Ep + p * 136 + j * 8);
    }
    __syncthreads();
  }
}

// -------- warp GEMM via MFMA, BOTH branches (z = 0 pos / 1 neg) --------
__global__ __launch_bounds__(512) void warp_mfma_kernel(const float* __restrict__ fv,
                                                        const float* __restrict__ ft,
                                                        const unsigned short* __restrict__ prb0,
                                                        const unsigned short* __restrict__ prb1,
                                                        const float* __restrict__ maskp,
                                                        const int* __restrict__ pos_idx,
                                                        const int* __restrict__ neg_idx,
                                                        float* __restrict__ outp,
                                                        float* __restrict__ dap,
                                                        float* __restrict__ dan) {
  __shared__ unsigned short AsHi[128 * 32];
  __shared__ unsigned short AsLo[128 * 32];
  __shared__ unsigned short Bs[288 * 32];
  int t    = threadIdx.x;
  int lane = t & 63;
  int wid  = t >> 6;
  int l15  = lane & 15, kg = lane >> 4;
  int wm   = wid >> 1, wn = wid & 1;
  int c0   = blockIdx.x * 128;
  int b    = blockIdx.y;
  int z    = blockIdx.z;
  int write_out = (z == 0);
  const unsigned short* prb = z ? prb1 : prb0;
  float* dsq = z ? dan : dap;
  int tb   = (z ? neg_idx : pos_idx)[b];
  const float* tgt = feat_base(fv, ft, tb);
  const float* fb  = feat_base(fv, ft, b);

  int ar = t >> 2, as = t & 3;
  int aslot = as ^ ((ar ^ (ar >> 2)) & 3);
  unsigned short* aDstHi = AsHi + ar * 32 + aslot * 8;
  unsigned short* aDstLo = AsLo + ar * 32 + aslot * 8;

  int aIdx[2];
#pragma unroll
  for (int fm = 0; fm < 2; ++fm) {
    int r = wm * 32 + fm * 16 + l15;
    aIdx[fm] = r * 32 + (kg ^ ((r ^ (r >> 2)) & 3)) * 8;
  }
  int bIdx[9];
#pragma unroll
  for (int fn = 0; fn < 9; ++fn) {
    int q = wn * 144 + fn * 16 + l15;
    bIdx[fn] = q * 32 + (kg ^ ((q ^ (q >> 2)) & 3)) * 8;
  }

  f32x4 acc[2][9];
#pragma unroll
  for (int fm = 0; fm < 2; ++fm)
#pragma unroll
    for (int fn = 0; fn < 9; ++fn) acc[fm][fn] = (f32x4){0.f, 0.f, 0.f, 0.f};

#pragma unroll 1
  for (int chunk = 0; chunk < 9; ++chunk) {
    int k0 = chunk * 32;
    __syncthreads();
    {
      const float* s = tgt + (size_t)(c0 + ar) * kHW + k0 + as * 8;
      float4 v0 = *(const float4*)(s);
      float4 v1 = *(const float4*)(s + 4);
      float xs[8] = {v0.x, v0.y, v0.z, v0.w, v1.x, v1.y, v1.z, v1.w};
      ushort8 hi, lo;
#pragma unroll
      for (int j = 0; j < 8; ++j) {
        unsigned short h = f2bf(xs[j]);
        hi[j] = h;
        lo[j] = f2bf(xs[j] - bf2f(h));
      }
      *(ushort8*)aDstHi = hi;
      *(ushort8*)aDstLo = lo;
    }
#pragma unroll
    for (int i = 0; i < 3; ++i) {
      int item = i * 512 + t;
      if (item < 1152) {
        int q = item >> 2, s = item & 3;
        ushort8 v = *(const ushort8*)(prb + ((size_t)b * kHW + q) * kHW + k0 + s * 8);
        *(ushort8*)(Bs + q * 32 + (s ^ ((q ^ (q >> 2)) & 3)) * 8) = v;
      }
    }
    __syncthreads();
    bf16x8 ah0 = *(const bf16x8*)(AsHi + aIdx[0]);
    bf16x8 al0 = *(const bf16x8*)(AsLo + aIdx[0]);
    bf16x8 ah1 = *(const bf16x8*)(AsHi + aIdx[1]);
    bf16x8 al1 = *(const bf16x8*)(AsLo + aIdx[1]);
#pragma unroll
    for (int fn = 0; fn < 9; ++fn) {
      bf16x8 bb = *(const bf16x8*)(Bs + bIdx[fn]);
      acc[0][fn] = __builtin_amdgcn_mfma_f32_16x16x32_bf16(ah0, bb, acc[0][fn], 0, 0, 0);
      acc[0][fn] = __builtin_amdgcn_mfma_f32_16x16x32_bf16(al0, bb, acc[0][fn], 0, 0, 0);
      acc[1][fn] = __builtin_amdgcn_mfma_f32_16x16x32_bf16(ah1, bb, acc[1][fn], 0, 0, 0);
      acc[1][fn] = __builtin_amdgcn_mfma_f32_16x16x32_bf16(al1, bb, acc[1][fn], 0, 0, 0);
    }
  }

#pragma unroll
  for (int fn = 0; fn < 9; ++fn) {
    int q = wn * 144 + fn * 16 + l15;
    float mj = maskp[b * kHW + q];
    float psum = 0.f;
#pragma unroll
    for (int fm = 0; fm < 2; ++fm) {
#pragma unroll
      for (int reg = 0; reg < 4; ++reg) {
        int c = c0 + wm * 32 + fm * 16 + kg * 4 + reg;
        float fvv = fb[(size_t)c * kHW + q];
        float Wv  = acc[fm][fn][reg];
        float d   = mj * (fvv - Wv) + 1e-6f;
        psum      = fmaf(d, d, psum);
        if (write_out)
          outp[((size_t)b * kC + c) * kHW + q] = mj * Wv + (1.f - mj) * fvv;
      }
    }
    psum += __shfl_xor(psum, 16);
    psum += __shfl_xor(psum, 32);
    if (lane < 16) atomicAdd(&dsq[b * kHW + q], psum);
  }
}

// -------- sim via MFMA + softmax + comask_raw (z=0), BOTH branches --------
__global__ __launch_bounds__(512, 1) void sim_mfma_kernel(const unsigned short* __restrict__ fqT,
                                                          const unsigned short* __restrict__ fkT,
                                                          const float* __restrict__ qss,
                                                          const float* __restrict__ kss,
                                                          const float* __restrict__ maskb,
                                                          const int* __restrict__ pos_idx,
                                                          const int* __restrict__ neg_idx,
                                                          unsigned short* __restrict__ prb0,
                                                          unsigned short* __restrict__ prb1,
                                                          float* __restrict__ craw) {
  __shared__ float Sbuf[96 * 289];  // 110976 B; As @0 (6KB), Bs @6144 (18KB) alias
  __shared__ float mtl[kHW];        // mask[tb] for comask dot
  unsigned short* As = (unsigned short*)Sbuf;
  unsigned short* Bs = (unsigned short*)((char*)Sbuf + 6144);
  float (*S)[289] = (float(*)[289])Sbuf;
  int t    = threadIdx.x;
  int lane = t & 63;
  int wid  = t >> 6;
  int l15  = lane & 15, kg = lane >> 4;
  int wm   = wid & 1, wn = wid >> 1;  // 2M x 4N
  int q0   = blockIdx.x * 96;
  int b    = blockIdx.y;
  int z    = blockIdx.z;
  int tb   = (z ? neg_idx : pos_idx)[b];
  unsigned short* prb = z ? prb1 : prb0;
  const unsigned short* fqb = fqT + ((size_t)b * kHW + q0) * kCQ;
  const unsigned short* fkb = fkT + (size_t)tb * kHW * kCQ;

  if (t < kHW) mtl[t] = maskb[tb * kHW + t];

  int aIdx[3];
#pragma unroll
  for (int fm = 0; fm < 3; ++fm) {
    int r = wm * 48 + fm * 16 + l15;
    aIdx[fm] = r * 32 + (kg ^ ((r ^ (r >> 2)) & 3)) * 8;
  }
  int nfn = (wn < 2) ? 5 : 4;
  int fnb = (wn < 2) ? wn * 5 : 10 + (wn - 2) * 4;
  int bIdx[5];
#pragma unroll
  for (int fi = 0; fi < 5; ++fi) {
    int kr = (fnb + fi) * 16 + l15;
    if (kr > 287) kr = 287;
    bIdx[fi] = kr * 32 + (kg ^ ((kr ^ (kr >> 2)) & 3)) * 8;
  }

  f32x4 acc[3][5];
#pragma unroll
  for (int fm = 0; fm < 3; ++fm)
#pragma unroll
    for (int fi = 0; fi < 5; ++fi) acc[fm][fi] = (f32x4){0.f, 0.f, 0.f, 0.f};

#pragma unroll 1
  for (int chunk = 0; chunk < 16; ++chunk) {
    int c0 = chunk * 32;
    __syncthreads();
    if (t < 384) {
      int ar = t >> 2, as = t & 3;
      ushort8 v = *(const ushort8*)(fqb + (size_t)ar * kCQ + c0 + as * 8);
      int slot = as ^ ((ar ^ (ar >> 2)) & 3);
      *(ushort8*)(As + ar * 32 + slot * 8) = v;
    }
#pragma unroll
    for (int i = 0; i < 3; ++i) {
      int item = i * 512 + t;
      if (item < 1152) {
        int kr = item >> 2, ks = item & 3;
        ushort8 v = *(const ushort8*)(fkb + (size_t)kr * kCQ + c0 + ks * 8);
        int slot = ks ^ ((kr ^ (kr >> 2)) & 3);
        *(ushort8*)(Bs + kr * 32 + slot * 8) = v;
      }
    }
    __syncthreads();
    bf16x8 a[3];
#pragma unroll
    for (int fm = 0; fm < 3; ++fm) a[fm] = *(const bf16x8*)(As + aIdx[fm]);
#pragma unroll
    for (int fi = 0; fi < 5; ++fi) {
      if (fi >= nfn) continue;
      bf16x8 bb = *(const bf16x8*)(Bs + bIdx[fi]);
#pragma unroll
      for (int fm = 0; fm < 3; ++fm)
        acc[fm][fi] = __builtin_amdgcn_mfma_f32_16x16x32_bf16(a[fm], bb, acc[fm][fi], 0, 0, 0);
    }
  }
  __syncthreads();  // frag reads done before S overwrites As/Bs

  float kinvv[5];
#pragma unroll
  for (int fi = 0; fi < 5; ++fi) {
    int col = (fnb + fi) * 16 + l15;
    if (col > 287) col = 287;
    kinvv[fi] = 1.f / fmaxf(sqrtf(kss[tb * kHW + col]), 1e-12f);
  }
#pragma unroll
  for (int fm = 0; fm < 3; ++fm)
#pragma unroll
    for (int reg = 0; reg < 4; ++reg) {
      int row = wm * 48 + fm * 16 + kg * 4 + reg;
      float qi = kTemp / fmaxf(sqrtf(qss[b * kHW + q0 + row]), 1e-12f);
#pragma unroll
      for (int fi = 0; fi < 5; ++fi) {
        if (fi >= nfn) continue;
        S[row][(fnb + fi) * 16 + l15] = qi * kinvv[fi] * acc[fm][fi][reg];
      }
    }
  __syncthreads();

  int l = lane;
  for (int q = wid; q < 96; q += 8) {
    float v[5];
    float m = -3.4e38f;
#pragma unroll
    for (int j = 0; j < 5; ++j) {
      int k = l + 64 * j;
      v[j] = (k < kHW) ? S[q][k] : -3.4e38f;
      m = fmaxf(m, v[j]);
    }
    for (int off = 32; off; off >>= 1) m = fmaxf(m, __shfl_xor(m, off));
    float e[5];
    float s = 0.f;
#pragma unroll
    for (int j = 0; j < 5; ++j) {
      int k = l + 64 * j;
      e[j] = (k < kHW) ? __expf(v[j] - m) : 0.f;
      s += e[j];
    }
    for (int off = 32; off; off >>= 1) s += __shfl_xor(s, off);
    float invs = 1.f / s;
    unsigned short* row = prb + ((size_t)b * kHW + q0 + q) * kHW;
    float dot = 0.f;
#pragma unroll
    for (int j = 0; j < 5; ++j) {
      int k = l + 64 * j;
      if (k < kHW) {
        float p = e[j] * invs;
        row[k] = f2bf(p);
        if (z == 0) dot = fmaf(bf2f(f2bf(p)), mtl[k], dot);
      }
    }
    if (z == 0) {
      for (int off = 32; off; off >>= 1) dot += __shfl_xor(dot, off);
      if (l == 0)
        craw[b * kHW + q0 + q] = maskb[b * kHW + q0 + q] * dot;
    }
  }
}

// -------- loss: comask min-max normalize (per b) + triplet reduce, one block --------
__global__ __launch_bounds__(256) void loss_kernel(const float* __restrict__ dap,
                                                   const float* __restrict__ dan,
                                                   const float* __restrict__ craw,
                                                   float* __restrict__ out) {
  int t = threadIdx.x;
  int wv = t >> 6, l = t & 63;
  __shared__ float sh4a[4], sh4b[4];
  __shared__ float sh2[2];
  float total = 0.f;
#pragma unroll 1
  for (int b = 0; b < kB; ++b) {
    const float* cb = craw + b * kHW;
    float v1 = cb[t];
    float v2 = (t < kHW - 256) ? cb[t + 256] : v1;
    float mnl = fminf(v1, v2), mxl = fmaxf(v1, v2);
    for (int off = 32; off; off >>= 1) {
      mnl = fminf(mnl, __shfl_xor(mnl, off));
      mxl = fmaxf(mxl, __shfl_xor(mxl, off));
    }
    if (l == 0) { sh4a[wv] = mnl; sh4b[wv] = mxl; }
    __syncthreads();
    if (t == 0) {
      float mn = sh4a[0], mx = sh4b[0];
      for (int i = 1; i < 4; ++i) { mn = fminf(mn, sh4a[i]); mx = fmaxf(mx, sh4b[i]); }
      sh2[0] = mn; sh2[1] = mx;
    }
    __syncthreads();
    float mn = sh2[0];
    float inv = 1.f / ((sh2[1] - mn) + 1e-12f);
    {
      int i = b * kHW + t;
      float cn = (v1 - mn) * inv;
      float tr = fmaxf(sqrtf(dap[i]) - sqrtf(dan[i]) + 0.3f, 0.f);
      total = fmaf(cn, tr, total);
    }
    if (t < kHW - 256) {
      int i = b * kHW + t + 256;
      float cn = (v2 - mn) * inv;
      float tr = fmaxf(sqrtf(dap[i]) - sqrtf(dan[i]) + 0.3f, 0.f);
      total = fmaf(cn, tr, total);
    }
    __syncthreads();
  }
  for (int off = 32; off; off >>= 1) total += __shfl_xor(total, off);
  if (l == 0) sh4a[wv] = total;
  __syncthreads();
  if (t == 0)
    out[(size_t)kB * kC * kHW] =
        (sh4a[0] + sh4a[1] + sh4a[2] + sh4a[3]) * (1.f / (float)(kB * kHW));
}

extern "C" void kernel_launch(void* const* d_in, const int* in_sizes, int n_in,
                              void* d_out, int out_size, void* d_ws, size_t ws_size,
                              hipStream_t stream) {
  const float* fv = (const float*)d_in[0];
  const float* ft = (const float*)d_in[1];
  const float* qw = (const float*)d_in[4];
  const float* qb = (const float*)d_in[5];
  const float* kw = (const float*)d_in[6];
  const float* kb = (const float*)d_in[7];
  const int* pos_idx = (const int*)d_in[8];
  const int* neg_idx = (const int*)d_in[9];
  float* out = (float*)d_out;

  constexpr size_t kFQ = (size_t)kB * kCQ * kHW;            // 9,437,184
  constexpr size_t kPR = (size_t)kB * kHW * kHW;            // 5,308,416 (u16)
  float* ws   = (float*)d_ws;
  unsigned short* fqT = (unsigned short*)ws;                // region1 (37.75M)
  unsigned short* fkT = fqT + (size_t)kB * kHW * kCQ;
  unsigned short* prb0 = (unsigned short*)(ws + kFQ);       // region2: pos P
  unsigned short* prb1 = prb0 + kPR;                        //          neg P
  unsigned short* wtq = (unsigned short*)(ws + 2 * kFQ);    // region3
  unsigned short* wtk = wtq + (size_t)9 * kCQ * kC;
  float* maskb   = (float*)(wtk + (size_t)9 * kCQ * kC);
  float* qss     = maskb + kB * kHW;
  float* kss     = qss + kB * kHW;
  float* craw    = kss + kB * kHW;
  float* dap     = craw + kB * kHW;
  float* dan     = dap + kB * kHW;
  if (ws_size < (size_t)113688576) return;

  // zero qss,kss,craw,dap,dan (contiguous)
  zero_kernel<<<dim3((5 * kB * kHW + 255) / 256), 256, 0, stream>>>(qss, 5 * kB * kHW);
  prep_w_kernel<<<dim3(kCQ, 2), 256, 0, stream>>>(qw, kw, wtq, wtk);
  conv_fused_kernel<<<dim3(256), 512, 0, stream>>>(wtq, wtk, qb, kb, fv, ft,
                                                   fqT, fkT, qss, kss, maskb);
  sim_mfma_kernel<<<dim3(3, kB, 2), 512, 0, stream>>>(fqT, fkT, qss, kss, maskb,
                                                      pos_idx, neg_idx, prb0, prb1, craw);
  warp_mfma_kernel<<<dim3(16, kB, 2), 512, 0, stream>>>(fv, ft, prb0, prb1, maskb,
                                                        pos_idx, neg_idx, out, dap, dan);
  loss_kernel<<<dim3(1), 256, 0, stream>>>(dap, dan, craw, out);
}

// Round 20
// 1039.893 us; speedup vs baseline: 6.3794x; 1.1002x over previous
//
#include <hip/hip_runtime.h>
#include <cstdint>
#include <cstddef>

// CMAlign forward. R20: R19 + XCD-clustered flat grids for warp (2048) and sim (384)
// so all blocks of one sample share an XCD -> P/fkT become L2-resident.
// 6 launches: zero, prep_w, conv, sim, warp, loss.
// Shapes: B=64, C=2048, Cq=512, H=24, W=12, HW=288.

namespace {
constexpr int kB    = 64;
constexpr int kHalf = 32;
constexpr int kC    = 2048;
constexpr int kCQ   = 512;
constexpr int kH    = 24;
constexpr int kW    = 12;
constexpr int kHW   = 288;
constexpr float kTemp = 50.0f;
constexpr int kXPlane = 366;  // 16B cells; 5856 B = 96 mod 128 -> kg quadrant offsets
}

typedef __attribute__((ext_vector_type(8))) __bf16 bf16x8;
typedef __attribute__((ext_vector_type(4))) float f32x4;
typedef __attribute__((ext_vector_type(8))) unsigned short ushort8;

__device__ __forceinline__ const float* feat_base(const float* fv, const float* ft, int b) {
  return (b < kHalf) ? (fv + (size_t)b * kC * kHW)
                     : (ft + (size_t)(b - kHalf) * kC * kHW);
}

__device__ __forceinline__ unsigned short f2bf(float f) {
  union { float f; unsigned u; } c; c.f = f;
  unsigned u = c.u;
  unsigned r = (u + 0x7FFFu + ((u >> 16) & 1u)) >> 16;  // RNE
  return (unsigned short)r;
}

__device__ __forceinline__ float bf2f(unsigned short h) {
  union { unsigned u; float f; } c; c.u = ((unsigned)h) << 16;
  return c.f;
}

__device__ __forceinline__ void gload_lds16(const void* g, void* l) {
  __builtin_amdgcn_global_load_lds(
      (const __attribute__((address_space(1))) unsigned int*)g,
      (__attribute__((address_space(3))) unsigned int*)l, 16, 0, 0);
}

__global__ void zero_kernel(float* __restrict__ p, int n) {
  int i = blockIdx.x * 256 + threadIdx.x;
  if (i < n) p[i] = 0.f;
}

// -------- weight prep: w[oc][ic][3][3] fp32 -> MFMA-image wt2 --------
__global__ __launch_bounds__(256) void prep_w_kernel(const float* __restrict__ qw,
                                                     const float* __restrict__ kw,
                                                     unsigned short* __restrict__ wtq,
                                                     unsigned short* __restrict__ wtk) {
  int oc = blockIdx.x;
  int z  = blockIdx.y;
  const float* w = (z ? kw : qw) + (size_t)oc * (kC * 9);
  unsigned short* wt = z ? wtk : wtq;
  __shared__ unsigned short lw[kC * 9];  // [ic][tap]
  int t = threadIdx.x;
#pragma unroll
  for (int it = 0; it < 18; ++it) {
    int i4 = (it * 256 + t) * 4;
    float4 v = *(const float4*)(w + i4);
    lw[i4 + 0] = f2bf(v.x);
    lw[i4 + 1] = f2bf(v.y);
    lw[i4 + 2] = f2bf(v.z);
    lw[i4 + 3] = f2bf(v.w);
  }
  __syncthreads();
  for (int item = t; item < 9 * 256; item += 256) {
    int tap = item >> 8;
    int icb = item & 255;
    ushort8 pk;
#pragma unroll
    for (int j = 0; j < 8; ++j) pk[j] = lw[(icb * 8 + j) * 9 + tap];
    size_t dst16 = (((size_t)(icb >> 2) * 9 + tap) * 32 + (oc >> 4)) * 64
                   + (oc & 15) + (icb & 3) * 16;
    *(ushort8*)(wt + dst16 * 8) = pk;
  }
}

// -------- FUSED MFMA conv + mask (R19, unchanged) --------
__global__ __launch_bounds__(512, 1) void conv_fused_kernel(const unsigned short* __restrict__ wtq,
                                                            const unsigned short* __restrict__ wtk,
                                                            const float* __restrict__ qb,
                                                            const float* __restrict__ kb,
                                                            const float* __restrict__ fv,
                                                            const float* __restrict__ ft,
                                                            unsigned short* __restrict__ fqT,
                                                            unsigned short* __restrict__ fkT,
                                                            float* __restrict__ qss,
                                                            float* __restrict__ kss,
                                                            float* __restrict__ maskb) {
  __shared__ unsigned short Wbuf[2 * 6 * 4096];   // 98304 B (reused: mask red / Ep)
  __shared__ unsigned short Xs[4 * kXPlane * 8];  // 23424 B (reused: mask Mred)
  int t    = threadIdx.x;
  int lane = t & 63;
  int wid  = t >> 6;
  int l15  = lane & 15, kg = lane >> 4;
  int wm   = wid & 1, wn = wid >> 1;  // 2M x 4N
  int n    = blockIdx.x;
  int xcd  = n & 7;
  int oc0  = (xcd >> 1) * 128;
  int b    = ((xcd & 1) << 5) + (n >> 3);
  int f0   = oc0 >> 4;
  const float* fb = feat_base(fv, ft, b);
  const char* wtqB = (const char*)wtq;
  const char* wtkB = (const char*)wtk;

  int  xoff[3];
  bool xvalid[3], xhas[3];
#pragma unroll
  for (int i = 0; i < 3; ++i) {
    int item = i * 512 + t;
    xhas[i] = item < 4 * kXPlane;
    int xkg = item / kXPlane;
    int hp  = item - xkg * kXPlane;
    int hy = hp / 14, hx = hp - hy * 14;
    int y = hy - 1, x = hx - 1;
    bool v = xhas[i] && hp < 364 && (y >= 0 && y < kH && x >= 0 && x < kW);
    xvalid[i] = v;
    xoff[i] = v ? (xkg * 8) * kHW + y * kW + x : 0;
  }

  int aAddr[4];
#pragma unroll
  for (int fm = 0; fm < 4; ++fm)
    aAddr[fm] = (((wm * 4 + fm) * 64) + lane) * 16;
  int nfn = (wn < 2) ? 5 : 4;
  int fnb = (wn < 2) ? wn * 5 : 10 + (wn - 2) * 4;
  int bAddr[5];
#pragma unroll
  for (int fi = 0; fi < 5; ++fi) {
    int p = (fnb + fi) * 16 + l15;
    if (p > 287) p = 287;
    int y = p / kW, x = p - y * kW;
    bAddr[fi] = kg * (kXPlane * 16) + ((y + 1) * 14 + (x + 1)) * 16;
  }

  f32x4 acc[2][4][5];
#pragma unroll
  for (int cv = 0; cv < 2; ++cv)
#pragma unroll
    for (int fm = 0; fm < 4; ++fm)
#pragma unroll
      for (int fi = 0; fi < 5; ++fi) acc[cv][fm][fi] = (f32x4){0.f, 0.f, 0.f, 0.f};

  float msum0 = 0.f, msum1 = 0.f, msum2 = 0.f;  // per-item sum of x^2 (mask)

  char* WsB = (char*)Wbuf;
  char* XsB = (char*)Xs;
  int wavebase = t & ~63;

#pragma unroll
  for (int i = 0; i < 3; ++i) {
    if (xhas[i] && !xvalid[i]) {
      ushort8 pk;
#pragma unroll
      for (int j = 0; j < 8; ++j) pk[j] = 0;
      *(ushort8*)(XsB + (size_t)(i * 512 + t) * 16) = pk;
    }
  }
#pragma unroll
  for (int r = 0; r < 3; ++r) {
    size_t g16 = ((size_t)r * 32 + f0 + wid) * 64 + lane;
    gload_lds16(wtqB + g16 * 16, WsB + (size_t)(r * 2 + 0) * 8192 + wavebase * 16);
    gload_lds16(wtkB + g16 * 16, WsB + (size_t)(r * 2 + 1) * 8192 + wavebase * 16);
  }

  int buf = 0;
#pragma unroll 1
  for (int chunk = 0; chunk < 64; ++chunk) {
    int ic0 = chunk * 32;
    {
      float xv[3][8];
#pragma unroll
      for (int i = 0; i < 3; ++i)
        if (xvalid[i]) {
          const float* s = fb + (size_t)ic0 * kHW + xoff[i];
#pragma unroll
          for (int j = 0; j < 8; ++j) xv[i][j] = s[(size_t)j * kHW];
        }
      if (xvalid[0]) {
#pragma unroll
        for (int j = 0; j < 8; ++j) msum0 = fmaf(xv[0][j], xv[0][j], msum0);
      }
      if (xvalid[1]) {
#pragma unroll
        for (int j = 0; j < 8; ++j) msum1 = fmaf(xv[1][j], xv[1][j], msum1);
      }
      if (xvalid[2]) {
#pragma unroll
        for (int j = 0; j < 8; ++j) msum2 = fmaf(xv[2][j], xv[2][j], msum2);
      }
#pragma unroll
      for (int i = 0; i < 3; ++i) {
        if (!xvalid[i]) continue;
        ushort8 pk;
#pragma unroll
        for (int j = 0; j < 8; ++j) pk[j] = f2bf(xv[i][j]);
        *(ushort8*)(XsB + (size_t)(i * 512 + t) * 16) = pk;
      }
    }
    __syncthreads();

#pragma unroll 1
    for (int g = 0; g < 3; ++g) {
      bool hn = (g < 2) || (chunk < 63);
      if (hn) {
        int nchunk = (g < 2) ? chunk : chunk + 1;
        int ng     = (g < 2) ? g + 1 : 0;
#pragma unroll
        for (int r = 0; r < 3; ++r) {
          size_t g16 = ((size_t)(nchunk * 9 + ng * 3 + r) * 32 + f0 + wid) * 64 + lane;
          gload_lds16(wtqB + g16 * 16,
                      WsB + (size_t)((buf ^ 1) * 6 + r * 2 + 0) * 8192 + wavebase * 16);
          gload_lds16(wtkB + g16 * 16,
                      WsB + (size_t)((buf ^ 1) * 6 + r * 2 + 1) * 8192 + wavebase * 16);
        }
      }
#pragma unroll
      for (int r = 0; r < 3; ++r) {
        int tap = g * 3 + r;
        int d16 = ((tap / 3 - 1) * 14 + (tap % 3 - 1)) * 16;
        bf16x8 af[2][4];
#pragma unroll
        for (int cv = 0; cv < 2; ++cv)
#pragma unroll
          for (int fm = 0; fm < 4; ++fm)
            af[cv][fm] = *(const bf16x8*)(WsB + (size_t)(buf * 6 + r * 2 + cv) * 8192 + aAddr[fm]);
#pragma unroll
        for (int fi = 0; fi < 5; ++fi) {
          if (fi >= nfn) continue;
          bf16x8 bb = *(const bf16x8*)(XsB + bAddr[fi] + d16);
#pragma unroll
          for (int cv = 0; cv < 2; ++cv)
#pragma unroll
            for (int fm = 0; fm < 4; ++fm)
              acc[cv][fm][fi] =
                  __builtin_amdgcn_mfma_f32_16x16x32_bf16(af[cv][fm], bb, acc[cv][fm][fi], 0, 0, 0);
        }
      }
      __syncthreads();
      buf ^= 1;
    }
  }

  // ---- mask reduce: only tile-0 blocks (one per b) ----
  if (oc0 == 0) {
    float* Mred = (float*)Xs;
    float msum[3] = {msum0, msum1, msum2};
#pragma unroll
    for (int i = 0; i < 3; ++i) {
      if (!xvalid[i]) continue;
      int item = i * 512 + t;
      int xkg = item / kXPlane;
      int hp  = item - xkg * kXPlane;
      int y = hp / 14 - 1, x = hp % 14 - 1;
      Mred[xkg * kHW + y * kW + x] = msum[i];
    }
    __syncthreads();
    float nv = 0.f;
    if (t < kHW)
      nv = sqrtf(Mred[t] + Mred[kHW + t] + Mred[2 * kHW + t] + Mred[3 * kHW + t]);
    float* red = (float*)Wbuf;
    red[t] = (t < kHW) ? nv : 3.4e38f;
    __syncthreads();
    float mn;
    {
      float m = 3.4e38f;
      if (t < 64) {
        for (int i = t; i < 512; i += 64) m = fminf(m, red[i]);
        for (int off = 32; off; off >>= 1) m = fminf(m, __shfl_xor(m, off));
      }
      __syncthreads();
      if (t == 0) red[0] = m;
      __syncthreads();
      mn = red[0];
      __syncthreads();
    }
    red[t] = (t < kHW) ? nv : -3.4e38f;
    __syncthreads();
    float mx;
    {
      float m = -3.4e38f;
      if (t < 64) {
        for (int i = t; i < 512; i += 64) m = fmaxf(m, red[i]);
        for (int off = 32; off; off >>= 1) m = fmaxf(m, __shfl_xor(m, off));
      }
      __syncthreads();
      if (t == 0) red[0] = m;
      __syncthreads();
      mx = red[0];
    }
    if (t < kHW) maskb[b * kHW + t] = (nv - mn) / ((mx - mn) + 1e-12f);
    __syncthreads();
  }

  // ---- epilogue: per cv (fully unrolled), Ep stage, sumsq, transposed store ----
  unsigned short* Ep = Wbuf;
#pragma unroll
  for (int cv = 0; cv < 2; ++cv) {
    const float* bias = cv ? kb : qb;
    float* ssq = cv ? kss : qss;
#pragma unroll
    for (int fi = 0; fi < 5; ++fi) {
      if (fi >= nfn) continue;
      int p = (fnb + fi) * 16 + l15;
      float ps = 0.f;
#pragma unroll
      for (int fm = 0; fm < 4; ++fm)
#pragma unroll
        for (int reg = 0; reg < 4; ++reg) {
          int ocl = wm * 64 + fm * 16 + kg * 4 + reg;
          float v = acc[cv][fm][fi][reg] + bias[oc0 + ocl];
          ps = fmaf(v, v, ps);
          Ep[p * 136 + ocl] = f2bf(v);
        }
      ps += __shfl_xor(ps, 16);
      ps += __shfl_xor(ps, 32);
      if (kg == 0) atomicAdd(ssq + b * kHW + p, ps);
    }
    __syncthreads();
    unsigned short* dstT = (cv ? fkT : fqT) + (size_t)b * kHW * kCQ + oc0;
#pragma unroll
    for (int it = 0; it < 9; ++it) {
      int item = it * 512 + t;
      int p = item >> 4, j = item & 15;
      *(ushort8*)(dstT + (size_t)p * kCQ + j * 8) =
          *(const ushort8*)(Ep + p * 136 + j * 8);
    }
    __syncthreads();
  }
}

// -------- warp GEMM via MFMA, both branches; XCD-clustered flat grid (2048) --------
__global__ __launch_bounds__(512) void warp_mfma_kernel(const float* __restrict__ fv,
                                                        const float* __restrict__ ft,
                                                        const unsigned short* __restrict__ prb0,
                                                        const unsigned short* __restrict__ prb1,
                                                        const float* __restrict__ maskp,
                                                        const int* __restrict__ pos_idx,
                                                        const int* __restrict__ neg_idx,
                                                        float* __restrict__ outp,
                                                        float* __restrict__ dap,
                                                        float* __restrict__ dan) {
  __shared__ unsigned short AsHi[128 * 32];
  __shared__ unsigned short AsLo[128 * 32];
  __shared__ unsigned short Bs[288 * 32];
  int t    = threadIdx.x;
  int lane = t & 63;
  int wid  = t >> 6;
  int l15  = lane & 15, kg = lane >> 4;
  int wm   = wid >> 1, wn = wid & 1;
  // XCD-clustered decode: all 32 blocks (16 c-tiles x 2 z) of sample b on one XCD
  int n    = blockIdx.x;
  int xcd  = n & 7;
  int m    = n >> 3;            // 0..255
  int b    = xcd + ((m & 7) << 3);
  int rest = m >> 3;            // 0..31
  int c0   = (rest & 15) * 128;
  int z    = rest >> 4;
  int write_out = (z == 0);
  const unsigned short* prb = z ? prb1 : prb0;
  float* dsq = z ? dan : dap;
  int tb   = (z ? neg_idx : pos_idx)[b];
  const float* tgt = feat_base(fv, ft, tb);
  const float* fb  = feat_base(fv, ft, b);

  int ar = t >> 2, as = t & 3;
  int aslot = as ^ ((ar ^ (ar >> 2)) & 3);
  unsigned short* aDstHi = AsHi + ar * 32 + aslot * 8;
  unsigned short* aDstLo = AsLo + ar * 32 + aslot * 8;

  int aIdx[2];
#pragma unroll
  for (int fm = 0; fm < 2; ++fm) {
    int r = wm * 32 + fm * 16 + l15;
    aIdx[fm] = r * 32 + (kg ^ ((r ^ (r >> 2)) & 3)) * 8;
  }
  int bIdx[9];
#pragma unroll
  for (int fn = 0; fn < 9; ++fn) {
    int q = wn * 144 + fn * 16 + l15;
    bIdx[fn] = q * 32 + (kg ^ ((q ^ (q >> 2)) & 3)) * 8;
  }

  f32x4 acc[2][9];
#pragma unroll
  for (int fm = 0; fm < 2; ++fm)
#pragma unroll
    for (int fn = 0; fn < 9; ++fn) acc[fm][fn] = (f32x4){0.f, 0.f, 0.f, 0.f};

#pragma unroll 1
  for (int chunk = 0; chunk < 9; ++chunk) {
    int k0 = chunk * 32;
    __syncthreads();
    {
      const float* s = tgt + (size_t)(c0 + ar) * kHW + k0 + as * 8;
      float4 v0 = *(const float4*)(s);
      float4 v1 = *(const float4*)(s + 4);
      float xs[8] = {v0.x, v0.y, v0.z, v0.w, v1.x, v1.y, v1.z, v1.w};
      ushort8 hi, lo;
#pragma unroll
      for (int j = 0; j < 8; ++j) {
        unsigned short h = f2bf(xs[j]);
        hi[j] = h;
        lo[j] = f2bf(xs[j] - bf2f(h));
      }
      *(ushort8*)aDstHi = hi;
      *(ushort8*)aDstLo = lo;
    }
#pragma unroll
    for (int i = 0; i < 3; ++i) {
      int item = i * 512 + t;
      if (item < 1152) {
        int q = item >> 2, s = item & 3;
        ushort8 v = *(const ushort8*)(prb + ((size_t)b * kHW + q) * kHW + k0 + s * 8);
        *(ushort8*)(Bs + q * 32 + (s ^ ((q ^ (q >> 2)) & 3)) * 8) = v;
      }
    }
    __syncthreads();
    bf16x8 ah0 = *(const bf16x8*)(AsHi + aIdx[0]);
    bf16x8 al0 = *(const bf16x8*)(AsLo + aIdx[0]);
    bf16x8 ah1 = *(const bf16x8*)(AsHi + aIdx[1]);
    bf16x8 al1 = *(const bf16x8*)(AsLo + aIdx[1]);
#pragma unroll
    for (int fn = 0; fn < 9; ++fn) {
      bf16x8 bb = *(const bf16x8*)(Bs + bIdx[fn]);
      acc[0][fn] = __builtin_amdgcn_mfma_f32_16x16x32_bf16(ah0, bb, acc[0][fn], 0, 0, 0);
      acc[0][fn] = __builtin_amdgcn_mfma_f32_16x16x32_bf16(al0, bb, acc[0][fn], 0, 0, 0);
      acc[1][fn] = __builtin_amdgcn_mfma_f32_16x16x32_bf16(ah1, bb, acc[1][fn], 0, 0, 0);
      acc[1][fn] = __builtin_amdgcn_mfma_f32_16x16x32_bf16(al1, bb, acc[1][fn], 0, 0, 0);
    }
  }

#pragma unroll
  for (int fn = 0; fn < 9; ++fn) {
    int q = wn * 144 + fn * 16 + l15;
    float mj = maskp[b * kHW + q];
    float psum = 0.f;
#pragma unroll
    for (int fm = 0; fm < 2; ++fm) {
#pragma unroll
      for (int reg = 0; reg < 4; ++reg) {
        int c = c0 + wm * 32 + fm * 16 + kg * 4 + reg;
        float fvv = fb[(size_t)c * kHW + q];
        float Wv  = acc[fm][fn][reg];
        float d   = mj * (fvv - Wv) + 1e-6f;
        psum      = fmaf(d, d, psum);
        if (write_out)
          outp[((size_t)b * kC + c) * kHW + q] = mj * Wv + (1.f - mj) * fvv;
      }
    }
    psum += __shfl_xor(psum, 16);
    psum += __shfl_xor(psum, 32);
    if (lane < 16) atomicAdd(&dsq[b * kHW + q], psum);
  }
}

// -------- sim via MFMA + softmax + comask_raw (z=0); XCD-clustered flat grid (384) --------
__global__ __launch_bounds__(512, 1) void sim_mfma_kernel(const unsigned short* __restrict__ fqT,
                                                          const unsigned short* __restrict__ fkT,
                                                          const float* __restrict__ qss,
                                                          const float* __restrict__ kss,
                                                          const float* __restrict__ maskb,
                                                          const int* __restrict__ pos_idx,
                                                          const int* __restrict__ neg_idx,
                                                          unsigned short* __restrict__ prb0,
                                                          unsigned short* __restrict__ prb1,
                                                          float* __restrict__ craw) {
  __shared__ float Sbuf[96 * 289];  // 110976 B; As @0 (6KB), Bs @6144 (18KB) alias
  __shared__ float mtl[kHW];        // mask[tb] for comask dot
  unsigned short* As = (unsigned short*)Sbuf;
  unsigned short* Bs = (unsigned short*)((char*)Sbuf + 6144);
  float (*S)[289] = (float(*)[289])Sbuf;
  int t    = threadIdx.x;
  int lane = t & 63;
  int wid  = t >> 6;
  int l15  = lane & 15, kg = lane >> 4;
  int wm   = wid & 1, wn = wid >> 1;  // 2M x 4N
  // XCD-clustered decode: all 6 blocks (3 q-tiles x 2 z) of sample b on one XCD
  int n    = blockIdx.x;
  int xcd  = n & 7;
  int m    = n >> 3;            // 0..47
  int b    = xcd + ((m & 7) << 3);
  int rest = m >> 3;            // 0..5
  int q0   = (rest % 3) * 96;
  int z    = rest / 3;
  int tb   = (z ? neg_idx : pos_idx)[b];
  unsigned short* prb = z ? prb1 : prb0;
  const unsigned short* fqb = fqT + ((size_t)b * kHW + q0) * kCQ;
  const unsigned short* fkb = fkT + (size_t)tb * kHW * kCQ;

  if (t < kHW) mtl[t] = maskb[tb * kHW + t];

  int aIdx[3];
#pragma unroll
  for (int fm = 0; fm < 3; ++fm) {
    int r = wm * 48 + fm * 16 + l15;
    aIdx[fm] = r * 32 + (kg ^ ((r ^ (r >> 2)) & 3)) * 8;
  }
  int nfn = (wn < 2) ? 5 : 4;
  int fnb = (wn < 2) ? wn * 5 : 10 + (wn - 2) * 4;
  int bIdx[5];
#pragma unroll
  for (int fi = 0; fi < 5; ++fi) {
    int kr = (fnb + fi) * 16 + l15;
    if (kr > 287) kr = 287;
    bIdx[fi] = kr * 32 + (kg ^ ((kr ^ (kr >> 2)) & 3)) * 8;
  }

  f32x4 acc[3][5];
#pragma unroll
  for (int fm = 0; fm < 3; ++fm)
#pragma unroll
    for (int fi = 0; fi < 5; ++fi) acc[fm][fi] = (f32x4){0.f, 0.f, 0.f, 0.f};

#pragma unroll 1
  for (int chunk = 0; chunk < 16; ++chunk) {
    int c0 = chunk * 32;
    __syncthreads();
    if (t < 384) {
      int ar = t >> 2, as = t & 3;
      ushort8 v = *(const ushort8*)(fqb + (size_t)ar * kCQ + c0 + as * 8);
      int slot = as ^ ((ar ^ (ar >> 2)) & 3);
      *(ushort8*)(As + ar * 32 + slot * 8) = v;
    }
#pragma unroll
    for (int i = 0; i < 3; ++i) {
      int item = i * 512 + t;
      if (item < 1152) {
        int kr = item >> 2, ks = item & 3;
        ushort8 v = *(const ushort8*)(fkb + (size_t)kr * kCQ + c0 + ks * 8);
        int slot = ks ^ ((kr ^ (kr >> 2)) & 3);
        *(ushort8*)(Bs + kr * 32 + slot * 8) = v;
      }
    }
    __syncthreads();
    bf16x8 a[3];
#pragma unroll
    for (int fm = 0; fm < 3; ++fm) a[fm] = *(const bf16x8*)(As + aIdx[fm]);
#pragma unroll
    for (int fi = 0; fi < 5; ++fi) {
      if (fi >= nfn) continue;
      bf16x8 bb = *(const bf16x8*)(Bs + bIdx[fi]);
#pragma unroll
      for (int fm = 0; fm < 3; ++fm)
        acc[fm][fi] = __builtin_amdgcn_mfma_f32_16x16x32_bf16(a[fm], bb, acc[fm][fi], 0, 0, 0);
    }
  }
  __syncthreads();  // frag reads done before S overwrites As/Bs

  float kinvv[5];
#pragma unroll
  for (int fi = 0; fi < 5; ++fi) {
    int col = (fnb + fi) * 16 + l15;
    if (col > 287) col = 287;
    kinvv[fi] = 1.f / fmaxf(sqrtf(kss[tb * kHW + col]), 1e-12f);
  }
#pragma unroll
  for (int fm = 0; fm < 3; ++fm)
#pragma unroll
    for (int reg = 0; reg < 4; ++reg) {
      int row = wm * 48 + fm * 16 + kg * 4 + reg;
      float qi = kTemp / fmaxf(sqrtf(qss[b * kHW + q0 + row]), 1e-12f);
#pragma unroll
      for (int fi = 0; fi < 5; ++fi) {
        if (fi >= nfn) continue;
        S[row][(fnb + fi) * 16 + l15] = qi * kinvv[fi] * acc[fm][fi][reg];
      }
    }
  __syncthreads();

  int l = lane;
  for (int q = wid; q < 96; q += 8) {
    float v[5];
    float m2 = -3.4e38f;
#pragma unroll
    for (int j = 0; j < 5; ++j) {
      int k = l + 64 * j;
      v[j] = (k < kHW) ? S[q][k] : -3.4e38f;
      m2 = fmaxf(m2, v[j]);
    }
    for (int off = 32; off; off >>= 1) m2 = fmaxf(m2, __shfl_xor(m2, off));
    float e[5];
    float s = 0.f;
#pragma unroll
    for (int j = 0; j < 5; ++j) {
      int k = l + 64 * j;
      e[j] = (k < kHW) ? __expf(v[j] - m2) : 0.f;
      s += e[j];
    }
    for (int off = 32; off; off >>= 1) s += __shfl_xor(s, off);
    float invs = 1.f / s;
    unsigned short* row = prb + ((size_t)b * kHW + q0 + q) * kHW;
    float dot = 0.f;
#pragma unroll
    for (int j = 0; j < 5; ++j) {
      int k = l + 64 * j;
      if (k < kHW) {
        float p = e[j] * invs;
        row[k] = f2bf(p);
        if (z == 0) dot = fmaf(bf2f(f2bf(p)), mtl[k], dot);
      }
    }
    if (z == 0) {
      for (int off = 32; off; off >>= 1) dot += __shfl_xor(dot, off);
      if (l == 0)
        craw[b * kHW + q0 + q] = maskb[b * kHW + q0 + q] * dot;
    }
  }
}

// -------- loss: comask min-max normalize (per b) + triplet reduce, one block --------
__global__ __launch_bounds__(256) void loss_kernel(const float* __restrict__ dap,
                                                   const float* __restrict__ dan,
                                                   const float* __restrict__ craw,
                                                   float* __restrict__ out) {
  int t = threadIdx.x;
  int wv = t >> 6, l = t & 63;
  __shared__ float sh4a[4], sh4b[4];
  __shared__ float sh2[2];
  float total = 0.f;
#pragma unroll 1
  for (int b = 0; b < kB; ++b) {
    const float* cb = craw + b * kHW;
    float v1 = cb[t];
    float v2 = (t < kHW - 256) ? cb[t + 256] : v1;
    float mnl = fminf(v1, v2), mxl = fmaxf(v1, v2);
    for (int off = 32; off; off >>= 1) {
      mnl = fminf(mnl, __shfl_xor(mnl, off));
      mxl = fmaxf(mxl, __shfl_xor(mxl, off));
    }
    if (l == 0) { sh4a[wv] = mnl; sh4b[wv] = mxl; }
    __syncthreads();
    if (t == 0) {
      float mn = sh4a[0], mx = sh4b[0];
      for (int i = 1; i < 4; ++i) { mn = fminf(mn, sh4a[i]); mx = fmaxf(mx, sh4b[i]); }
      sh2[0] = mn; sh2[1] = mx;
    }
    __syncthreads();
    float mn = sh2[0];
    float inv = 1.f / ((sh2[1] - mn) + 1e-12f);
    {
      int i = b * kHW + t;
      float cn = (v1 - mn) * inv;
      float tr = fmaxf(sqrtf(dap[i]) - sqrtf(dan[i]) + 0.3f, 0.f);
      total = fmaf(cn, tr, total);
    }
    if (t < kHW - 256) {
      int i = b * kHW + t + 256;
      float cn = (v2 - mn) * inv;
      float tr = fmaxf(sqrtf(dap[i]) - sqrtf(dan[i]) + 0.3f, 0.f);
      total = fmaf(cn, tr, total);
    }
    __syncthreads();
  }
  for (int off = 32; off; off >>= 1) total += __shfl_xor(total, off);
  if (l == 0) sh4a[wv] = total;
  __syncthreads();
  if (t == 0)
    out[(size_t)kB * kC * kHW] =
        (sh4a[0] + sh4a[1] + sh4a[2] + sh4a[3]) * (1.f / (float)(kB * kHW));
}

extern "C" void kernel_launch(void* const* d_in, const int* in_sizes, int n_in,
                              void* d_out, int out_size, void* d_ws, size_t ws_size,
                              hipStream_t stream) {
  const float* fv = (const float*)d_in[0];
  const float* ft = (const float*)d_in[1];
  const float* qw = (const float*)d_in[4];
  const float* qb = (const float*)d_in[5];
  const float* kw = (const float*)d_in[6];
  const float* kb = (const float*)d_in[7];
  const int* pos_idx = (const int*)d_in[8];
  const int* neg_idx = (const int*)d_in[9];
  float* out = (float*)d_out;

  constexpr size_t kFQ = (size_t)kB * kCQ * kHW;            // 9,437,184
  constexpr size_t kPR = (size_t)kB * kHW * kHW;            // 5,308,416 (u16)
  float* ws   = (float*)d_ws;
  unsigned short* fqT = (unsigned short*)ws;                // region1 (37.75M)
  unsigned short* fkT = fqT + (size_t)kB * kHW * kCQ;
  unsigned short* prb0 = (unsigned short*)(ws + kFQ);       // region2: pos P
  unsigned short* prb1 = prb0 + kPR;                        //          neg P
  unsigned short* wtq = (unsigned short*)(ws + 2 * kFQ);    // region3
  unsigned short* wtk = wtq + (size_t)9 * kCQ * kC;
  float* maskb   = (float*)(wtk + (size_t)9 * kCQ * kC);
  float* qss     = maskb + kB * kHW;
  float* kss     = qss + kB * kHW;
  float* craw    = kss + kB * kHW;
  float* dap     = craw + kB * kHW;
  float* dan     = dap + kB * kHW;
  if (ws_size < (size_t)113688576) return;

  zero_kernel<<<dim3((5 * kB * kHW + 255) / 256), 256, 0, stream>>>(qss, 5 * kB * kHW);
  prep_w_kernel<<<dim3(kCQ, 2), 256, 0, stream>>>(qw, kw, wtq, wtk);
  conv_fused_kernel<<<dim3(256), 512, 0, stream>>>(wtq, wtk, qb, kb, fv, ft,
                                                   fqT, fkT, qss, kss, maskb);
  sim_mfma_kernel<<<dim3(384), 512, 0, stream>>>(fqT, fkT, qss, kss, maskb,
                                                 pos_idx, neg_idx, prb0, prb1, craw);
  warp_mfma_kernel<<<dim3(2048), 512, 0, stream>>>(fv, ft, prb0, prb1, maskb,
                                                   pos_idx, neg_idx, out, dap, dan);
  loss_kernel<<<dim3(1), 256, 0, stream>>>(dap, dan, craw, out);
}

// Round 21
// 1006.046 us; speedup vs baseline: 6.5940x; 1.0336x over previous
//
#include <hip/hip_runtime.h>
#include <cstdint>
#include <cstddef>

// CMAlign forward. R21: conv at TRUE 2 blocks/CU — M=64 tile, grid=512,
// launch_bounds(512,4) with engineered regs<=128 (acc 80, per-i X staging),
// LDS 72.6KB (Wbuf 48K 3-tap-dbuf + Xs 23.4K), b-pinned XCD decode (X reuse x8,
// W chunk working set ~590KB/XCD L2-fits). sim/warp = R20 (XCD-clustered).
// Shapes: B=64, C=2048, Cq=512, H=24, W=12, HW=288.

namespace {
constexpr int kB    = 64;
constexpr int kHalf = 32;
constexpr int kC    = 2048;
constexpr int kCQ   = 512;
constexpr int kH    = 24;
constexpr int kW    = 12;
constexpr int kHW   = 288;
constexpr float kTemp = 50.0f;
constexpr int kXPlane = 366;  // 16B cells; 5856 B = 96 mod 128 -> kg quadrant offsets
}

typedef __attribute__((ext_vector_type(8))) __bf16 bf16x8;
typedef __attribute__((ext_vector_type(4))) float f32x4;
typedef __attribute__((ext_vector_type(8))) unsigned short ushort8;

__device__ __forceinline__ const float* feat_base(const float* fv, const float* ft, int b) {
  return (b < kHalf) ? (fv + (size_t)b * kC * kHW)
                     : (ft + (size_t)(b - kHalf) * kC * kHW);
}

__device__ __forceinline__ unsigned short f2bf(float f) {
  union { float f; unsigned u; } c; c.f = f;
  unsigned u = c.u;
  unsigned r = (u + 0x7FFFu + ((u >> 16) & 1u)) >> 16;  // RNE
  return (unsigned short)r;
}

__device__ __forceinline__ float bf2f(unsigned short h) {
  union { unsigned u; float f; } c; c.u = ((unsigned)h) << 16;
  return c.f;
}

__device__ __forceinline__ void gload_lds16(const void* g, void* l) {
  __builtin_amdgcn_global_load_lds(
      (const __attribute__((address_space(1))) unsigned int*)g,
      (__attribute__((address_space(3))) unsigned int*)l, 16, 0, 0);
}

__global__ void zero_kernel(float* __restrict__ p, int n) {
  int i = blockIdx.x * 256 + threadIdx.x;
  if (i < n) p[i] = 0.f;
}

// -------- weight prep: w[oc][ic][3][3] fp32 -> MFMA-image wt2 --------
__global__ __launch_bounds__(256) void prep_w_kernel(const float* __restrict__ qw,
                                                     const float* __restrict__ kw,
                                                     unsigned short* __restrict__ wtq,
                                                     unsigned short* __restrict__ wtk) {
  int oc = blockIdx.x;
  int z  = blockIdx.y;
  const float* w = (z ? kw : qw) + (size_t)oc * (kC * 9);
  unsigned short* wt = z ? wtk : wtq;
  __shared__ unsigned short lw[kC * 9];  // [ic][tap]
  int t = threadIdx.x;
#pragma unroll
  for (int it = 0; it < 18; ++it) {
    int i4 = (it * 256 + t) * 4;
    float4 v = *(const float4*)(w + i4);
    lw[i4 + 0] = f2bf(v.x);
    lw[i4 + 1] = f2bf(v.y);
    lw[i4 + 2] = f2bf(v.z);
    lw[i4 + 3] = f2bf(v.w);
  }
  __syncthreads();
  for (int item = t; item < 9 * 256; item += 256) {
    int tap = item >> 8;
    int icb = item & 255;
    ushort8 pk;
#pragma unroll
    for (int j = 0; j < 8; ++j) pk[j] = lw[(icb * 8 + j) * 9 + tap];
    size_t dst16 = (((size_t)(icb >> 2) * 9 + tap) * 32 + (oc >> 4)) * 64
                   + (oc & 15) + (icb & 3) * 16;
    *(ushort8*)(wt + dst16 * 8) = pk;
  }
}

// -------- FUSED MFMA conv + mask: M=64 tile, grid 512, 2 blocks/CU --------
// Wbuf[2 buf][6 slot = tap*2+cv][frag4][lane64][8] = 49152 B; Xs 23424 B.
// 8 waves as 2M x 4N: acc[2cv][2fm][<=5fi] = 80 regs.
__global__ __launch_bounds__(512, 4) void conv_fused_kernel(const unsigned short* __restrict__ wtq,
                                                            const unsigned short* __restrict__ wtk,
                                                            const float* __restrict__ qb,
                                                            const float* __restrict__ kb,
                                                            const float* __restrict__ fv,
                                                            const float* __restrict__ ft,
                                                            unsigned short* __restrict__ fqT,
                                                            unsigned short* __restrict__ fkT,
                                                            float* __restrict__ qss,
                                                            float* __restrict__ kss,
                                                            float* __restrict__ maskb) {
  __shared__ unsigned short Wbuf[2 * 6 * 2048];   // 49152 B (epilogue: Ep[288][72] 41.5KB)
  __shared__ unsigned short Xs[4 * kXPlane * 8];  // 23424 B (mask: Mred)
  int t    = threadIdx.x;
  int lane = t & 63;
  int l15  = lane & 15, kg = lane >> 4;
  int wid  = t >> 6;
  int wm   = wid & 1, wn = wid >> 1;  // 2M x 4N
  // b-pinned XCD decode: all 8 Mtiles of sample b on one XCD
  int n    = blockIdx.x;
  int xcd  = n & 7;
  int idx  = n >> 3;              // 0..63
  int b    = xcd + ((idx & 7) << 3);
  int mt   = idx >> 3;            // 0..7
  int oc0  = mt * 64;
  int f0   = mt * 4;              // frag base (16-oc units)
  const float* fb = feat_base(fv, ft, b);
  const char* wtqB = (const char*)wtq;
  const char* wtkB = (const char*)wtk;

  // Xs staging descriptors
  int  xoff[3];
  bool xvalid[3], xhas[3];
#pragma unroll
  for (int i = 0; i < 3; ++i) {
    int item = i * 512 + t;
    xhas[i] = item < 4 * kXPlane;
    int xkg = item / kXPlane;
    int hp  = item - xkg * kXPlane;
    int hy = hp / 14, hx = hp - hy * 14;
    int y = hy - 1, x = hx - 1;
    bool v = xhas[i] && hp < 364 && (y >= 0 && y < kH && x >= 0 && x < kW);
    xvalid[i] = v;
    xoff[i] = v ? (xkg * 8) * kHW + y * kW + x : 0;
  }

  // W staging decode (wave-uniform per k): item i = k*512+t -> slot s=i>>8, frag=(i>>6)&3
  // A-frag read addrs within a 4KB slot
  int aAddr[2];
#pragma unroll
  for (int fm = 0; fm < 2; ++fm)
    aAddr[fm] = (((wm * 2 + fm) * 64) + lane) * 16;
  int nfn = (wn < 2) ? 5 : 4;
  int fnb = (wn < 2) ? wn * 5 : 10 + (wn - 2) * 4;
  int bAddr[5];
#pragma unroll
  for (int fi = 0; fi < 5; ++fi) {
    int p = (fnb + fi) * 16 + l15;
    if (p > 287) p = 287;
    int y = p / kW, x = p - y * kW;
    bAddr[fi] = kg * (kXPlane * 16) + ((y + 1) * 14 + (x + 1)) * 16;
  }

  f32x4 acc[2][2][5];
#pragma unroll
  for (int cv = 0; cv < 2; ++cv)
#pragma unroll
    for (int fm = 0; fm < 2; ++fm)
#pragma unroll
      for (int fi = 0; fi < 5; ++fi) acc[cv][fm][fi] = (f32x4){0.f, 0.f, 0.f, 0.f};

  float msum0 = 0.f, msum1 = 0.f, msum2 = 0.f;

  char* WsB = (char*)Wbuf;
  char* XsB = (char*)Xs;
  int wavebase = t & ~63;

  // zero halo/pad X cells once
#pragma unroll
  for (int i = 0; i < 3; ++i) {
    if (xhas[i] && !xvalid[i]) {
      ushort8 pk;
#pragma unroll
      for (int j = 0; j < 8; ++j) pk[j] = 0;
      *(ushort8*)(XsB + (size_t)(i * 512 + t) * 16) = pk;
    }
  }
  // prologue: stage group (chunk0, g0) -> buf0 (3 gloads/thread)
#pragma unroll
  for (int k = 0; k < 3; ++k) {
    int i  = k * 512 + t;
    int s  = i >> 8;           // slot 0..5 (wave-uniform)
    int cv = s & 1, rr = s >> 1;
    int frag = (i >> 6) & 3;   // wave-uniform
    const char* wsrc = cv ? wtkB : wtqB;
    size_t g16 = ((size_t)rr * 32 + f0 + frag) * 64 + lane;
    gload_lds16(wsrc + g16 * 16, WsB + (size_t)(k * 512 + wavebase) * 16);
  }

  int buf = 0;
#pragma unroll 1
  for (int chunk = 0; chunk < 64; ++chunk) {
    int ic0 = chunk * 32;
    // X staging: per-i (short register lifetimes)
    if (xvalid[0]) {
      const float* s = fb + (size_t)ic0 * kHW + xoff[0];
      float xv[8];
#pragma unroll
      for (int j = 0; j < 8; ++j) xv[j] = s[(size_t)j * kHW];
      ushort8 pk;
#pragma unroll
      for (int j = 0; j < 8; ++j) { msum0 = fmaf(xv[j], xv[j], msum0); pk[j] = f2bf(xv[j]); }
      *(ushort8*)(XsB + (size_t)t * 16) = pk;
    }
    if (xvalid[1]) {
      const float* s = fb + (size_t)ic0 * kHW + xoff[1];
      float xv[8];
#pragma unroll
      for (int j = 0; j < 8; ++j) xv[j] = s[(size_t)j * kHW];
      ushort8 pk;
#pragma unroll
      for (int j = 0; j < 8; ++j) { msum1 = fmaf(xv[j], xv[j], msum1); pk[j] = f2bf(xv[j]); }
      *(ushort8*)(XsB + (size_t)(512 + t) * 16) = pk;
    }
    if (xvalid[2]) {
      const float* s = fb + (size_t)ic0 * kHW + xoff[2];
      float xv[8];
#pragma unroll
      for (int j = 0; j < 8; ++j) xv[j] = s[(size_t)j * kHW];
      ushort8 pk;
#pragma unroll
      for (int j = 0; j < 8; ++j) { msum2 = fmaf(xv[j], xv[j], msum2); pk[j] = f2bf(xv[j]); }
      *(ushort8*)(XsB + (size_t)(1024 + t) * 16) = pk;
    }
    __syncthreads();  // X visible + prior W staging drained

#pragma unroll 1
    for (int g = 0; g < 3; ++g) {
      bool hn = (g < 2) || (chunk < 63);
      if (hn) {
        int nchunk = (g < 2) ? chunk : chunk + 1;
        int ng     = (g < 2) ? g + 1 : 0;
#pragma unroll
        for (int k = 0; k < 3; ++k) {
          int i  = k * 512 + t;
          int s  = i >> 8;
          int cv = s & 1, rr = s >> 1;
          int frag = (i >> 6) & 3;
          const char* wsrc = cv ? wtkB : wtqB;
          size_t g16 = ((size_t)(nchunk * 9 + ng * 3 + rr) * 32 + f0 + frag) * 64 + lane;
          gload_lds16(wsrc + g16 * 16,
                      WsB + (size_t)((buf ^ 1) * 1536 + k * 512 + wavebase) * 16);
        }
      }
      // compute group: 3 taps x 2cv x 2fm x nfn
#pragma unroll
      for (int r = 0; r < 3; ++r) {
        int tap = g * 3 + r;
        int d16 = ((tap / 3 - 1) * 14 + (tap % 3 - 1)) * 16;
        bf16x8 af[2][2];
#pragma unroll
        for (int cv = 0; cv < 2; ++cv)
#pragma unroll
          for (int fm = 0; fm < 2; ++fm)
            af[cv][fm] =
                *(const bf16x8*)(WsB + (size_t)(buf * 6 + r * 2 + cv) * 4096 + aAddr[fm]);
#pragma unroll
        for (int fi = 0; fi < 5; ++fi) {
          if (fi >= nfn) continue;  // wave-uniform
          bf16x8 bb = *(const bf16x8*)(XsB + bAddr[fi] + d16);
#pragma unroll
          for (int cv = 0; cv < 2; ++cv)
#pragma unroll
            for (int fm = 0; fm < 2; ++fm)
              acc[cv][fm][fi] =
                  __builtin_amdgcn_mfma_f32_16x16x32_bf16(af[cv][fm], bb, acc[cv][fm][fi], 0, 0, 0);
        }
      }
      __syncthreads();
      buf ^= 1;
    }
  }

  // ---- mask reduce: only mt==0 blocks (one per b) ----
  if (mt == 0) {
    float* Mred = (float*)Xs;
    float msum[3] = {msum0, msum1, msum2};
#pragma unroll
    for (int i = 0; i < 3; ++i) {
      if (!xvalid[i]) continue;
      int item = i * 512 + t;
      int xkg = item / kXPlane;
      int hp  = item - xkg * kXPlane;
      int y = hp / 14 - 1, x = hp % 14 - 1;
      Mred[xkg * kHW + y * kW + x] = msum[i];
    }
    __syncthreads();
    float nv = 0.f;
    if (t < kHW)
      nv = sqrtf(Mred[t] + Mred[kHW + t] + Mred[2 * kHW + t] + Mred[3 * kHW + t]);
    float* red = (float*)Wbuf;
    red[t] = (t < kHW) ? nv : 3.4e38f;
    __syncthreads();
    float mn;
    {
      float m = 3.4e38f;
      if (t < 64) {
        for (int i = t; i < 512; i += 64) m = fminf(m, red[i]);
        for (int off = 32; off; off >>= 1) m = fminf(m, __shfl_xor(m, off));
      }
      __syncthreads();
      if (t == 0) red[0] = m;
      __syncthreads();
      mn = red[0];
      __syncthreads();
    }
    red[t] = (t < kHW) ? nv : -3.4e38f;
    __syncthreads();
    float mx;
    {
      float m = -3.4e38f;
      if (t < 64) {
        for (int i = t; i < 512; i += 64) m = fmaxf(m, red[i]);
        for (int off = 32; off; off >>= 1) m = fmaxf(m, __shfl_xor(m, off));
      }
      __syncthreads();
      if (t == 0) red[0] = m;
      __syncthreads();
      mx = red[0];
    }
    if (t < kHW) maskb[b * kHW + t] = (nv - mn) / ((mx - mn) + 1e-12f);
    __syncthreads();
  }

  // ---- epilogue: per cv (fully unrolled), Ep[288][72] stage, sumsq, transposed store ----
  unsigned short* Ep = Wbuf;
#pragma unroll
  for (int cv = 0; cv < 2; ++cv) {
    const float* bias = cv ? kb : qb;
    float* ssq = cv ? kss : qss;
#pragma unroll
    for (int fi = 0; fi < 5; ++fi) {
      if (fi >= nfn) continue;
      int p = (fnb + fi) * 16 + l15;
      float ps = 0.f;
#pragma unroll
      for (int fm = 0; fm < 2; ++fm)
#pragma unroll
        for (int reg = 0; reg < 4; ++reg) {
          int ocl = wm * 32 + fm * 16 + kg * 4 + reg;
          float v = acc[cv][fm][fi][reg] + bias[oc0 + ocl];
          ps = fmaf(v, v, ps);
          Ep[p * 72 + ocl] = f2bf(v);
        }
      ps += __shfl_xor(ps, 16);
      ps += __shfl_xor(ps, 32);
      if (kg == 0) atomicAdd(ssq + b * kHW + p, ps);
    }
    __syncthreads();
    unsigned short* dstT = (cv ? fkT : fqT) + (size_t)b * kHW * kCQ + oc0;
#pragma unroll
    for (int it = 0; it < 5; ++it) {
      int item = it * 512 + t;
      if (item < 2304) {
        int p = item >> 3, j = item & 7;
        *(ushort8*)(dstT + (size_t)p * kCQ + j * 8) =
            *(const ushort8*)(Ep + p * 72 + j * 8);
      }
    }
    __syncthreads();
  }
}

// -------- warp GEMM via MFMA, both branches; XCD-clustered flat grid (2048) --------
__global__ __launch_bounds__(512) void warp_mfma_kernel(const float* __restrict__ fv,
                                                        const float* __restrict__ ft,
                                                        const unsigned short* __restrict__ prb0,
                                                        const unsigned short* __restrict__ prb1,
                                                        const float* __restrict__ maskp,
                                                        const int* __restrict__ pos_idx,
                                                        const int* __restrict__ neg_idx,
                                                        float* __restrict__ outp,
                                                        float* __restrict__ dap,
                                                        float* __restrict__ dan) {
  __shared__ unsigned short AsHi[128 * 32];
  __shared__ unsigned short AsLo[128 * 32];
  __shared__ unsigned short Bs[288 * 32];
  int t    = threadIdx.x;
  int lane = t & 63;
  int wid  = t >> 6;
  int l15  = lane & 15, kg = lane >> 4;
  int wm   = wid >> 1, wn = wid & 1;
  int n    = blockIdx.x;
  int xcd  = n & 7;
  int m    = n >> 3;
  int b    = xcd + ((m & 7) << 3);
  int rest = m >> 3;
  int c0   = (rest & 15) * 128;
  int z    = rest >> 4;
  int write_out = (z == 0);
  const unsigned short* prb = z ? prb1 : prb0;
  float* dsq = z ? dan : dap;
  int tb   = (z ? neg_idx : pos_idx)[b];
  const float* tgt = feat_base(fv, ft, tb);
  const float* fb  = feat_base(fv, ft, b);

  int ar = t >> 2, as = t & 3;
  int aslot = as ^ ((ar ^ (ar >> 2)) & 3);
  unsigned short* aDstHi = AsHi + ar * 32 + aslot * 8;
  unsigned short* aDstLo = AsLo + ar * 32 + aslot * 8;

  int aIdx[2];
#pragma unroll
  for (int fm = 0; fm < 2; ++fm) {
    int r = wm * 32 + fm * 16 + l15;
    aIdx[fm] = r * 32 + (kg ^ ((r ^ (r >> 2)) & 3)) * 8;
  }
  int bIdx[9];
#pragma unroll
  for (int fn = 0; fn < 9; ++fn) {
    int q = wn * 144 + fn * 16 + l15;
    bIdx[fn] = q * 32 + (kg ^ ((q ^ (q >> 2)) & 3)) * 8;
  }

  f32x4 acc[2][9];
#pragma unroll
  for (int fm = 0; fm < 2; ++fm)
#pragma unroll
    for (int fn = 0; fn < 9; ++fn) acc[fm][fn] = (f32x4){0.f, 0.f, 0.f, 0.f};

#pragma unroll 1
  for (int chunk = 0; chunk < 9; ++chunk) {
    int k0 = chunk * 32;
    __syncthreads();
    {
      const float* s = tgt + (size_t)(c0 + ar) * kHW + k0 + as * 8;
      float4 v0 = *(const float4*)(s);
      float4 v1 = *(const float4*)(s + 4);
      float xs[8] = {v0.x, v0.y, v0.z, v0.w, v1.x, v1.y, v1.z, v1.w};
      ushort8 hi, lo;
#pragma unroll
      for (int j = 0; j < 8; ++j) {
        unsigned short h = f2bf(xs[j]);
        hi[j] = h;
        lo[j] = f2bf(xs[j] - bf2f(h));
      }
      *(ushort8*)aDstHi = hi;
      *(ushort8*)aDstLo = lo;
    }
#pragma unroll
    for (int i = 0; i < 3; ++i) {
      int item = i * 512 + t;
      if (item < 1152) {
        int q = item >> 2, s = item & 3;
        ushort8 v = *(const ushort8*)(prb + ((size_t)b * kHW + q) * kHW + k0 + s * 8);
        *(ushort8*)(Bs + q * 32 + (s ^ ((q ^ (q >> 2)) & 3)) * 8) = v;
      }
    }
    __syncthreads();
    bf16x8 ah0 = *(const bf16x8*)(AsHi + aIdx[0]);
    bf16x8 al0 = *(const bf16x8*)(AsLo + aIdx[0]);
    bf16x8 ah1 = *(const bf16x8*)(AsHi + aIdx[1]);
    bf16x8 al1 = *(const bf16x8*)(AsLo + aIdx[1]);
#pragma unroll
    for (int fn = 0; fn < 9; ++fn) {
      bf16x8 bb = *(const bf16x8*)(Bs + bIdx[fn]);
      acc[0][fn] = __builtin_amdgcn_mfma_f32_16x16x32_bf16(ah0, bb, acc[0][fn], 0, 0, 0);
      acc[0][fn] = __builtin_amdgcn_mfma_f32_16x16x32_bf16(al0, bb, acc[0][fn], 0, 0, 0);
      acc[1][fn] = __builtin_amdgcn_mfma_f32_16x16x32_bf16(ah1, bb, acc[1][fn], 0, 0, 0);
      acc[1][fn] = __builtin_amdgcn_mfma_f32_16x16x32_bf16(al1, bb, acc[1][fn], 0, 0, 0);
    }
  }

#pragma unroll
  for (int fn = 0; fn < 9; ++fn) {
    int q = wn * 144 + fn * 16 + l15;
    float mj = maskp[b * kHW + q];
    float psum = 0.f;
#pragma unroll
    for (int fm = 0; fm < 2; ++fm) {
#pragma unroll
      for (int reg = 0; reg < 4; ++reg) {
        int c = c0 + wm * 32 + fm * 16 + kg * 4 + reg;
        float fvv = fb[(size_t)c * kHW + q];
        float Wv  = acc[fm][fn][reg];
        float d   = mj * (fvv - Wv) + 1e-6f;
        psum      = fmaf(d, d, psum);
        if (write_out)
          outp[((size_t)b * kC + c) * kHW + q] = mj * Wv + (1.f - mj) * fvv;
      }
    }
    psum += __shfl_xor(psum, 16);
    psum += __shfl_xor(psum, 32);
    if (lane < 16) atomicAdd(&dsq[b * kHW + q], psum);
  }
}

// -------- sim via MFMA + softmax + comask_raw (z=0); XCD-clustered flat grid (384) --------
__global__ __launch_bounds__(512, 1) void sim_mfma_kernel(const unsigned short* __restrict__ fqT,
                                                          const unsigned short* __restrict__ fkT,
                                                          const float* __restrict__ qss,
                                                          const float* __restrict__ kss,
                                                          const float* __restrict__ maskb,
                                                          const int* __restrict__ pos_idx,
                                                          const int* __restrict__ neg_idx,
                                                          unsigned short* __restrict__ prb0,
                                                          unsigned short* __restrict__ prb1,
                                                          float* __restrict__ craw) {
  __shared__ float Sbuf[96 * 289];  // 110976 B; As @0 (6KB), Bs @6144 (18KB) alias
  __shared__ float mtl[kHW];
  unsigned short* As = (unsigned short*)Sbuf;
  unsigned short* Bs = (unsigned short*)((char*)Sbuf + 6144);
  float (*S)[289] = (float(*)[289])Sbuf;
  int t    = threadIdx.x;
  int lane = t & 63;
  int wid  = t >> 6;
  int l15  = lane & 15, kg = lane >> 4;
  int wm   = wid & 1, wn = wid >> 1;
  int n    = blockIdx.x;
  int xcd  = n & 7;
  int m    = n >> 3;
  int b    = xcd + ((m & 7) << 3);
  int rest = m >> 3;
  int q0   = (rest % 3) * 96;
  int z    = rest / 3;
  int tb   = (z ? neg_idx : pos_idx)[b];
  unsigned short* prb = z ? prb1 : prb0;
  const unsigned short* fqb = fqT + ((size_t)b * kHW + q0) * kCQ;
  const unsigned short* fkb = fkT + (size_t)tb * kHW * kCQ;

  if (t < kHW) mtl[t] = maskb[tb * kHW + t];

  int aIdx[3];
#pragma unroll
  for (int fm = 0; fm < 3; ++fm) {
    int r = wm * 48 + fm * 16 + l15;
    aIdx[fm] = r * 32 + (kg ^ ((r ^ (r >> 2)) & 3)) * 8;
  }
  int nfn = (wn < 2) ? 5 : 4;
  int fnb = (wn < 2) ? wn * 5 : 10 + (wn - 2) * 4;
  int bIdx[5];
#pragma unroll
  for (int fi = 0; fi < 5; ++fi) {
    int kr = (fnb + fi) * 16 + l15;
    if (kr > 287) kr = 287;
    bIdx[fi] = kr * 32 + (kg ^ ((kr ^ (kr >> 2)) & 3)) * 8;
  }

  f32x4 acc[3][5];
#pragma unroll
  for (int fm = 0; fm < 3; ++fm)
#pragma unroll
    for (int fi = 0; fi < 5; ++fi) acc[fm][fi] = (f32x4){0.f, 0.f, 0.f, 0.f};

#pragma unroll 1
  for (int chunk = 0; chunk < 16; ++chunk) {
    int c0 = chunk * 32;
    __syncthreads();
    if (t < 384) {
      int ar = t >> 2, as = t & 3;
      ushort8 v = *(const ushort8*)(fqb + (size_t)ar * kCQ + c0 + as * 8);
      int slot = as ^ ((ar ^ (ar >> 2)) & 3);
      *(ushort8*)(As + ar * 32 + slot * 8) = v;
    }
#pragma unroll
    for (int i = 0; i < 3; ++i) {
      int item = i * 512 + t;
      if (item < 1152) {
        int kr = item >> 2, ks = item & 3;
        ushort8 v = *(const ushort8*)(fkb + (size_t)kr * kCQ + c0 + ks * 8);
        int slot = ks ^ ((kr ^ (kr >> 2)) & 3);
        *(ushort8*)(Bs + kr * 32 + slot * 8) = v;
      }
    }
    __syncthreads();
    bf16x8 a[3];
#pragma unroll
    for (int fm = 0; fm < 3; ++fm) a[fm] = *(const bf16x8*)(As + aIdx[fm]);
#pragma unroll
    for (int fi = 0; fi < 5; ++fi) {
      if (fi >= nfn) continue;
      bf16x8 bb = *(const bf16x8*)(Bs + bIdx[fi]);
#pragma unroll
      for (int fm = 0; fm < 3; ++fm)
        acc[fm][fi] = __builtin_amdgcn_mfma_f32_16x16x32_bf16(a[fm], bb, acc[fm][fi], 0, 0, 0);
    }
  }
  __syncthreads();

  float kinvv[5];
#pragma unroll
  for (int fi = 0; fi < 5; ++fi) {
    int col = (fnb + fi) * 16 + l15;
    if (col > 287) col = 287;
    kinvv[fi] = 1.f / fmaxf(sqrtf(kss[tb * kHW + col]), 1e-12f);
  }
#pragma unroll
  for (int fm = 0; fm < 3; ++fm)
#pragma unroll
    for (int reg = 0; reg < 4; ++reg) {
      int row = wm * 48 + fm * 16 + kg * 4 + reg;
      float qi = kTemp / fmaxf(sqrtf(qss[b * kHW + q0 + row]), 1e-12f);
#pragma unroll
      for (int fi = 0; fi < 5; ++fi) {
        if (fi >= nfn) continue;
        S[row][(fnb + fi) * 16 + l15] = qi * kinvv[fi] * acc[fm][fi][reg];
      }
    }
  __syncthreads();

  int l = lane;
  for (int q = wid; q < 96; q += 8) {
    float v[5];
    float m2 = -3.4e38f;
#pragma unroll
    for (int j = 0; j < 5; ++j) {
      int k = l + 64 * j;
      v[j] = (k < kHW) ? S[q][k] : -3.4e38f;
      m2 = fmaxf(m2, v[j]);
    }
    for (int off = 32; off; off >>= 1) m2 = fmaxf(m2, __shfl_xor(m2, off));
    float e[5];
    float s = 0.f;
#pragma unroll
    for (int j = 0; j < 5; ++j) {
      int k = l + 64 * j;
      e[j] = (k < kHW) ? __expf(v[j] - m2) : 0.f;
      s += e[j];
    }
    for (int off = 32; off; off >>= 1) s += __shfl_xor(s, off);
    float invs = 1.f / s;
    unsigned short* row = prb + ((size_t)b * kHW + q0 + q) * kHW;
    float dot = 0.f;
#pragma unroll
    for (int j = 0; j < 5; ++j) {
      int k = l + 64 * j;
      if (k < kHW) {
        float p = e[j] * invs;
        row[k] = f2bf(p);
        if (z == 0) dot = fmaf(bf2f(f2bf(p)), mtl[k], dot);
      }
    }
    if (z == 0) {
      for (int off = 32; off; off >>= 1) dot += __shfl_xor(dot, off);
      if (l == 0)
        craw[b * kHW + q0 + q] = maskb[b * kHW + q0 + q] * dot;
    }
  }
}

// -------- loss: comask min-max normalize (per b) + triplet reduce, one block --------
__global__ __launch_bounds__(256) void loss_kernel(const float* __restrict__ dap,
                                                   const float* __restrict__ dan,
                                                   const float* __restrict__ craw,
                                                   float* __restrict__ out) {
  int t = threadIdx.x;
  int wv = t >> 6, l = t & 63;
  __shared__ float sh4a[4], sh4b[4];
  __shared__ float sh2[2];
  float total = 0.f;
#pragma unroll 1
  for (int b = 0; b < kB; ++b) {
    const float* cb = craw + b * kHW;
    float v1 = cb[t];
    float v2 = (t < kHW - 256) ? cb[t + 256] : v1;
    float mnl = fminf(v1, v2), mxl = fmaxf(v1, v2);
    for (int off = 32; off; off >>= 1) {
      mnl = fminf(mnl, __shfl_xor(mnl, off));
      mxl = fmaxf(mxl, __shfl_xor(mxl, off));
    }
    if (l == 0) { sh4a[wv] = mnl; sh4b[wv] = mxl; }
    __syncthreads();
    if (t == 0) {
      float mn = sh4a[0], mx = sh4b[0];
      for (int i = 1; i < 4; ++i) { mn = fminf(mn, sh4a[i]); mx = fmaxf(mx, sh4b[i]); }
      sh2[0] = mn; sh2[1] = mx;
    }
    __syncthreads();
    float mn = sh2[0];
    float inv = 1.f / ((sh2[1] - mn) + 1e-12f);
    {
      int i = b * kHW + t;
      float cn = (v1 - mn) * inv;
      float tr = fmaxf(sqrtf(dap[i]) - sqrtf(dan[i]) + 0.3f, 0.f);
      total = fmaf(cn, tr, total);
    }
    if (t < kHW - 256) {
      int i = b * kHW + t + 256;
      float cn = (v2 - mn) * inv;
      float tr = fmaxf(sqrtf(dap[i]) - sqrtf(dan[i]) + 0.3f, 0.f);
      total = fmaf(cn, tr, total);
    }
    __syncthreads();
  }
  for (int off = 32; off; off >>= 1) total += __shfl_xor(total, off);
  if (l == 0) sh4a[wv] = total;
  __syncthreads();
  if (t == 0)
    out[(size_t)kB * kC * kHW] =
        (sh4a[0] + sh4a[1] + sh4a[2] + sh4a[3]) * (1.f / (float)(kB * kHW));
}

extern "C" void kernel_launch(void* const* d_in, const int* in_sizes, int n_in,
                              void* d_out, int out_size, void* d_ws, size_t ws_size,
                              hipStream_t stream) {
  const float* fv = (const float*)d_in[0];
  const float* ft = (const float*)d_in[1];
  const float* qw = (const float*)d_in[4];
  const float* qb = (const float*)d_in[5];
  const float* kw = (const float*)d_in[6];
  const float* kb = (const float*)d_in[7];
  const int* pos_idx = (const int*)d_in[8];
  const int* neg_idx = (const int*)d_in[9];
  float* out = (float*)d_out;

  constexpr size_t kFQ = (size_t)kB * kCQ * kHW;            // 9,437,184
  constexpr size_t kPR = (size_t)kB * kHW * kHW;            // 5,308,416 (u16)
  float* ws   = (float*)d_ws;
  unsigned short* fqT = (unsigned short*)ws;                // region1 (37.75M)
  unsigned short* fkT = fqT + (size_t)kB * kHW * kCQ;
  unsigned short* prb0 = (unsigned short*)(ws + kFQ);       // region2: pos P
  unsigned short* prb1 = prb0 + kPR;                        //          neg P
  unsigned short* wtq = (unsigned short*)(ws + 2 * kFQ);    // region3
  unsigned short* wtk = wtq + (size_t)9 * kCQ * kC;
  float* maskb   = (float*)(wtk + (size_t)9 * kCQ * kC);
  float* qss     = maskb + kB * kHW;
  float* kss     = qss + kB * kHW;
  float* craw    = kss + kB * kHW;
  float* dap     = craw + kB * kHW;
  float* dan     = dap + kB * kHW;
  if (ws_size < (size_t)113688576) return;

  zero_kernel<<<dim3((5 * kB * kHW + 255) / 256), 256, 0, stream>>>(qss, 5 * kB * kHW);
  prep_w_kernel<<<dim3(kCQ, 2), 256, 0, stream>>>(qw, kw, wtq, wtk);
  conv_fused_kernel<<<dim3(512), 512, 0, stream>>>(wtq, wtk, qb, kb, fv, ft,
                                                   fqT, fkT, qss, kss, maskb);
  sim_mfma_kernel<<<dim3(384), 512, 0, stream>>>(fqT, fkT, qss, kss, maskb,
                                                 pos_idx, neg_idx, prb0, prb1, craw);
  warp_mfma_kernel<<<dim3(2048), 512, 0, stream>>>(fv, ft, prb0, prb1, maskb,
                                                   pos_idx, neg_idx, out, dap, dan);
  loss_kernel<<<dim3(1), 256, 0, stream>>>(dap, dan, craw, out);
}

// Round 22
// 1003.410 us; speedup vs baseline: 6.6113x; 1.0026x over previous
//
#include <hip/hip_runtime.h>
#include <cstdint>
#include <cstddef>

// CMAlign forward. R22: R21 + zero folded into prep_w (5 launches), craw zeroing
// dropped (fully overwritten by sim). Conv = R21 (M=64, 2 blocks/CU, 640us).
// Shapes: B=64, C=2048, Cq=512, H=24, W=12, HW=288.

namespace {
constexpr int kB    = 64;
constexpr int kHalf = 32;
constexpr int kC    = 2048;
constexpr int kCQ   = 512;
constexpr int kH    = 24;
constexpr int kW    = 12;
constexpr int kHW   = 288;
constexpr float kTemp = 50.0f;
constexpr int kXPlane = 366;  // 16B cells; 5856 B = 96 mod 128 -> kg quadrant offsets
}

typedef __attribute__((ext_vector_type(8))) __bf16 bf16x8;
typedef __attribute__((ext_vector_type(4))) float f32x4;
typedef __attribute__((ext_vector_type(8))) unsigned short ushort8;

__device__ __forceinline__ const float* feat_base(const float* fv, const float* ft, int b) {
  return (b < kHalf) ? (fv + (size_t)b * kC * kHW)
                     : (ft + (size_t)(b - kHalf) * kC * kHW);
}

__device__ __forceinline__ unsigned short f2bf(float f) {
  union { float f; unsigned u; } c; c.f = f;
  unsigned u = c.u;
  unsigned r = (u + 0x7FFFu + ((u >> 16) & 1u)) >> 16;  // RNE
  return (unsigned short)r;
}

__device__ __forceinline__ float bf2f(unsigned short h) {
  union { unsigned u; float f; } c; c.u = ((unsigned)h) << 16;
  return c.f;
}

__device__ __forceinline__ void gload_lds16(const void* g, void* l) {
  __builtin_amdgcn_global_load_lds(
      (const __attribute__((address_space(1))) unsigned int*)g,
      (__attribute__((address_space(3))) unsigned int*)l, 16, 0, 0);
}

// -------- weight prep (+ zeroing of accumulators): w fp32 -> MFMA-image wt2 --------
__global__ __launch_bounds__(256) void prep_w_kernel(const float* __restrict__ qw,
                                                     const float* __restrict__ kw,
                                                     unsigned short* __restrict__ wtq,
                                                     unsigned short* __restrict__ wtk,
                                                     float* __restrict__ zr1,   // qss+kss (36864)
                                                     float* __restrict__ zr2) { // dap+dan (36864)
  int oc = blockIdx.x;
  int z  = blockIdx.y;
  int t  = threadIdx.x;
  // fold-in zeroing: 1024 blocks x 72 floats = 73728 = 2*36864
  {
    int bid = oc + (z << 9);  // 0..1023
    if (t < 72) {
      int off = bid * 72 + t;
      if (off < 36864) zr1[off] = 0.f;
      else             zr2[off - 36864] = 0.f;
    }
  }
  const float* w = (z ? kw : qw) + (size_t)oc * (kC * 9);
  unsigned short* wt = z ? wtk : wtq;
  __shared__ unsigned short lw[kC * 9];  // [ic][tap]
#pragma unroll
  for (int it = 0; it < 18; ++it) {
    int i4 = (it * 256 + t) * 4;
    float4 v = *(const float4*)(w + i4);
    lw[i4 + 0] = f2bf(v.x);
    lw[i4 + 1] = f2bf(v.y);
    lw[i4 + 2] = f2bf(v.z);
    lw[i4 + 3] = f2bf(v.w);
  }
  __syncthreads();
  for (int item = t; item < 9 * 256; item += 256) {
    int tap = item >> 8;
    int icb = item & 255;
    ushort8 pk;
#pragma unroll
    for (int j = 0; j < 8; ++j) pk[j] = lw[(icb * 8 + j) * 9 + tap];
    size_t dst16 = (((size_t)(icb >> 2) * 9 + tap) * 32 + (oc >> 4)) * 64
                   + (oc & 15) + (icb & 3) * 16;
    *(ushort8*)(wt + dst16 * 8) = pk;
  }
}

// -------- FUSED MFMA conv + mask: M=64 tile, grid 512, 2 blocks/CU (R21) --------
__global__ __launch_bounds__(512, 4) void conv_fused_kernel(const unsigned short* __restrict__ wtq,
                                                            const unsigned short* __restrict__ wtk,
                                                            const float* __restrict__ qb,
                                                            const float* __restrict__ kb,
                                                            const float* __restrict__ fv,
                                                            const float* __restrict__ ft,
                                                            unsigned short* __restrict__ fqT,
                                                            unsigned short* __restrict__ fkT,
                                                            float* __restrict__ qss,
                                                            float* __restrict__ kss,
                                                            float* __restrict__ maskb) {
  __shared__ unsigned short Wbuf[2 * 6 * 2048];   // 49152 B (epilogue: Ep[288][72] 41.5KB)
  __shared__ unsigned short Xs[4 * kXPlane * 8];  // 23424 B (mask: Mred)
  int t    = threadIdx.x;
  int lane = t & 63;
  int l15  = lane & 15, kg = lane >> 4;
  int wid  = t >> 6;
  int wm   = wid & 1, wn = wid >> 1;  // 2M x 4N
  int n    = blockIdx.x;
  int xcd  = n & 7;
  int idx  = n >> 3;              // 0..63
  int b    = xcd + ((idx & 7) << 3);
  int mt   = idx >> 3;            // 0..7
  int oc0  = mt * 64;
  int f0   = mt * 4;              // frag base (16-oc units)
  const float* fb = feat_base(fv, ft, b);
  const char* wtqB = (const char*)wtq;
  const char* wtkB = (const char*)wtk;

  int  xoff[3];
  bool xvalid[3], xhas[3];
#pragma unroll
  for (int i = 0; i < 3; ++i) {
    int item = i * 512 + t;
    xhas[i] = item < 4 * kXPlane;
    int xkg = item / kXPlane;
    int hp  = item - xkg * kXPlane;
    int hy = hp / 14, hx = hp - hy * 14;
    int y = hy - 1, x = hx - 1;
    bool v = xhas[i] && hp < 364 && (y >= 0 && y < kH && x >= 0 && x < kW);
    xvalid[i] = v;
    xoff[i] = v ? (xkg * 8) * kHW + y * kW + x : 0;
  }

  int aAddr[2];
#pragma unroll
  for (int fm = 0; fm < 2; ++fm)
    aAddr[fm] = (((wm * 2 + fm) * 64) + lane) * 16;
  int nfn = (wn < 2) ? 5 : 4;
  int fnb = (wn < 2) ? wn * 5 : 10 + (wn - 2) * 4;
  int bAddr[5];
#pragma unroll
  for (int fi = 0; fi < 5; ++fi) {
    int p = (fnb + fi) * 16 + l15;
    if (p > 287) p = 287;
    int y = p / kW, x = p - y * kW;
    bAddr[fi] = kg * (kXPlane * 16) + ((y + 1) * 14 + (x + 1)) * 16;
  }

  f32x4 acc[2][2][5];
#pragma unroll
  for (int cv = 0; cv < 2; ++cv)
#pragma unroll
    for (int fm = 0; fm < 2; ++fm)
#pragma unroll
      for (int fi = 0; fi < 5; ++fi) acc[cv][fm][fi] = (f32x4){0.f, 0.f, 0.f, 0.f};

  float msum0 = 0.f, msum1 = 0.f, msum2 = 0.f;

  char* WsB = (char*)Wbuf;
  char* XsB = (char*)Xs;
  int wavebase = t & ~63;

#pragma unroll
  for (int i = 0; i < 3; ++i) {
    if (xhas[i] && !xvalid[i]) {
      ushort8 pk;
#pragma unroll
      for (int j = 0; j < 8; ++j) pk[j] = 0;
      *(ushort8*)(XsB + (size_t)(i * 512 + t) * 16) = pk;
    }
  }
#pragma unroll
  for (int k = 0; k < 3; ++k) {
    int i  = k * 512 + t;
    int s  = i >> 8;
    int cv = s & 1, rr = s >> 1;
    int frag = (i >> 6) & 3;
    const char* wsrc = cv ? wtkB : wtqB;
    size_t g16 = ((size_t)rr * 32 + f0 + frag) * 64 + lane;
    gload_lds16(wsrc + g16 * 16, WsB + (size_t)(k * 512 + wavebase) * 16);
  }

  int buf = 0;
#pragma unroll 1
  for (int chunk = 0; chunk < 64; ++chunk) {
    int ic0 = chunk * 32;
    if (xvalid[0]) {
      const float* s = fb + (size_t)ic0 * kHW + xoff[0];
      float xv[8];
#pragma unroll
      for (int j = 0; j < 8; ++j) xv[j] = s[(size_t)j * kHW];
      ushort8 pk;
#pragma unroll
      for (int j = 0; j < 8; ++j) { msum0 = fmaf(xv[j], xv[j], msum0); pk[j] = f2bf(xv[j]); }
      *(ushort8*)(XsB + (size_t)t * 16) = pk;
    }
    if (xvalid[1]) {
      const float* s = fb + (size_t)ic0 * kHW + xoff[1];
      float xv[8];
#pragma unroll
      for (int j = 0; j < 8; ++j) xv[j] = s[(size_t)j * kHW];
      ushort8 pk;
#pragma unroll
      for (int j = 0; j < 8; ++j) { msum1 = fmaf(xv[j], xv[j], msum1); pk[j] = f2bf(xv[j]); }
      *(ushort8*)(XsB + (size_t)(512 + t) * 16) = pk;
    }
    if (xvalid[2]) {
      const float* s = fb + (size_t)ic0 * kHW + xoff[2];
      float xv[8];
#pragma unroll
      for (int j = 0; j < 8; ++j) xv[j] = s[(size_t)j * kHW];
      ushort8 pk;
#pragma unroll
      for (int j = 0; j < 8; ++j) { msum2 = fmaf(xv[j], xv[j], msum2); pk[j] = f2bf(xv[j]); }
      *(ushort8*)(XsB + (size_t)(1024 + t) * 16) = pk;
    }
    __syncthreads();

#pragma unroll 1
    for (int g = 0; g < 3; ++g) {
      bool hn = (g < 2) || (chunk < 63);
      if (hn) {
        int nchunk = (g < 2) ? chunk : chunk + 1;
        int ng     = (g < 2) ? g + 1 : 0;
#pragma unroll
        for (int k = 0; k < 3; ++k) {
          int i  = k * 512 + t;
          int s  = i >> 8;
          int cv = s & 1, rr = s >> 1;
          int frag = (i >> 6) & 3;
          const char* wsrc = cv ? wtkB : wtqB;
          size_t g16 = ((size_t)(nchunk * 9 + ng * 3 + rr) * 32 + f0 + frag) * 64 + lane;
          gload_lds16(wsrc + g16 * 16,
                      WsB + (size_t)((buf ^ 1) * 1536 + k * 512 + wavebase) * 16);
        }
      }
#pragma unroll
      for (int r = 0; r < 3; ++r) {
        int tap = g * 3 + r;
        int d16 = ((tap / 3 - 1) * 14 + (tap % 3 - 1)) * 16;
        bf16x8 af[2][2];
#pragma unroll
        for (int cv = 0; cv < 2; ++cv)
#pragma unroll
          for (int fm = 0; fm < 2; ++fm)
            af[cv][fm] =
                *(const bf16x8*)(WsB + (size_t)(buf * 6 + r * 2 + cv) * 4096 + aAddr[fm]);
#pragma unroll
        for (int fi = 0; fi < 5; ++fi) {
          if (fi >= nfn) continue;
          bf16x8 bb = *(const bf16x8*)(XsB + bAddr[fi] + d16);
#pragma unroll
          for (int cv = 0; cv < 2; ++cv)
#pragma unroll
            for (int fm = 0; fm < 2; ++fm)
              acc[cv][fm][fi] =
                  __builtin_amdgcn_mfma_f32_16x16x32_bf16(af[cv][fm], bb, acc[cv][fm][fi], 0, 0, 0);
        }
      }
      __syncthreads();
      buf ^= 1;
    }
  }

  // ---- mask reduce: only mt==0 blocks (one per b) ----
  if (mt == 0) {
    float* Mred = (float*)Xs;
    float msum[3] = {msum0, msum1, msum2};
#pragma unroll
    for (int i = 0; i < 3; ++i) {
      if (!xvalid[i]) continue;
      int item = i * 512 + t;
      int xkg = item / kXPlane;
      int hp  = item - xkg * kXPlane;
      int y = hp / 14 - 1, x = hp % 14 - 1;
      Mred[xkg * kHW + y * kW + x] = msum[i];
    }
    __syncthreads();
    float nv = 0.f;
    if (t < kHW)
      nv = sqrtf(Mred[t] + Mred[kHW + t] + Mred[2 * kHW + t] + Mred[3 * kHW + t]);
    float* red = (float*)Wbuf;
    red[t] = (t < kHW) ? nv : 3.4e38f;
    __syncthreads();
    float mn;
    {
      float m = 3.4e38f;
      if (t < 64) {
        for (int i = t; i < 512; i += 64) m = fminf(m, red[i]);
        for (int off = 32; off; off >>= 1) m = fminf(m, __shfl_xor(m, off));
      }
      __syncthreads();
      if (t == 0) red[0] = m;
      __syncthreads();
      mn = red[0];
      __syncthreads();
    }
    red[t] = (t < kHW) ? nv : -3.4e38f;
    __syncthreads();
    float mx;
    {
      float m = -3.4e38f;
      if (t < 64) {
        for (int i = t; i < 512; i += 64) m = fmaxf(m, red[i]);
        for (int off = 32; off; off >>= 1) m = fmaxf(m, __shfl_xor(m, off));
      }
      __syncthreads();
      if (t == 0) red[0] = m;
      __syncthreads();
      mx = red[0];
    }
    if (t < kHW) maskb[b * kHW + t] = (nv - mn) / ((mx - mn) + 1e-12f);
    __syncthreads();
  }

  // ---- epilogue: per cv (fully unrolled), Ep[288][72] stage, sumsq, transposed store ----
  unsigned short* Ep = Wbuf;
#pragma unroll
  for (int cv = 0; cv < 2; ++cv) {
    const float* bias = cv ? kb : qb;
    float* ssq = cv ? kss : qss;
#pragma unroll
    for (int fi = 0; fi < 5; ++fi) {
      if (fi >= nfn) continue;
      int p = (fnb + fi) * 16 + l15;
      float ps = 0.f;
#pragma unroll
      for (int fm = 0; fm < 2; ++fm)
#pragma unroll
        for (int reg = 0; reg < 4; ++reg) {
          int ocl = wm * 32 + fm * 16 + kg * 4 + reg;
          float v = acc[cv][fm][fi][reg] + bias[oc0 + ocl];
          ps = fmaf(v, v, ps);
          Ep[p * 72 + ocl] = f2bf(v);
        }
      ps += __shfl_xor(ps, 16);
      ps += __shfl_xor(ps, 32);
      if (kg == 0) atomicAdd(ssq + b * kHW + p, ps);
    }
    __syncthreads();
    unsigned short* dstT = (cv ? fkT : fqT) + (size_t)b * kHW * kCQ + oc0;
#pragma unroll
    for (int it = 0; it < 5; ++it) {
      int item = it * 512 + t;
      if (item < 2304) {
        int p = item >> 3, j = item & 7;
        *(ushort8*)(dstT + (size_t)p * kCQ + j * 8) =
            *(const ushort8*)(Ep + p * 72 + j * 8);
      }
    }
    __syncthreads();
  }
}

// -------- warp GEMM via MFMA, both branches; XCD-clustered flat grid (2048) --------
__global__ __launch_bounds__(512) void warp_mfma_kernel(const float* __restrict__ fv,
                                                        const float* __restrict__ ft,
                                                        const unsigned short* __restrict__ prb0,
                                                        const unsigned short* __restrict__ prb1,
                                                        const float* __restrict__ maskp,
                                                        const int* __restrict__ pos_idx,
                                                        const int* __restrict__ neg_idx,
                                                        float* __restrict__ outp,
                                                        float* __restrict__ dap,
                                                        float* __restrict__ dan) {
  __shared__ unsigned short AsHi[128 * 32];
  __shared__ unsigned short AsLo[128 * 32];
  __shared__ unsigned short Bs[288 * 32];
  int t    = threadIdx.x;
  int lane = t & 63;
  int wid  = t >> 6;
  int l15  = lane & 15, kg = lane >> 4;
  int wm   = wid >> 1, wn = wid & 1;
  int n    = blockIdx.x;
  int xcd  = n & 7;
  int m    = n >> 3;
  int b    = xcd + ((m & 7) << 3);
  int rest = m >> 3;
  int c0   = (rest & 15) * 128;
  int z    = rest >> 4;
  int write_out = (z == 0);
  const unsigned short* prb = z ? prb1 : prb0;
  float* dsq = z ? dan : dap;
  int tb   = (z ? neg_idx : pos_idx)[b];
  const float* tgt = feat_base(fv, ft, tb);
  const float* fb  = feat_base(fv, ft, b);

  int ar = t >> 2, as = t & 3;
  int aslot = as ^ ((ar ^ (ar >> 2)) & 3);
  unsigned short* aDstHi = AsHi + ar * 32 + aslot * 8;
  unsigned short* aDstLo = AsLo + ar * 32 + aslot * 8;

  int aIdx[2];
#pragma unroll
  for (int fm = 0; fm < 2; ++fm) {
    int r = wm * 32 + fm * 16 + l15;
    aIdx[fm] = r * 32 + (kg ^ ((r ^ (r >> 2)) & 3)) * 8;
  }
  int bIdx[9];
#pragma unroll
  for (int fn = 0; fn < 9; ++fn) {
    int q = wn * 144 + fn * 16 + l15;
    bIdx[fn] = q * 32 + (kg ^ ((q ^ (q >> 2)) & 3)) * 8;
  }

  f32x4 acc[2][9];
#pragma unroll
  for (int fm = 0; fm < 2; ++fm)
#pragma unroll
    for (int fn = 0; fn < 9; ++fn) acc[fm][fn] = (f32x4){0.f, 0.f, 0.f, 0.f};

#pragma unroll 1
  for (int chunk = 0; chunk < 9; ++chunk) {
    int k0 = chunk * 32;
    __syncthreads();
    {
      const float* s = tgt + (size_t)(c0 + ar) * kHW + k0 + as * 8;
      float4 v0 = *(const float4*)(s);
      float4 v1 = *(const float4*)(s + 4);
      float xs[8] = {v0.x, v0.y, v0.z, v0.w, v1.x, v1.y, v1.z, v1.w};
      ushort8 hi, lo;
#pragma unroll
      for (int j = 0; j < 8; ++j) {
        unsigned short h = f2bf(xs[j]);
        hi[j] = h;
        lo[j] = f2bf(xs[j] - bf2f(h));
      }
      *(ushort8*)aDstHi = hi;
      *(ushort8*)aDstLo = lo;
    }
#pragma unroll
    for (int i = 0; i < 3; ++i) {
      int item = i * 512 + t;
      if (item < 1152) {
        int q = item >> 2, s = item & 3;
        ushort8 v = *(const ushort8*)(prb + ((size_t)b * kHW + q) * kHW + k0 + s * 8);
        *(ushort8*)(Bs + q * 32 + (s ^ ((q ^ (q >> 2)) & 3)) * 8) = v;
      }
    }
    __syncthreads();
    bf16x8 ah0 = *(const bf16x8*)(AsHi + aIdx[0]);
    bf16x8 al0 = *(const bf16x8*)(AsLo + aIdx[0]);
    bf16x8 ah1 = *(const bf16x8*)(AsHi + aIdx[1]);
    bf16x8 al1 = *(const bf16x8*)(AsLo + aIdx[1]);
#pragma unroll
    for (int fn = 0; fn < 9; ++fn) {
      bf16x8 bb = *(const bf16x8*)(Bs + bIdx[fn]);
      acc[0][fn] = __builtin_amdgcn_mfma_f32_16x16x32_bf16(ah0, bb, acc[0][fn], 0, 0, 0);
      acc[0][fn] = __builtin_amdgcn_mfma_f32_16x16x32_bf16(al0, bb, acc[0][fn], 0, 0, 0);
      acc[1][fn] = __builtin_amdgcn_mfma_f32_16x16x32_bf16(ah1, bb, acc[1][fn], 0, 0, 0);
      acc[1][fn] = __builtin_amdgcn_mfma_f32_16x16x32_bf16(al1, bb, acc[1][fn], 0, 0, 0);
    }
  }

#pragma unroll
  for (int fn = 0; fn < 9; ++fn) {
    int q = wn * 144 + fn * 16 + l15;
    float mj = maskp[b * kHW + q];
    float psum = 0.f;
#pragma unroll
    for (int fm = 0; fm < 2; ++fm) {
#pragma unroll
      for (int reg = 0; reg < 4; ++reg) {
        int c = c0 + wm * 32 + fm * 16 + kg * 4 + reg;
        float fvv = fb[(size_t)c * kHW + q];
        float Wv  = acc[fm][fn][reg];
        float d   = mj * (fvv - Wv) + 1e-6f;
        psum      = fmaf(d, d, psum);
        if (write_out)
          outp[((size_t)b * kC + c) * kHW + q] = mj * Wv + (1.f - mj) * fvv;
      }
    }
    psum += __shfl_xor(psum, 16);
    psum += __shfl_xor(psum, 32);
    if (lane < 16) atomicAdd(&dsq[b * kHW + q], psum);
  }
}

// -------- sim via MFMA + softmax + comask_raw (z=0); XCD-clustered flat grid (384) --------
__global__ __launch_bounds__(512, 1) void sim_mfma_kernel(const unsigned short* __restrict__ fqT,
                                                          const unsigned short* __restrict__ fkT,
                                                          const float* __restrict__ qss,
                                                          const float* __restrict__ kss,
                                                          const float* __restrict__ maskb,
                                                          const int* __restrict__ pos_idx,
                                                          const int* __restrict__ neg_idx,
                                                          unsigned short* __restrict__ prb0,
                                                          unsigned short* __restrict__ prb1,
                                                          float* __restrict__ craw) {
  __shared__ float Sbuf[96 * 289];  // 110976 B; As @0 (6KB), Bs @6144 (18KB) alias
  __shared__ float mtl[kHW];
  unsigned short* As = (unsigned short*)Sbuf;
  unsigned short* Bs = (unsigned short*)((char*)Sbuf + 6144);
  float (*S)[289] = (float(*)[289])Sbuf;
  int t    = threadIdx.x;
  int lane = t & 63;
  int wid  = t >> 6;
  int l15  = lane & 15, kg = lane >> 4;
  int wm   = wid & 1, wn = wid >> 1;
  int n    = blockIdx.x;
  int xcd  = n & 7;
  int m    = n >> 3;
  int b    = xcd + ((m & 7) << 3);
  int rest = m >> 3;
  int q0   = (rest % 3) * 96;
  int z    = rest / 3;
  int tb   = (z ? neg_idx : pos_idx)[b];
  unsigned short* prb = z ? prb1 : prb0;
  const unsigned short* fqb = fqT + ((size_t)b * kHW + q0) * kCQ;
  const unsigned short* fkb = fkT + (size_t)tb * kHW * kCQ;

  if (t < kHW) mtl[t] = maskb[tb * kHW + t];

  int aIdx[3];
#pragma unroll
  for (int fm = 0; fm < 3; ++fm) {
    int r = wm * 48 + fm * 16 + l15;
    aIdx[fm] = r * 32 + (kg ^ ((r ^ (r >> 2)) & 3)) * 8;
  }
  int nfn = (wn < 2) ? 5 : 4;
  int fnb = (wn < 2) ? wn * 5 : 10 + (wn - 2) * 4;
  int bIdx[5];
#pragma unroll
  for (int fi = 0; fi < 5; ++fi) {
    int kr = (fnb + fi) * 16 + l15;
    if (kr > 287) kr = 287;
    bIdx[fi] = kr * 32 + (kg ^ ((kr ^ (kr >> 2)) & 3)) * 8;
  }

  f32x4 acc[3][5];
#pragma unroll
  for (int fm = 0; fm < 3; ++fm)
#pragma unroll
    for (int fi = 0; fi < 5; ++fi) acc[fm][fi] = (f32x4){0.f, 0.f, 0.f, 0.f};

#pragma unroll 1
  for (int chunk = 0; chunk < 16; ++chunk) {
    int c0 = chunk * 32;
    __syncthreads();
    if (t < 384) {
      int ar = t >> 2, as = t & 3;
      ushort8 v = *(const ushort8*)(fqb + (size_t)ar * kCQ + c0 + as * 8);
      int slot = as ^ ((ar ^ (ar >> 2)) & 3);
      *(ushort8*)(As + ar * 32 + slot * 8) = v;
    }
#pragma unroll
    for (int i = 0; i < 3; ++i) {
      int item = i * 512 + t;
      if (item < 1152) {
        int kr = item >> 2, ks = item & 3;
        ushort8 v = *(const ushort8*)(fkb + (size_t)kr * kCQ + c0 + ks * 8);
        int slot = ks ^ ((kr ^ (kr >> 2)) & 3);
        *(ushort8*)(Bs + kr * 32 + slot * 8) = v;
      }
    }
    __syncthreads();
    bf16x8 a[3];
#pragma unroll
    for (int fm = 0; fm < 3; ++fm) a[fm] = *(const bf16x8*)(As + aIdx[fm]);
#pragma unroll
    for (int fi = 0; fi < 5; ++fi) {
      if (fi >= nfn) continue;
      bf16x8 bb = *(const bf16x8*)(Bs + bIdx[fi]);
#pragma unroll
      for (int fm = 0; fm < 3; ++fm)
        acc[fm][fi] = __builtin_amdgcn_mfma_f32_16x16x32_bf16(a[fm], bb, acc[fm][fi], 0, 0, 0);
    }
  }
  __syncthreads();

  float kinvv[5];
#pragma unroll
  for (int fi = 0; fi < 5; ++fi) {
    int col = (fnb + fi) * 16 + l15;
    if (col > 287) col = 287;
    kinvv[fi] = 1.f / fmaxf(sqrtf(kss[tb * kHW + col]), 1e-12f);
  }
#pragma unroll
  for (int fm = 0; fm < 3; ++fm)
#pragma unroll
    for (int reg = 0; reg < 4; ++reg) {
      int row = wm * 48 + fm * 16 + kg * 4 + reg;
      float qi = kTemp / fmaxf(sqrtf(qss[b * kHW + q0 + row]), 1e-12f);
#pragma unroll
      for (int fi = 0; fi < 5; ++fi) {
        if (fi >= nfn) continue;
        S[row][(fnb + fi) * 16 + l15] = qi * kinvv[fi] * acc[fm][fi][reg];
      }
    }
  __syncthreads();

  int l = lane;
  for (int q = wid; q < 96; q += 8) {
    float v[5];
    float m2 = -3.4e38f;
#pragma unroll
    for (int j = 0; j < 5; ++j) {
      int k = l + 64 * j;
      v[j] = (k < kHW) ? S[q][k] : -3.4e38f;
      m2 = fmaxf(m2, v[j]);
    }
    for (int off = 32; off; off >>= 1) m2 = fmaxf(m2, __shfl_xor(m2, off));
    float e[5];
    float s = 0.f;
#pragma unroll
    for (int j = 0; j < 5; ++j) {
      int k = l + 64 * j;
      e[j] = (k < kHW) ? __expf(v[j] - m2) : 0.f;
      s += e[j];
    }
    for (int off = 32; off; off >>= 1) s += __shfl_xor(s, off);
    float invs = 1.f / s;
    unsigned short* row = prb + ((size_t)b * kHW + q0 + q) * kHW;
    float dot = 0.f;
#pragma unroll
    for (int j = 0; j < 5; ++j) {
      int k = l + 64 * j;
      if (k < kHW) {
        float p = e[j] * invs;
        row[k] = f2bf(p);
        if (z == 0) dot = fmaf(bf2f(f2bf(p)), mtl[k], dot);
      }
    }
    if (z == 0) {
      for (int off = 32; off; off >>= 1) dot += __shfl_xor(dot, off);
      if (l == 0)
        craw[b * kHW + q0 + q] = maskb[b * kHW + q0 + q] * dot;
    }
  }
}

// -------- loss: comask min-max normalize (per b) + triplet reduce, one block --------
__global__ __launch_bounds__(256) void loss_kernel(const float* __restrict__ dap,
                                                   const float* __restrict__ dan,
                                                   const float* __restrict__ craw,
                                                   float* __restrict__ out) {
  int t = threadIdx.x;
  int wv = t >> 6, l = t & 63;
  __shared__ float sh4a[4], sh4b[4];
  __shared__ float sh2[2];
  float total = 0.f;
#pragma unroll 1
  for (int b = 0; b < kB; ++b) {
    const float* cb = craw + b * kHW;
    float v1 = cb[t];
    float v2 = (t < kHW - 256) ? cb[t + 256] : v1;
    float mnl = fminf(v1, v2), mxl = fmaxf(v1, v2);
    for (int off = 32; off; off >>= 1) {
      mnl = fminf(mnl, __shfl_xor(mnl, off));
      mxl = fmaxf(mxl, __shfl_xor(mxl, off));
    }
    if (l == 0) { sh4a[wv] = mnl; sh4b[wv] = mxl; }
    __syncthreads();
    if (t == 0) {
      float mn = sh4a[0], mx = sh4b[0];
      for (int i = 1; i < 4; ++i) { mn = fminf(mn, sh4a[i]); mx = fmaxf(mx, sh4b[i]); }
      sh2[0] = mn; sh2[1] = mx;
    }
    __syncthreads();
    float mn = sh2[0];
    float inv = 1.f / ((sh2[1] - mn) + 1e-12f);
    {
      int i = b * kHW + t;
      float cn = (v1 - mn) * inv;
      float tr = fmaxf(sqrtf(dap[i]) - sqrtf(dan[i]) + 0.3f, 0.f);
      total = fmaf(cn, tr, total);
    }
    if (t < kHW - 256) {
      int i = b * kHW + t + 256;
      float cn = (v2 - mn) * inv;
      float tr = fmaxf(sqrtf(dap[i]) - sqrtf(dan[i]) + 0.3f, 0.f);
      total = fmaf(cn, tr, total);
    }
    __syncthreads();
  }
  for (int off = 32; off; off >>= 1) total += __shfl_xor(total, off);
  if (l == 0) sh4a[wv] = total;
  __syncthreads();
  if (t == 0)
    out[(size_t)kB * kC * kHW] =
        (sh4a[0] + sh4a[1] + sh4a[2] + sh4a[3]) * (1.f / (float)(kB * kHW));
}

extern "C" void kernel_launch(void* const* d_in, const int* in_sizes, int n_in,
                              void* d_out, int out_size, void* d_ws, size_t ws_size,
                              hipStream_t stream) {
  const float* fv = (const float*)d_in[0];
  const float* ft = (const float*)d_in[1];
  const float* qw = (const float*)d_in[4];
  const float* qb = (const float*)d_in[5];
  const float* kw = (const float*)d_in[6];
  const float* kb = (const float*)d_in[7];
  const int* pos_idx = (const int*)d_in[8];
  const int* neg_idx = (const int*)d_in[9];
  float* out = (float*)d_out;

  constexpr size_t kFQ = (size_t)kB * kCQ * kHW;            // 9,437,184
  constexpr size_t kPR = (size_t)kB * kHW * kHW;            // 5,308,416 (u16)
  float* ws   = (float*)d_ws;
  unsigned short* fqT = (unsigned short*)ws;                // region1 (37.75M)
  unsigned short* fkT = fqT + (size_t)kB * kHW * kCQ;
  unsigned short* prb0 = (unsigned short*)(ws + kFQ);       // region2: pos P
  unsigned short* prb1 = prb0 + kPR;                        //          neg P
  unsigned short* wtq = (unsigned short*)(ws + 2 * kFQ);    // region3
  unsigned short* wtk = wtq + (size_t)9 * kCQ * kC;
  float* maskb   = (float*)(wtk + (size_t)9 * kCQ * kC);
  float* qss     = maskb + kB * kHW;
  float* kss     = qss + kB * kHW;
  float* craw    = kss + kB * kHW;   // fully overwritten by sim (no zeroing needed)
  float* dap     = craw + kB * kHW;
  float* dan     = dap + kB * kHW;
  if (ws_size < (size_t)113688576) return;

  // 5 launches: prep_w(+zero qss/kss,dap/dan), conv, sim, warp, loss
  prep_w_kernel<<<dim3(kCQ, 2), 256, 0, stream>>>(qw, kw, wtq, wtk, qss, dap);
  conv_fused_kernel<<<dim3(512), 512, 0, stream>>>(wtq, wtk, qb, kb, fv, ft,
                                                   fqT, fkT, qss, kss, maskb);
  sim_mfma_kernel<<<dim3(384), 512, 0, stream>>>(fqT, fkT, qss, kss, maskb,
                                                 pos_idx, neg_idx, prb0, prb1, craw);
  warp_mfma_kernel<<<dim3(2048), 512, 0, stream>>>(fv, ft, prb0, prb1, maskb,
                                                   pos_idx, neg_idx, out, dap, dan);
  loss_kernel<<<dim3(1), 256, 0, stream>>>(dap, dan, craw, out);
}